// Round 1
// 3451.402 us; speedup vs baseline: 1.0512x; 1.0512x over previous
//
#include <hip/hip_runtime.h>
#include <hip/hip_bf16.h>

// ---------------- problem constants ----------------
namespace {
constexpr int kN = 32768, kIN = 768, kH1 = 2048, kH2 = 1024, kE = 64, kNE = 256;
constexpr int kKP = 4096, kTT = 8192;
constexpr int kCh = 4096;  // rows per GEMM slice
constexpr int kMaxFix = 4096;  // rows handled by the fast fix chain

// flat float32 offsets in d_out, reference return order
constexpr size_t OFF_OUT = 0;
constexpr size_t OFF_VQ  = (size_t)kN * kIN;
constexpr size_t OFF_IDX = OFF_VQ + 1;
constexpr size_t OFF_XQ  = OFF_IDX + (size_t)kN;
constexpr size_t OFF_OCL = OFF_XQ + (size_t)kN * kE;
constexpr size_t OFF_ITL = OFF_OCL + 1;
constexpr size_t OFF_QDA = OFF_ITL + 1;
}  // namespace

typedef short bf16x8 __attribute__((ext_vector_type(8)));
typedef float f32x4 __attribute__((ext_vector_type(4)));

__device__ __forceinline__ unsigned short f2bf(float v) {
  __hip_bfloat16 h = __float2bfloat16(v);
  return *reinterpret_cast<unsigned short*>(&h);
}
__device__ __forceinline__ float bf2f(unsigned short u) {
  __hip_bfloat16 h = *reinterpret_cast<__hip_bfloat16*>(&u);
  return __bfloat162float(h);
}

__device__ __forceinline__ void gload_lds16(const void* g, void* lds) {
  __builtin_amdgcn_global_load_lds(
      (const __attribute__((address_space(1))) void*)g,
      (__attribute__((address_space(3))) void*)lds, 16, 0, 0);
}

// ---------------- bf16 MFMA GEMM: C = relu?(A @ Bt^T + bias) ----------------
// A: MxK bf16 row-major. Bt: NxK bf16 row-major. 4 waves in 2x2; 16x16x32 MFMA.
template <int BM, int BN, int BK, bool RELU, bool OUTF, bool OUTB>
__global__ __launch_bounds__(256) void gemm_bt(const unsigned short* __restrict__ A,
                                               const unsigned short* __restrict__ Bt,
                                               const float* __restrict__ bias,
                                               float* __restrict__ Cf,
                                               unsigned short* __restrict__ Cb,
                                               int N, int K) {
  constexpr int WM = BM / 2, WN = BN / 2, TMt = WM / 16, TNt = WN / 16;
  constexpr int CH = BK / 8;
  constexpr int RA = BM * BK / 2048, RB = BN * BK / 2048;
  __shared__ unsigned short As[BM * BK];
  __shared__ unsigned short Bs[BN * BK];
  const int tid = threadIdx.x, lane = tid & 63, wave = tid >> 6;
  const int wm = (wave >> 1) * WM, wn = (wave & 1) * WN;
  const int l15 = lane & 15, quad = lane >> 4;
  const int rowA0 = blockIdx.y * BM, colB0 = blockIdx.x * BN;
  f32x4 acc[TMt][TNt];
#pragma unroll
  for (int i = 0; i < TMt; ++i)
#pragma unroll
    for (int j = 0; j < TNt; ++j) acc[i][j] = (f32x4){0.f, 0.f, 0.f, 0.f};

  const char* Ab = (const char*)A;
  const char* Bb = (const char*)Bt;
  char* AsB = (char*)As;
  char* BsB = (char*)Bs;

  for (int k0 = 0; k0 < K; k0 += BK) {
    if (k0) __syncthreads();
#pragma unroll
    for (int r = 0; r < RA; ++r) {
      int off = (r * 256 + tid) * 16;
      int row = off / (BK * 2);
      int sc = ((off >> 4) ^ row) & (CH - 1);
      gload_lds16(Ab + (size_t)(rowA0 + row) * (K * 2) + (size_t)k0 * 2 + sc * 16,
                  AsB + off);
    }
#pragma unroll
    for (int r = 0; r < RB; ++r) {
      int off = (r * 256 + tid) * 16;
      int row = off / (BK * 2);
      int sc = ((off >> 4) ^ row) & (CH - 1);
      gload_lds16(Bb + (size_t)(colB0 + row) * (K * 2) + (size_t)k0 * 2 + sc * 16,
                  BsB + off);
    }
    __syncthreads();
#pragma unroll
    for (int ks = 0; ks < BK; ks += 32) {
      bf16x8 af[TMt], bfr[TNt];
#pragma unroll
      for (int i = 0; i < TMt; ++i) {
        int row = wm + i * 16 + l15;
        int c = (((ks >> 3) + quad) ^ row) & (CH - 1);
        af[i] = *(const bf16x8*)(AsB + row * (BK * 2) + c * 16);
      }
#pragma unroll
      for (int j = 0; j < TNt; ++j) {
        int col = wn + j * 16 + l15;
        int c = (((ks >> 3) + quad) ^ col) & (CH - 1);
        bfr[j] = *(const bf16x8*)(BsB + col * (BK * 2) + c * 16);
      }
#pragma unroll
      for (int i = 0; i < TMt; ++i)
#pragma unroll
        for (int j = 0; j < TNt; ++j)
          acc[i][j] = __builtin_amdgcn_mfma_f32_16x16x32_bf16(af[i], bfr[j],
                                                              acc[i][j], 0, 0, 0);
    }
  }
#pragma unroll
  for (int j = 0; j < TNt; ++j) {
    int col = colB0 + wn + j * 16 + l15;
    float bv = bias[col];
#pragma unroll
    for (int i = 0; i < TMt; ++i) {
      int rbase = rowA0 + wm + i * 16 + quad * 4;
#pragma unroll
      for (int r = 0; r < 4; ++r) {
        float v = acc[i][j][r] + bv;
        if (RELU) v = fmaxf(v, 0.f);
        size_t o = (size_t)(rbase + r) * N + col;
        if (OUTF) Cf[o] = v;
        if (OUTB) Cb[o] = f2bf(v);
      }
    }
  }
}

// ---------------- split-bf16 MFMA GEMM (fp32-accurate x-path) ----------------
// C = relu?((Ah+Al) @ (Bh+Bl)^T + bias), dropping Al*Bl (err ~2^-18).
// OM: 0 = write fp32 C; 2 = write split bf16 (Ch, Cl).
template <int BM, int BN, int BK, bool RELU, int OM>
__global__ __launch_bounds__(256) void gemm_bt_split(
    const unsigned short* __restrict__ Ah, const unsigned short* __restrict__ Al,
    const unsigned short* __restrict__ Bh, const unsigned short* __restrict__ Bl,
    const float* __restrict__ bias, float* __restrict__ Cf,
    unsigned short* __restrict__ Ch, unsigned short* __restrict__ Cl,
    int N, int K) {
  constexpr int WM = BM / 2, WN = BN / 2, TMt = WM / 16, TNt = WN / 16;
  constexpr int CH = BK / 8;
  constexpr int RA = BM * BK / 2048, RB = BN * BK / 2048;
  __shared__ unsigned short AsH[BM * BK];
  __shared__ unsigned short AsL[BM * BK];
  __shared__ unsigned short BsH[BN * BK];
  __shared__ unsigned short BsL[BN * BK];
  const int tid = threadIdx.x, lane = tid & 63, wave = tid >> 6;
  const int wm = (wave >> 1) * WM, wn = (wave & 1) * WN;
  const int l15 = lane & 15, quad = lane >> 4;
  const int rowA0 = blockIdx.y * BM, colB0 = blockIdx.x * BN;
  f32x4 acc[TMt][TNt];
#pragma unroll
  for (int i = 0; i < TMt; ++i)
#pragma unroll
    for (int j = 0; j < TNt; ++j) acc[i][j] = (f32x4){0.f, 0.f, 0.f, 0.f};

  const char* AhB = (const char*)Ah;
  const char* AlB = (const char*)Al;
  const char* BhB = (const char*)Bh;
  const char* BlB = (const char*)Bl;

  for (int k0 = 0; k0 < K; k0 += BK) {
    if (k0) __syncthreads();
#pragma unroll
    for (int r = 0; r < RA; ++r) {
      int off = (r * 256 + tid) * 16;
      int row = off / (BK * 2);
      int sc = ((off >> 4) ^ row) & (CH - 1);
      size_t go = (size_t)(rowA0 + row) * (K * 2) + (size_t)k0 * 2 + sc * 16;
      gload_lds16(AhB + go, (char*)AsH + off);
      gload_lds16(AlB + go, (char*)AsL + off);
    }
#pragma unroll
    for (int r = 0; r < RB; ++r) {
      int off = (r * 256 + tid) * 16;
      int row = off / (BK * 2);
      int sc = ((off >> 4) ^ row) & (CH - 1);
      size_t go = (size_t)(colB0 + row) * (K * 2) + (size_t)k0 * 2 + sc * 16;
      gload_lds16(BhB + go, (char*)BsH + off);
      gload_lds16(BlB + go, (char*)BsL + off);
    }
    __syncthreads();
#pragma unroll
    for (int ks = 0; ks < BK; ks += 32) {
      bf16x8 ah[TMt], al[TMt], bh[TNt], bl[TNt];
#pragma unroll
      for (int i = 0; i < TMt; ++i) {
        int row = wm + i * 16 + l15;
        int c = (((ks >> 3) + quad) ^ row) & (CH - 1);
        int off = row * (BK * 2) + c * 16;
        ah[i] = *(const bf16x8*)((const char*)AsH + off);
        al[i] = *(const bf16x8*)((const char*)AsL + off);
      }
#pragma unroll
      for (int j = 0; j < TNt; ++j) {
        int col = wn + j * 16 + l15;
        int c = (((ks >> 3) + quad) ^ col) & (CH - 1);
        int off = col * (BK * 2) + c * 16;
        bh[j] = *(const bf16x8*)((const char*)BsH + off);
        bl[j] = *(const bf16x8*)((const char*)BsL + off);
      }
#pragma unroll
      for (int i = 0; i < TMt; ++i)
#pragma unroll
        for (int j = 0; j < TNt; ++j) {
          acc[i][j] = __builtin_amdgcn_mfma_f32_16x16x32_bf16(ah[i], bh[j], acc[i][j], 0, 0, 0);
          acc[i][j] = __builtin_amdgcn_mfma_f32_16x16x32_bf16(ah[i], bl[j], acc[i][j], 0, 0, 0);
          acc[i][j] = __builtin_amdgcn_mfma_f32_16x16x32_bf16(al[i], bh[j], acc[i][j], 0, 0, 0);
        }
    }
  }
#pragma unroll
  for (int j = 0; j < TNt; ++j) {
    int col = colB0 + wn + j * 16 + l15;
    float bv = bias[col];
#pragma unroll
    for (int i = 0; i < TMt; ++i) {
      int rbase = rowA0 + wm + i * 16 + quad * 4;
#pragma unroll
      for (int r = 0; r < 4; ++r) {
        float v = acc[i][j][r] + bv;
        if (RELU) v = fmaxf(v, 0.f);
        size_t o = (size_t)(rbase + r) * N + col;
        if (OM == 0) {
          Cf[o] = v;
        } else {
          unsigned short hi = f2bf(v);
          Ch[o] = hi;
          Cl[o] = f2bf(v - bf2f(hi));
        }
      }
    }
  }
}

// ---------------- weight transpose fp32 KxN -> bf16 NxK (single) ------------
__global__ __launch_bounds__(256) void transpose_bf16(const float* __restrict__ W,
                                                      unsigned short* __restrict__ Wt,
                                                      int K, int N) {
  __shared__ float t[32][33];
  int bx = blockIdx.x * 32, by = blockIdx.y * 32;
  int tx = threadIdx.x & 31, ty = threadIdx.x >> 5;
#pragma unroll
  for (int i = 0; i < 32; i += 8)
    t[ty + i][tx] = W[(size_t)(by + ty + i) * N + bx + tx];
  __syncthreads();
#pragma unroll
  for (int i = 0; i < 32; i += 8)
    Wt[(size_t)(bx + ty + i) * K + by + tx] = f2bf(t[tx][ty + i]);
}

// ---------------- weight transpose fp32 KxN -> split bf16 NxK ---------------
__global__ __launch_bounds__(256) void transpose_bf16_split(
    const float* __restrict__ W, unsigned short* __restrict__ Wh,
    unsigned short* __restrict__ Wl, int K, int N) {
  __shared__ float t[32][33];
  int bx = blockIdx.x * 32, by = blockIdx.y * 32;
  int tx = threadIdx.x & 31, ty = threadIdx.x >> 5;
#pragma unroll
  for (int i = 0; i < 32; i += 8)
    t[ty + i][tx] = W[(size_t)(by + ty + i) * N + bx + tx];
  __syncthreads();
#pragma unroll
  for (int i = 0; i < 32; i += 8) {
    float v = t[tx][ty + i];
    unsigned short hi = f2bf(v);
    size_t o = (size_t)(bx + ty + i) * K + by + tx;
    Wh[o] = hi;
    Wl[o] = f2bf(v - bf2f(hi));
  }
}

// ---------------- fp32 -> bf16 convert (single) ----------------
__global__ __launch_bounds__(256) void conv_bf16(const float* __restrict__ in,
                                                 unsigned short* __restrict__ out,
                                                 int n4) {
  int i = (blockIdx.x * 256 + threadIdx.x);
  if (i < n4) {
    float4 v = *(const float4*)(in + (size_t)i * 4);
    unsigned short o[4] = {f2bf(v.x), f2bf(v.y), f2bf(v.z), f2bf(v.w)};
    *(uint2*)(out + (size_t)i * 4) = *(uint2*)o;
  }
}

// ---------------- fp32 -> split bf16 convert ----------------
__global__ __launch_bounds__(256) void conv_split(const float* __restrict__ in,
                                                  unsigned short* __restrict__ oh,
                                                  unsigned short* __restrict__ ol,
                                                  int n4) {
  int i = (blockIdx.x * 256 + threadIdx.x);
  if (i < n4) {
    float4 v = *(const float4*)(in + (size_t)i * 4);
    unsigned short h[4], l[4];
    float vv[4] = {v.x, v.y, v.z, v.w};
#pragma unroll
    for (int k = 0; k < 4; ++k) {
      h[k] = f2bf(vv[k]);
      l[k] = f2bf(vv[k] - bf2f(h[k]));
    }
    *(uint2*)(oh + (size_t)i * 4) = *(uint2*)h;
    *(uint2*)(ol + (size_t)i * 4) = *(uint2*)l;
  }
}

// ---------------- VQ: argmin over 256 codes + gap-flagging ----------------
__global__ __launch_bounds__(256) void vq_kernel(const float* __restrict__ z,
                                                 const float* __restrict__ cb,
                                                 float* __restrict__ idx_out,
                                                 float* __restrict__ xq_out,
                                                 unsigned short* __restrict__ xqb_out,
                                                 float* __restrict__ xn_out,
                                                 float* __restrict__ acc,
                                                 int* __restrict__ flags,
                                                 int* __restrict__ flagcnt) {
  __shared__ float zs[kE];
  __shared__ float dsv[256];
  __shared__ float rv[256];
  __shared__ int ri[256];
  __shared__ int defer;
  const int i = blockIdx.x;
  const int t = threadIdx.x;
  if (t < kE) zs[t] = z[(size_t)i * kE + t];
  __syncthreads();
  float dot = 0.f, nrm = 0.f, zn = 0.f;
  const float* c = cb + (size_t)t * kE;
#pragma unroll 8
  for (int e = 0; e < kE; ++e) {
    float ce = c[e];
    float ze = zs[e];
    dot = fmaf(ze, ce, dot);
    nrm = fmaf(ce, ce, nrm);
    zn = fmaf(ze, ze, zn);
  }
  float d = nrm - 2.f * dot;
  dsv[t] = d;
  rv[t] = d;
  ri[t] = t;
  __syncthreads();
  for (int s = 128; s > 0; s >>= 1) {
    if (t < s) {
      float v2 = rv[t + s];
      int i2 = ri[t + s];
      if (v2 < rv[t] || (v2 == rv[t] && i2 < ri[t])) { rv[t] = v2; ri[t] = i2; }
    }
    __syncthreads();
  }
  const int best = ri[0];
  const float d1 = rv[0];
  __syncthreads();
  // second-best value
  rv[t] = (t == best) ? 3.4e38f : dsv[t];
  __syncthreads();
  for (int s = 128; s > 0; s >>= 1) {
    if (t < s) rv[t] = fminf(rv[t], rv[t + s]);
    __syncthreads();
  }
  if (t == 0) {
    float tau = 5e-5f * sqrtf(zn);
    if (rv[0] - d1 < tau) {
      defer = 1;
      int slot = atomicAdd(flagcnt, 1);
      flags[slot] = i;
    } else {
      defer = 0;
    }
  }
  __syncthreads();
  if (defer) return;
  if (t == 0) idx_out[i] = (float)best;
  if (t < kE) {
    float xq = cb[(size_t)best * kE + t];
    xq_out[(size_t)i * kE + t] = xq;
    xqb_out[(size_t)i * kE + t] = f2bf(xq);
    float dd = xq - zs[t];
    float sq = dd * dd;
    float nq = xq * xq;
#pragma unroll
    for (int m = 32; m > 0; m >>= 1) {
      sq += __shfl_xor(sq, m);
      nq += __shfl_xor(nq, m);
    }
    float inv = 1.f / fmaxf(sqrtf(nq), 1e-12f);
    xn_out[(size_t)i * kE + t] = xq * inv;
    if (t == 0) atomicAdd(&acc[i & 255], sq);
  }
}

// ---------------- fix phase A: h1f = relu(x[flag] @ ew0 + eb0) --------------
// Work item = (row-batch of 8, 256-column chunk). Weight element reused 8x.
__global__ __launch_bounds__(256) void fix_h1(
    const float* __restrict__ x, const float* __restrict__ ew0,
    const float* __restrict__ eb0, const int* __restrict__ flags,
    const int* __restrict__ flagcnt, float* __restrict__ h1f) {
  constexpr int R = 8, NJC = 8, JC = kH1 / NJC;  // 256 cols/chunk
  __shared__ float xs[R][kIN];
  const int t = threadIdx.x;
  int cnt = *flagcnt;
  if (cnt > kMaxFix) cnt = kMaxFix;
  const int nrb = (cnt + R - 1) / R;
  const int nwork = nrb * NJC;
  for (int w = blockIdx.x; w < nwork; w += gridDim.x) {
    const int rb = w / NJC, jc = w % NJC;
    const int nr = min(R, cnt - rb * R);
    for (int rr = 0; rr < nr; ++rr) {
      const int r = flags[rb * R + rr];
      for (int q = t; q < kIN; q += 256) xs[rr][q] = x[(size_t)r * kIN + q];
    }
    __syncthreads();
    const int j = jc * JC + t;
    float s[R];
    const float b = eb0[j];
#pragma unroll
    for (int rr = 0; rr < R; ++rr) s[rr] = b;
#pragma unroll 8
    for (int k = 0; k < kIN; ++k) {
      float wv = ew0[(size_t)k * kH1 + j];
#pragma unroll
      for (int rr = 0; rr < R; ++rr) s[rr] = fmaf(xs[rr][k], wv, s[rr]);
    }
    for (int rr = 0; rr < nr; ++rr)
      h1f[(size_t)(rb * R + rr) * kH1 + j] = fmaxf(s[rr], 0.f);
    __syncthreads();
  }
}

// ---------------- fix phase B: h2f = relu(h1f @ ew1 + eb1) ------------------
__global__ __launch_bounds__(256) void fix_h2(
    const float* __restrict__ h1f, const float* __restrict__ ew1,
    const float* __restrict__ eb1, const int* __restrict__ flagcnt,
    float* __restrict__ h2f) {
  constexpr int R = 4, NJC = 4, JC = kH2 / NJC;  // 256 cols/chunk
  __shared__ float hs[R][kH1];  // 32 KB
  const int t = threadIdx.x;
  int cnt = *flagcnt;
  if (cnt > kMaxFix) cnt = kMaxFix;
  const int nrb = (cnt + R - 1) / R;
  const int nwork = nrb * NJC;
  for (int w = blockIdx.x; w < nwork; w += gridDim.x) {
    const int rb = w / NJC, jc = w % NJC;
    const int nr = min(R, cnt - rb * R);
    for (int rr = 0; rr < nr; ++rr)
      for (int q = t; q < kH1; q += 256)
        hs[rr][q] = h1f[(size_t)(rb * R + rr) * kH1 + q];
    __syncthreads();
    const int j = jc * JC + t;
    float s[R];
    const float b = eb1[j];
#pragma unroll
    for (int rr = 0; rr < R; ++rr) s[rr] = b;
#pragma unroll 8
    for (int k = 0; k < kH1; ++k) {
      float wv = ew1[(size_t)k * kH2 + j];
#pragma unroll
      for (int rr = 0; rr < R; ++rr) s[rr] = fmaf(hs[rr][k], wv, s[rr]);
    }
    for (int rr = 0; rr < nr; ++rr)
      h2f[(size_t)(rb * R + rr) * kH2 + j] = fmaxf(s[rr], 0.f);
    __syncthreads();
  }
}

// ---------------- fix phase C: z + argmin + outputs (1 block / row) ---------
__global__ __launch_bounds__(256) void fix_z(
    const float* __restrict__ h2f, const float* __restrict__ ew2,
    const float* __restrict__ eb2, const float* __restrict__ cb,
    const int* __restrict__ flags, const int* __restrict__ flagcnt,
    float* __restrict__ z, float* __restrict__ idx_out,
    float* __restrict__ xq_out, unsigned short* __restrict__ xqb_out,
    float* __restrict__ xn_out, float* __restrict__ acc) {
  __shared__ float hrow[kH2];
  __shared__ float sred[256];
  __shared__ float szs[kE];
  __shared__ float rv[256];
  __shared__ int ri[256];
  const int t = threadIdx.x;
  int cnt = *flagcnt;
  if (cnt > kMaxFix) cnt = kMaxFix;
  for (int fi = blockIdx.x; fi < cnt; fi += gridDim.x) {
    const int r = flags[fi];
    for (int q = t; q < kH2; q += 256) hrow[q] = h2f[(size_t)fi * kH2 + q];
    __syncthreads();
    // z: 64 outputs, 4 partial threads each (same order as old fix_rows)
    {
      const int j = t & 63, p = t >> 6;
      float s = 0.f;
      for (int k = p * 256; k < p * 256 + 256; ++k)
        s = fmaf(hrow[k], ew2[(size_t)k * kE + j], s);
      sred[t] = s;
      __syncthreads();
      if (t < kE) {
        float zv = sred[t] + sred[t + 64] + sred[t + 128] + sred[t + 192] + eb2[t];
        szs[t] = zv;
        z[(size_t)r * kE + t] = zv;
      }
      __syncthreads();
    }
    // argmin over codes
    {
      float dot = 0.f, nrm = 0.f;
      const float* c = cb + (size_t)t * kE;
#pragma unroll 8
      for (int e = 0; e < kE; ++e) {
        float ce = c[e];
        dot = fmaf(szs[e], ce, dot);
        nrm = fmaf(ce, ce, nrm);
      }
      rv[t] = nrm - 2.f * dot;
      ri[t] = t;
      __syncthreads();
      for (int s = 128; s > 0; s >>= 1) {
        if (t < s) {
          float v2 = rv[t + s];
          int i2 = ri[t + s];
          if (v2 < rv[t] || (v2 == rv[t] && i2 < ri[t])) { rv[t] = v2; ri[t] = i2; }
        }
        __syncthreads();
      }
      const int best = ri[0];
      if (t == 0) idx_out[r] = (float)best;
      if (t < kE) {
        float xq = cb[(size_t)best * kE + t];
        xq_out[(size_t)r * kE + t] = xq;
        xqb_out[(size_t)r * kE + t] = f2bf(xq);
        float dd = xq - szs[t];
        float sq = dd * dd;
        float nq = xq * xq;
#pragma unroll
        for (int m = 32; m > 0; m >>= 1) {
          sq += __shfl_xor(sq, m);
          nq += __shfl_xor(nq, m);
        }
        float inv = 1.f / fmaxf(sqrtf(nq), 1e-12f);
        xn_out[(size_t)r * kE + t] = xq * inv;
        if (t == 0) atomicAdd(&acc[r & 255], sq);
      }
      __syncthreads();
    }
  }
}

// ---------------- fallback: exact fp32 MLP for rows >= kMaxFix --------------
__global__ __launch_bounds__(256) void fix_rows(
    const float* __restrict__ x, const float* __restrict__ ew0,
    const float* __restrict__ eb0, const float* __restrict__ ew1,
    const float* __restrict__ eb1, const float* __restrict__ ew2,
    const float* __restrict__ eb2, const float* __restrict__ cb,
    const int* __restrict__ flags, const int* __restrict__ flagcnt,
    float* __restrict__ z, float* __restrict__ idx_out,
    float* __restrict__ xq_out, unsigned short* __restrict__ xqb_out,
    float* __restrict__ xn_out, float* __restrict__ acc) {
  __shared__ float xs[kIN];
  __shared__ float sh1[kH1];
  __shared__ float sh2[kH2];
  __shared__ float sred[256];
  __shared__ float szs[kE];
  __shared__ float rv[256];
  __shared__ int ri[256];
  const int t = threadIdx.x;
  const int cnt = *flagcnt;
  for (int fi = kMaxFix + blockIdx.x; fi < cnt; fi += gridDim.x) {
    const int r = flags[fi];
    for (int q = t; q < kIN; q += 256) xs[q] = x[(size_t)r * kIN + q];
    __syncthreads();
#pragma unroll
    for (int o = 0; o < kH1 / 256; ++o) {
      int j = t + 256 * o;
      float s = eb0[j];
      for (int k = 0; k < kIN; ++k) s = fmaf(xs[k], ew0[(size_t)k * kH1 + j], s);
      sh1[j] = fmaxf(s, 0.f);
    }
    __syncthreads();
#pragma unroll
    for (int o = 0; o < kH2 / 256; ++o) {
      int j = t + 256 * o;
      float s = eb1[j];
      for (int k = 0; k < kH1; ++k) s = fmaf(sh1[k], ew1[(size_t)k * kH2 + j], s);
      sh2[j] = fmaxf(s, 0.f);
    }
    __syncthreads();
    {
      int j = t & 63, p = t >> 6;
      float s = 0.f;
      for (int k = p * 256; k < p * 256 + 256; ++k)
        s = fmaf(sh2[k], ew2[(size_t)k * kE + j], s);
      sred[t] = s;
      __syncthreads();
      if (t < kE) {
        float zv = sred[t] + sred[t + 64] + sred[t + 128] + sred[t + 192] + eb2[t];
        szs[t] = zv;
        z[(size_t)r * kE + t] = zv;
      }
      __syncthreads();
    }
    {
      float dot = 0.f, nrm = 0.f;
      const float* c = cb + (size_t)t * kE;
#pragma unroll 8
      for (int e = 0; e < kE; ++e) {
        float ce = c[e];
        dot = fmaf(szs[e], ce, dot);
        nrm = fmaf(ce, ce, nrm);
      }
      rv[t] = nrm - 2.f * dot;
      ri[t] = t;
      __syncthreads();
      for (int s = 128; s > 0; s >>= 1) {
        if (t < s) {
          float v2 = rv[t + s];
          int i2 = ri[t + s];
          if (v2 < rv[t] || (v2 == rv[t] && i2 < ri[t])) { rv[t] = v2; ri[t] = i2; }
        }
        __syncthreads();
      }
      const int best = ri[0];
      if (t == 0) idx_out[r] = (float)best;
      if (t < kE) {
        float xq = cb[(size_t)best * kE + t];
        xq_out[(size_t)r * kE + t] = xq;
        xqb_out[(size_t)r * kE + t] = f2bf(xq);
        float dd = xq - szs[t];
        float sq = dd * dd;
        float nq = xq * xq;
#pragma unroll
        for (int m = 32; m > 0; m >>= 1) {
          sq += __shfl_xor(sq, m);
          nq += __shfl_xor(nq, m);
        }
        float inv = 1.f / fmaxf(sqrtf(nq), 1e-12f);
        xn_out[(size_t)r * kE + t] = xq * inv;
        if (t == 0) atomicAdd(&acc[r & 255], sq);
      }
      __syncthreads();
    }
  }
}

// ---------------- qd_align ----------------
__global__ __launch_bounds__(256) void qd_kernel(const float* __restrict__ z,
                                                 const float* __restrict__ qz,
                                                 const float* __restrict__ w,
                                                 float* __restrict__ acc) {
  const int i = blockIdx.x * 4 + (threadIdx.x >> 6);
  const int l = threadIdx.x & 63;
  float a = z[(size_t)i * kE + l];
  float b = qz[(size_t)i * kE + l];
  float dot = a * b, na = a * a, nb = b * b;
#pragma unroll
  for (int m = 32; m > 0; m >>= 1) {
    dot += __shfl_xor(dot, m);
    na += __shfl_xor(na, m);
    nb += __shfl_xor(nb, m);
  }
  if (l == 0) {
    float cosv = dot / fmaxf(sqrtf(na) * sqrtf(nb), 1e-8f);
    atomicAdd(&acc[i & 255], w[i] * cosv);
  }
}

// ---------------- triplet ----------------
__global__ __launch_bounds__(256) void trip_kernel(const float* __restrict__ z,
                                                   const int* __restrict__ tr,
                                                   float* __restrict__ acc) {
  const int t = blockIdx.x * 4 + (threadIdx.x >> 6);
  const int l = threadIdx.x & 63;
  int ia = tr[3 * t], ip = tr[3 * t + 1], in2 = tr[3 * t + 2];
  float a = z[(size_t)ia * kE + l];
  float p = z[(size_t)ip * kE + l];
  float n = z[(size_t)in2 * kE + l];
  float d1 = (a - p) * (a - p);
  float d2 = (a - n) * (a - n);
#pragma unroll
  for (int m = 32; m > 0; m >>= 1) {
    d1 += __shfl_xor(d1, m);
    d2 += __shfl_xor(d2, m);
  }
  if (l == 0) {
    float dp = sqrtf(d1 + 1e-12f);
    float dn = sqrtf(d2 + 1e-12f);
    atomicAdd(&acc[t & 255], fmaxf(dp - dn + 0.2f, 0.f));
  }
}

// ---------------- pairs: subtract positive sim ----------------
__global__ __launch_bounds__(256) void pos_kernel(const float* __restrict__ xn,
                                                  const int* __restrict__ pairs,
                                                  float* __restrict__ acc) {
  const int k = blockIdx.x * 4 + (threadIdx.x >> 6);
  const int l = threadIdx.x & 63;
  int i0 = pairs[2 * k], i1 = pairs[2 * k + 1];
  float v = xn[(size_t)i0 * kE + l] * xn[(size_t)i1 * kE + l];
#pragma unroll
  for (int m = 32; m > 0; m >>= 1) v += __shfl_xor(v, m);
  if (l == 0) atomicAdd(&acc[k & 255], -10.f * v);
}

// ---------------- pairs: partial sumexp over a j-segment ----------------
__global__ __launch_bounds__(256) void lse_kernel(const float* __restrict__ xn,
                                                  const int* __restrict__ pairs,
                                                  float* __restrict__ pairsum) {
  constexpr int PPB = 16, TJ = 128, PAD = 4, JSEG = kN / 8;
  __shared__ float anch[PPB][kE];
  __shared__ float tileT[kE][TJ + PAD];
  const int t = threadIdx.x;
  const int pb = blockIdx.x * PPB;
  const int jbase = blockIdx.y * JSEG;
  for (int q = t; q < PPB * kE; q += 256) {
    int p = q >> 6, e = q & 63;
    anch[p][e] = xn[(size_t)pairs[2 * (pb + p)] * kE + e];
  }
  const int cg = t & 31;
  const int pg = t >> 5;
  const int c0 = cg * 4;
  const int p0 = 2 * pg, p1 = 2 * pg + 1;
  const int cload = t & 127;
  const int eb = t >> 7;
  float s0 = 0.f, s1 = 0.f;
  for (int j0 = jbase; j0 < jbase + JSEG; j0 += TJ) {
    __syncthreads();
#pragma unroll
    for (int i = 0; i < 8; ++i) {
      int e4 = (eb + 2 * i) * 4;
      float4 v = *(const float4*)(xn + (size_t)(j0 + cload) * kE + e4);
      tileT[e4 + 0][cload] = v.x;
      tileT[e4 + 1][cload] = v.y;
      tileT[e4 + 2][cload] = v.z;
      tileT[e4 + 3][cload] = v.w;
    }
    __syncthreads();
    float4 d0 = {0.f, 0.f, 0.f, 0.f}, d1 = {0.f, 0.f, 0.f, 0.f};
#pragma unroll
    for (int e = 0; e < kE; e += 4) {
      float4 a0 = *(const float4*)(&anch[p0][e]);
      float4 a1 = *(const float4*)(&anch[p1][e]);
      float4 t0 = *(const float4*)(&tileT[e + 0][c0]);
      float4 t1 = *(const float4*)(&tileT[e + 1][c0]);
      float4 t2 = *(const float4*)(&tileT[e + 2][c0]);
      float4 t3 = *(const float4*)(&tileT[e + 3][c0]);
#define ACC4(dd, aa, tt)              \
  dd.x = fmaf(aa, tt.x, dd.x);        \
  dd.y = fmaf(aa, tt.y, dd.y);        \
  dd.z = fmaf(aa, tt.z, dd.z);        \
  dd.w = fmaf(aa, tt.w, dd.w)
      ACC4(d0, a0.x, t0); ACC4(d0, a0.y, t1); ACC4(d0, a0.z, t2); ACC4(d0, a0.w, t3);
      ACC4(d1, a1.x, t0); ACC4(d1, a1.y, t1); ACC4(d1, a1.z, t2); ACC4(d1, a1.w, t3);
#undef ACC4
    }
    s0 += expf(10.f * d0.x) + expf(10.f * d0.y) + expf(10.f * d0.z) + expf(10.f * d0.w);
    s1 += expf(10.f * d1.x) + expf(10.f * d1.y) + expf(10.f * d1.z) + expf(10.f * d1.w);
  }
#pragma unroll
  for (int m = 16; m > 0; m >>= 1) {
    s0 += __shfl_xor(s0, m);
    s1 += __shfl_xor(s1, m);
  }
  if (cg == 0) {
    atomicAdd(&pairsum[pb + p0], s0);
    atomicAdd(&pairsum[pb + p1], s1);
  }
}

__global__ __launch_bounds__(256) void lse_log_kernel(const float* __restrict__ pairsum,
                                                      float* __restrict__ acc) {
  int p = blockIdx.x * 256 + threadIdx.x;
  atomicAdd(&acc[p & 255], logf(pairsum[p]));
}

// ---------------- finalize scalars ----------------
__global__ __launch_bounds__(256) void finalize_kernel(const float* __restrict__ acc,
                                                       float* __restrict__ out) {
  const int t = threadIdx.x;
  float vq = acc[t], qd = acc[256 + t], tr = acc[512 + t], ou = acc[768 + t];
#pragma unroll
  for (int m = 32; m > 0; m >>= 1) {
    vq += __shfl_xor(vq, m);
    qd += __shfl_xor(qd, m);
    tr += __shfl_xor(tr, m);
    ou += __shfl_xor(ou, m);
  }
  __shared__ float sm[4][4];
  const int w = t >> 6;
  if ((t & 63) == 0) { sm[0][w] = vq; sm[1][w] = qd; sm[2][w] = tr; sm[3][w] = ou; }
  __syncthreads();
  if (t == 0) {
    float svq = sm[0][0] + sm[0][1] + sm[0][2] + sm[0][3];
    float sqd = sm[1][0] + sm[1][1] + sm[1][2] + sm[1][3];
    float str = sm[2][0] + sm[2][1] + sm[2][2] + sm[2][3];
    float sou = sm[3][0] + sm[3][1] + sm[3][2] + sm[3][3];
    out[OFF_VQ]  = 1.001f * svq / (float)((size_t)kN * kE);
    out[OFF_OCL] = sou / (float)kKP;
    out[OFF_ITL] = str / (float)kTT;
    out[OFF_QDA] = 1.f - sqd / (float)kN;
  }
}

// ---------------- orchestration ----------------
extern "C" void kernel_launch(void* const* d_in, const int* in_sizes, int n_in,
                              void* d_out, int out_size, void* d_ws, size_t ws_size,
                              hipStream_t stream) {
  (void)in_sizes; (void)n_in; (void)out_size; (void)ws_size;
  const float* x    = (const float*)d_in[0];
  const float* qe   = (const float*)d_in[1];
  const float* qdw  = (const float*)d_in[2];
  const int*   prs  = (const int*)d_in[3];
  const int*   trs  = (const int*)d_in[4];
  const float* ew0  = (const float*)d_in[5];
  const float* eb0  = (const float*)d_in[6];
  const float* ew1  = (const float*)d_in[7];
  const float* eb1  = (const float*)d_in[8];
  const float* ew2  = (const float*)d_in[9];
  const float* eb2  = (const float*)d_in[10];
  const float* dw0  = (const float*)d_in[11];
  const float* db0  = (const float*)d_in[12];
  const float* dw1  = (const float*)d_in[13];
  const float* db1  = (const float*)d_in[14];
  const float* dw2  = (const float*)d_in[15];
  const float* db2  = (const float*)d_in[16];
  const float* cb   = (const float*)d_in[17];
  float* out = (float*)d_out;

  // ---- workspace carve-up (~114 MB) ----
  float* z   = (float*)d_ws;                         // N x E fp32
  float* qz  = z  + (size_t)kN * kE;
  float* xn  = qz + (size_t)kN * kE;
  float* acc = xn + (size_t)kN * kE;                 // 1024
  float* pairsum = acc + 1024;                       // 4096
  int*   flagcnt = (int*)(pairsum + 4096);           // 64 (1 used)
  int*   flags   = flagcnt + 64;                     // kN ints
  unsigned short* xqb  = (unsigned short*)(flags + kN);     // N x E bf16
  unsigned short* wt0h = xqb  + (size_t)kN * kE;     // enc w0^T hi 2048x768
  unsigned short* wt0l = wt0h + (size_t)kH1 * kIN;
  unsigned short* wt1h = wt0l + (size_t)kH1 * kIN;   // 1024x2048
  unsigned short* wt1l = wt1h + (size_t)kH2 * kH1;
  unsigned short* wt2h = wt1l + (size_t)kH2 * kH1;   // 64x1024
  unsigned short* wt2l = wt2h + (size_t)kE * kH2;
  unsigned short* wt3  = wt2l + (size_t)kE * kH2;    // dec w0^T 1024x64
  unsigned short* wt4  = wt3  + (size_t)kH2 * kE;    // dec w1^T 2048x1024
  unsigned short* wt5  = wt4  + (size_t)kH1 * kH2;   // dec w2^T 768x2048
  // chunk scratch (union across phases), 4096-row chunks
  unsigned short* xh  = wt5 + (size_t)kIN * kH1;     // 4096x768
  unsigned short* xl  = xh + (size_t)kCh * kIN;
  unsigned short* h1h = xl + (size_t)kCh * kIN;      // 4096x2048
  unsigned short* h1l = h1h + (size_t)kCh * kH1;
  unsigned short* h2h = h1l + (size_t)kCh * kH1;     // 4096x1024
  unsigned short* h2l = h2h + (size_t)kCh * kH2;
  // fix-chain scratch: aliases chunk scratch (dead between x-enc and decoder).
  // h1f: kMaxFix x kH1 fp32 (32 MB) + h2f: kMaxFix x kH2 fp32 (16 MB) = 48 MB
  // <= 62.9 MB of chunk scratch. Decoder overwrites afterwards; fine.
  float* h1f = (float*)xh;
  float* h2f = h1f + (size_t)kMaxFix * kH1;

  hipMemsetAsync(acc, 0, (1024 + 4096 + 64) * sizeof(float), stream);

  // weight transposes: encoder split, decoder single
  transpose_bf16_split<<<dim3(kH1 / 32, kIN / 32), 256, 0, stream>>>(ew0, wt0h, wt0l, kIN, kH1);
  transpose_bf16_split<<<dim3(kH2 / 32, kH1 / 32), 256, 0, stream>>>(ew1, wt1h, wt1l, kH1, kH2);
  transpose_bf16_split<<<dim3(kE / 32, kH2 / 32), 256, 0, stream>>>(ew2, wt2h, wt2l, kH2, kE);
  transpose_bf16<<<dim3(kH2 / 32, kE / 32), 256, 0, stream>>>(dw0, wt3, kE, kH2);
  transpose_bf16<<<dim3(kH1 / 32, kH2 / 32), 256, 0, stream>>>(dw1, wt4, kH2, kH1);
  transpose_bf16<<<dim3(kIN / 32, kH1 / 32), 256, 0, stream>>>(dw2, wt5, kH1, kIN);

  // x-encoder (split-bf16 MFMA) -> z fp32
  for (int c = 0; c < kN / kCh; ++c) {
    conv_split<<<(kCh * kIN / 4 + 255) / 256, 256, 0, stream>>>(
        x + (size_t)c * kCh * kIN, xh, xl, kCh * kIN / 4);
    gemm_bt_split<128, 128, 64, true, 2>
        <<<dim3(kH1 / 128, kCh / 128), 256, 0, stream>>>(
            xh, xl, wt0h, wt0l, eb0, nullptr, h1h, h1l, kH1, kIN);
    gemm_bt_split<128, 128, 64, true, 2>
        <<<dim3(kH2 / 128, kCh / 128), 256, 0, stream>>>(
            h1h, h1l, wt1h, wt1l, eb1, nullptr, h2h, h2l, kH2, kH1);
    gemm_bt_split<128, 64, 64, false, 0>
        <<<dim3(kE / 64, kCh / 128), 256, 0, stream>>>(
            h2h, h2l, wt2h, wt2l, eb2, z + (size_t)c * kCh * kE, nullptr, nullptr,
            kE, kH2);
  }

  // VQ with gap-flagging, then exact fp32 fix for flagged rows.
  // Fix chain: 3 phase kernels tiling (row-batch x col-chunk) so encoder
  // weights are partitioned across blocks and reused across rows (the old
  // monolithic fix_rows re-read all 15 MB of weights per row: 477 us).
  vq_kernel<<<kN, 256, 0, stream>>>(z, cb, out + OFF_IDX, out + OFF_XQ, xqb, xn,
                                    acc, flags, flagcnt);
  fix_h1<<<512, 256, 0, stream>>>(x, ew0, eb0, flags, flagcnt, h1f);
  fix_h2<<<512, 256, 0, stream>>>(h1f, ew1, eb1, flagcnt, h2f);
  fix_z<<<512, 256, 0, stream>>>(h2f, ew2, eb2, cb, flags, flagcnt, z,
                                 out + OFF_IDX, out + OFF_XQ, xqb, xn, acc);
  // fallback for pathological flag counts (> kMaxFix); no-op otherwise
  fix_rows<<<64, 256, 0, stream>>>(x, ew0, eb0, ew1, eb1, ew2, eb2, cb, flags,
                                   flagcnt, z, out + OFF_IDX, out + OFF_XQ, xqb,
                                   xn, acc);

  // decoder (bf16 MFMA) on x_q_st -> out
  for (int c = 0; c < kN / kCh; ++c) {
    gemm_bt<128, 128, 64, true, false, true>
        <<<dim3(kH2 / 128, kCh / 128), 256, 0, stream>>>(
            xqb + (size_t)c * kCh * kE, wt3, db0, nullptr, h2h, kH2, kE);
    gemm_bt<128, 128, 64, true, false, true>
        <<<dim3(kH1 / 128, kCh / 128), 256, 0, stream>>>(
            h2h, wt4, db1, nullptr, h1h, kH1, kH2);
    gemm_bt<128, 128, 64, false, true, false>
        <<<dim3(kIN / 128, kCh / 128), 256, 0, stream>>>(
            h1h, wt5, db2, out + OFF_OUT + (size_t)c * kCh * kIN, nullptr, kIN, kH1);
  }

  // q-encoder (bf16 MFMA) -> qz
  for (int c = 0; c < kN / kCh; ++c) {
    conv_bf16<<<(kCh * kIN / 4 + 255) / 256, 256, 0, stream>>>(
        qe + (size_t)c * kCh * kIN, xh, kCh * kIN / 4);
    gemm_bt<128, 128, 64, true, false, true>
        <<<dim3(kH1 / 128, kCh / 128), 256, 0, stream>>>(
            xh, wt0h, eb0, nullptr, h1h, kH1, kIN);
    gemm_bt<128, 128, 64, true, false, true>
        <<<dim3(kH2 / 128, kCh / 128), 256, 0, stream>>>(
            h1h, wt1h, eb1, nullptr, h2h, kH2, kH1);
    gemm_bt<128, 64, 64, false, true, false>
        <<<dim3(kE / 64, kCh / 128), 256, 0, stream>>>(
            h2h, wt2h, eb2, qz + (size_t)c * kCh * kE, nullptr, kE, kH2);
  }

  // small loss kernels (all after fix chain: z/xn final)
  qd_kernel<<<kN / 4, 256, 0, stream>>>(z, qz, qdw, acc + 256);
  trip_kernel<<<kTT / 4, 256, 0, stream>>>(z, trs, acc + 512);
  pos_kernel<<<kKP / 4, 256, 0, stream>>>(xn, prs, acc + 768);
  lse_kernel<<<dim3(kKP / 16, 8), 256, 0, stream>>>(xn, prs, pairsum);
  lse_log_kernel<<<kKP / 256, 256, 0, stream>>>(pairsum, acc + 768);

  finalize_kernel<<<1, 256, 0, stream>>>(acc, out);
}

// Round 2
// 3075.108 us; speedup vs baseline: 1.1799x; 1.1224x over previous
//
#include <hip/hip_runtime.h>
#include <hip/hip_bf16.h>

// ---------------- problem constants ----------------
namespace {
constexpr int kN = 32768, kIN = 768, kH1 = 2048, kH2 = 1024, kE = 64, kNE = 256;
constexpr int kKP = 4096, kTT = 8192;
constexpr int kCh = 4096;  // rows per GEMM slice
constexpr int kMaxFix = 4096;  // rows handled by the fast fix chain

// flat float32 offsets in d_out, reference return order
constexpr size_t OFF_OUT = 0;
constexpr size_t OFF_VQ  = (size_t)kN * kIN;
constexpr size_t OFF_IDX = OFF_VQ + 1;
constexpr size_t OFF_XQ  = OFF_IDX + (size_t)kN;
constexpr size_t OFF_OCL = OFF_XQ + (size_t)kN * kE;
constexpr size_t OFF_ITL = OFF_OCL + 1;
constexpr size_t OFF_QDA = OFF_ITL + 1;
}  // namespace

typedef short bf16x8 __attribute__((ext_vector_type(8)));
typedef float f32x4 __attribute__((ext_vector_type(4)));

__device__ __forceinline__ unsigned short f2bf(float v) {
  __hip_bfloat16 h = __float2bfloat16(v);
  return *reinterpret_cast<unsigned short*>(&h);
}
__device__ __forceinline__ float bf2f(unsigned short u) {
  __hip_bfloat16 h = *reinterpret_cast<__hip_bfloat16*>(&u);
  return __bfloat162float(h);
}

__device__ __forceinline__ void gload_lds16(const void* g, void* lds) {
  __builtin_amdgcn_global_load_lds(
      (const __attribute__((address_space(1))) void*)g,
      (__attribute__((address_space(3))) void*)lds, 16, 0, 0);
}

// ---------------- bf16 MFMA GEMM: C = relu?(A @ Bt^T + bias) ----------------
// A: MxK bf16 row-major. Bt: NxK bf16 row-major. 4 waves in 2x2; 16x16x32 MFMA.
template <int BM, int BN, int BK, bool RELU, bool OUTF, bool OUTB>
__global__ __launch_bounds__(256) void gemm_bt(const unsigned short* __restrict__ A,
                                               const unsigned short* __restrict__ Bt,
                                               const float* __restrict__ bias,
                                               float* __restrict__ Cf,
                                               unsigned short* __restrict__ Cb,
                                               int N, int K) {
  constexpr int WM = BM / 2, WN = BN / 2, TMt = WM / 16, TNt = WN / 16;
  constexpr int CH = BK / 8;
  constexpr int RA = BM * BK / 2048, RB = BN * BK / 2048;
  __shared__ unsigned short As[BM * BK];
  __shared__ unsigned short Bs[BN * BK];
  const int tid = threadIdx.x, lane = tid & 63, wave = tid >> 6;
  const int wm = (wave >> 1) * WM, wn = (wave & 1) * WN;
  const int l15 = lane & 15, quad = lane >> 4;
  const int rowA0 = blockIdx.y * BM, colB0 = blockIdx.x * BN;
  f32x4 acc[TMt][TNt];
#pragma unroll
  for (int i = 0; i < TMt; ++i)
#pragma unroll
    for (int j = 0; j < TNt; ++j) acc[i][j] = (f32x4){0.f, 0.f, 0.f, 0.f};

  const char* Ab = (const char*)A;
  const char* Bb = (const char*)Bt;
  char* AsB = (char*)As;
  char* BsB = (char*)Bs;

  for (int k0 = 0; k0 < K; k0 += BK) {
    if (k0) __syncthreads();
#pragma unroll
    for (int r = 0; r < RA; ++r) {
      int off = (r * 256 + tid) * 16;
      int row = off / (BK * 2);
      int sc = ((off >> 4) ^ row) & (CH - 1);
      gload_lds16(Ab + (size_t)(rowA0 + row) * (K * 2) + (size_t)k0 * 2 + sc * 16,
                  AsB + off);
    }
#pragma unroll
    for (int r = 0; r < RB; ++r) {
      int off = (r * 256 + tid) * 16;
      int row = off / (BK * 2);
      int sc = ((off >> 4) ^ row) & (CH - 1);
      gload_lds16(Bb + (size_t)(colB0 + row) * (K * 2) + (size_t)k0 * 2 + sc * 16,
                  BsB + off);
    }
    __syncthreads();
#pragma unroll
    for (int ks = 0; ks < BK; ks += 32) {
      bf16x8 af[TMt], bfr[TNt];
#pragma unroll
      for (int i = 0; i < TMt; ++i) {
        int row = wm + i * 16 + l15;
        int c = (((ks >> 3) + quad) ^ row) & (CH - 1);
        af[i] = *(const bf16x8*)(AsB + row * (BK * 2) + c * 16);
      }
#pragma unroll
      for (int j = 0; j < TNt; ++j) {
        int col = wn + j * 16 + l15;
        int c = (((ks >> 3) + quad) ^ col) & (CH - 1);
        bfr[j] = *(const bf16x8*)(BsB + col * (BK * 2) + c * 16);
      }
#pragma unroll
      for (int i = 0; i < TMt; ++i)
#pragma unroll
        for (int j = 0; j < TNt; ++j)
          acc[i][j] = __builtin_amdgcn_mfma_f32_16x16x32_bf16(af[i], bfr[j],
                                                              acc[i][j], 0, 0, 0);
    }
  }
#pragma unroll
  for (int j = 0; j < TNt; ++j) {
    int col = colB0 + wn + j * 16 + l15;
    float bv = bias[col];
#pragma unroll
    for (int i = 0; i < TMt; ++i) {
      int rbase = rowA0 + wm + i * 16 + quad * 4;
#pragma unroll
      for (int r = 0; r < 4; ++r) {
        float v = acc[i][j][r] + bv;
        if (RELU) v = fmaxf(v, 0.f);
        size_t o = (size_t)(rbase + r) * N + col;
        if (OUTF) Cf[o] = v;
        if (OUTB) Cb[o] = f2bf(v);
      }
    }
  }
}

// ---------------- split-bf16 MFMA GEMM (fp32-accurate x-path) ----------------
// C = relu?((Ah+Al) @ (Bh+Bl)^T + bias), dropping Al*Bl (err ~2^-18).
// OM: 0 = write fp32 C; 2 = write split bf16 (Ch, Cl).
template <int BM, int BN, int BK, bool RELU, int OM>
__global__ __launch_bounds__(256) void gemm_bt_split(
    const unsigned short* __restrict__ Ah, const unsigned short* __restrict__ Al,
    const unsigned short* __restrict__ Bh, const unsigned short* __restrict__ Bl,
    const float* __restrict__ bias, float* __restrict__ Cf,
    unsigned short* __restrict__ Ch, unsigned short* __restrict__ Cl,
    int N, int K) {
  constexpr int WM = BM / 2, WN = BN / 2, TMt = WM / 16, TNt = WN / 16;
  constexpr int CH = BK / 8;
  constexpr int RA = BM * BK / 2048, RB = BN * BK / 2048;
  __shared__ unsigned short AsH[BM * BK];
  __shared__ unsigned short AsL[BM * BK];
  __shared__ unsigned short BsH[BN * BK];
  __shared__ unsigned short BsL[BN * BK];
  const int tid = threadIdx.x, lane = tid & 63, wave = tid >> 6;
  const int wm = (wave >> 1) * WM, wn = (wave & 1) * WN;
  const int l15 = lane & 15, quad = lane >> 4;
  const int rowA0 = blockIdx.y * BM, colB0 = blockIdx.x * BN;
  f32x4 acc[TMt][TNt];
#pragma unroll
  for (int i = 0; i < TMt; ++i)
#pragma unroll
    for (int j = 0; j < TNt; ++j) acc[i][j] = (f32x4){0.f, 0.f, 0.f, 0.f};

  const char* AhB = (const char*)Ah;
  const char* AlB = (const char*)Al;
  const char* BhB = (const char*)Bh;
  const char* BlB = (const char*)Bl;

  for (int k0 = 0; k0 < K; k0 += BK) {
    if (k0) __syncthreads();
#pragma unroll
    for (int r = 0; r < RA; ++r) {
      int off = (r * 256 + tid) * 16;
      int row = off / (BK * 2);
      int sc = ((off >> 4) ^ row) & (CH - 1);
      size_t go = (size_t)(rowA0 + row) * (K * 2) + (size_t)k0 * 2 + sc * 16;
      gload_lds16(AhB + go, (char*)AsH + off);
      gload_lds16(AlB + go, (char*)AsL + off);
    }
#pragma unroll
    for (int r = 0; r < RB; ++r) {
      int off = (r * 256 + tid) * 16;
      int row = off / (BK * 2);
      int sc = ((off >> 4) ^ row) & (CH - 1);
      size_t go = (size_t)(colB0 + row) * (K * 2) + (size_t)k0 * 2 + sc * 16;
      gload_lds16(BhB + go, (char*)BsH + off);
      gload_lds16(BlB + go, (char*)BsL + off);
    }
    __syncthreads();
#pragma unroll
    for (int ks = 0; ks < BK; ks += 32) {
      bf16x8 ah[TMt], al[TMt], bh[TNt], bl[TNt];
#pragma unroll
      for (int i = 0; i < TMt; ++i) {
        int row = wm + i * 16 + l15;
        int c = (((ks >> 3) + quad) ^ row) & (CH - 1);
        int off = row * (BK * 2) + c * 16;
        ah[i] = *(const bf16x8*)((const char*)AsH + off);
        al[i] = *(const bf16x8*)((const char*)AsL + off);
      }
#pragma unroll
      for (int j = 0; j < TNt; ++j) {
        int col = wn + j * 16 + l15;
        int c = (((ks >> 3) + quad) ^ col) & (CH - 1);
        int off = col * (BK * 2) + c * 16;
        bh[j] = *(const bf16x8*)((const char*)BsH + off);
        bl[j] = *(const bf16x8*)((const char*)BsL + off);
      }
#pragma unroll
      for (int i = 0; i < TMt; ++i)
#pragma unroll
        for (int j = 0; j < TNt; ++j) {
          acc[i][j] = __builtin_amdgcn_mfma_f32_16x16x32_bf16(ah[i], bh[j], acc[i][j], 0, 0, 0);
          acc[i][j] = __builtin_amdgcn_mfma_f32_16x16x32_bf16(ah[i], bl[j], acc[i][j], 0, 0, 0);
          acc[i][j] = __builtin_amdgcn_mfma_f32_16x16x32_bf16(al[i], bh[j], acc[i][j], 0, 0, 0);
        }
    }
  }
#pragma unroll
  for (int j = 0; j < TNt; ++j) {
    int col = colB0 + wn + j * 16 + l15;
    float bv = bias[col];
#pragma unroll
    for (int i = 0; i < TMt; ++i) {
      int rbase = rowA0 + wm + i * 16 + quad * 4;
#pragma unroll
      for (int r = 0; r < 4; ++r) {
        float v = acc[i][j][r] + bv;
        if (RELU) v = fmaxf(v, 0.f);
        size_t o = (size_t)(rbase + r) * N + col;
        if (OM == 0) {
          Cf[o] = v;
        } else {
          unsigned short hi = f2bf(v);
          Ch[o] = hi;
          Cl[o] = f2bf(v - bf2f(hi));
        }
      }
    }
  }
}

// ---------------- weight transpose fp32 KxN -> bf16 NxK (single) ------------
__global__ __launch_bounds__(256) void transpose_bf16(const float* __restrict__ W,
                                                      unsigned short* __restrict__ Wt,
                                                      int K, int N) {
  __shared__ float t[32][33];
  int bx = blockIdx.x * 32, by = blockIdx.y * 32;
  int tx = threadIdx.x & 31, ty = threadIdx.x >> 5;
#pragma unroll
  for (int i = 0; i < 32; i += 8)
    t[ty + i][tx] = W[(size_t)(by + ty + i) * N + bx + tx];
  __syncthreads();
#pragma unroll
  for (int i = 0; i < 32; i += 8)
    Wt[(size_t)(bx + ty + i) * K + by + tx] = f2bf(t[tx][ty + i]);
}

// ---------------- weight transpose fp32 KxN -> split bf16 NxK ---------------
__global__ __launch_bounds__(256) void transpose_bf16_split(
    const float* __restrict__ W, unsigned short* __restrict__ Wh,
    unsigned short* __restrict__ Wl, int K, int N) {
  __shared__ float t[32][33];
  int bx = blockIdx.x * 32, by = blockIdx.y * 32;
  int tx = threadIdx.x & 31, ty = threadIdx.x >> 5;
#pragma unroll
  for (int i = 0; i < 32; i += 8)
    t[ty + i][tx] = W[(size_t)(by + ty + i) * N + bx + tx];
  __syncthreads();
#pragma unroll
  for (int i = 0; i < 32; i += 8) {
    float v = t[tx][ty + i];
    unsigned short hi = f2bf(v);
    size_t o = (size_t)(bx + ty + i) * K + by + tx;
    Wh[o] = hi;
    Wl[o] = f2bf(v - bf2f(hi));
  }
}

// ---------------- fp32 -> bf16 convert (single) ----------------
__global__ __launch_bounds__(256) void conv_bf16(const float* __restrict__ in,
                                                 unsigned short* __restrict__ out,
                                                 int n4) {
  int i = (blockIdx.x * 256 + threadIdx.x);
  if (i < n4) {
    float4 v = *(const float4*)(in + (size_t)i * 4);
    unsigned short o[4] = {f2bf(v.x), f2bf(v.y), f2bf(v.z), f2bf(v.w)};
    *(uint2*)(out + (size_t)i * 4) = *(uint2*)o;
  }
}

// ---------------- fp32 -> split bf16 convert ----------------
__global__ __launch_bounds__(256) void conv_split(const float* __restrict__ in,
                                                  unsigned short* __restrict__ oh,
                                                  unsigned short* __restrict__ ol,
                                                  int n4) {
  int i = (blockIdx.x * 256 + threadIdx.x);
  if (i < n4) {
    float4 v = *(const float4*)(in + (size_t)i * 4);
    unsigned short h[4], l[4];
    float vv[4] = {v.x, v.y, v.z, v.w};
#pragma unroll
    for (int k = 0; k < 4; ++k) {
      h[k] = f2bf(vv[k]);
      l[k] = f2bf(vv[k] - bf2f(h[k]));
    }
    *(uint2*)(oh + (size_t)i * 4) = *(uint2*)h;
    *(uint2*)(ol + (size_t)i * 4) = *(uint2*)l;
  }
}

// ---------------- VQ: argmin over 256 codes + gap-flagging ----------------
__global__ __launch_bounds__(256) void vq_kernel(const float* __restrict__ z,
                                                 const float* __restrict__ cb,
                                                 float* __restrict__ idx_out,
                                                 float* __restrict__ xq_out,
                                                 unsigned short* __restrict__ xqb_out,
                                                 float* __restrict__ xn_out,
                                                 float* __restrict__ acc,
                                                 int* __restrict__ flags,
                                                 int* __restrict__ flagcnt) {
  __shared__ float zs[kE];
  __shared__ float dsv[256];
  __shared__ float rv[256];
  __shared__ int ri[256];
  __shared__ int defer;
  const int i = blockIdx.x;
  const int t = threadIdx.x;
  if (t < kE) zs[t] = z[(size_t)i * kE + t];
  __syncthreads();
  float dot = 0.f, nrm = 0.f, zn = 0.f;
  const float* c = cb + (size_t)t * kE;
#pragma unroll 8
  for (int e = 0; e < kE; ++e) {
    float ce = c[e];
    float ze = zs[e];
    dot = fmaf(ze, ce, dot);
    nrm = fmaf(ce, ce, nrm);
    zn = fmaf(ze, ze, zn);
  }
  float d = nrm - 2.f * dot;
  dsv[t] = d;
  rv[t] = d;
  ri[t] = t;
  __syncthreads();
  for (int s = 128; s > 0; s >>= 1) {
    if (t < s) {
      float v2 = rv[t + s];
      int i2 = ri[t + s];
      if (v2 < rv[t] || (v2 == rv[t] && i2 < ri[t])) { rv[t] = v2; ri[t] = i2; }
    }
    __syncthreads();
  }
  const int best = ri[0];
  const float d1 = rv[0];
  __syncthreads();
  // second-best value
  rv[t] = (t == best) ? 3.4e38f : dsv[t];
  __syncthreads();
  for (int s = 128; s > 0; s >>= 1) {
    if (t < s) rv[t] = fminf(rv[t], rv[t + s]);
    __syncthreads();
  }
  if (t == 0) {
    float tau = 5e-5f * sqrtf(zn);
    if (rv[0] - d1 < tau) {
      defer = 1;
      int slot = atomicAdd(flagcnt, 1);
      flags[slot] = i;
    } else {
      defer = 0;
    }
  }
  __syncthreads();
  if (defer) return;
  if (t == 0) idx_out[i] = (float)best;
  if (t < kE) {
    float xq = cb[(size_t)best * kE + t];
    xq_out[(size_t)i * kE + t] = xq;
    xqb_out[(size_t)i * kE + t] = f2bf(xq);
    float dd = xq - zs[t];
    float sq = dd * dd;
    float nq = xq * xq;
#pragma unroll
    for (int m = 32; m > 0; m >>= 1) {
      sq += __shfl_xor(sq, m);
      nq += __shfl_xor(nq, m);
    }
    float inv = 1.f / fmaxf(sqrtf(nq), 1e-12f);
    xn_out[(size_t)i * kE + t] = xq * inv;
    if (t == 0) atomicAdd(&acc[i & 255], sq);
  }
}

// ---------------- fix phase A: h1f = relu(x[flag] @ ew0 + eb0) --------------
// Work item = (row-batch of 8, 256-column chunk). Weight element reused 8x.
__global__ __launch_bounds__(256) void fix_h1(
    const float* __restrict__ x, const float* __restrict__ ew0,
    const float* __restrict__ eb0, const int* __restrict__ flags,
    const int* __restrict__ flagcnt, float* __restrict__ h1f) {
  constexpr int R = 8, NJC = 8, JC = kH1 / NJC;  // 256 cols/chunk
  __shared__ float xs[R][kIN];
  const int t = threadIdx.x;
  int cnt = *flagcnt;
  if (cnt > kMaxFix) cnt = kMaxFix;
  const int nrb = (cnt + R - 1) / R;
  const int nwork = nrb * NJC;
  for (int w = blockIdx.x; w < nwork; w += gridDim.x) {
    const int rb = w / NJC, jc = w % NJC;
    const int nr = min(R, cnt - rb * R);
    for (int rr = 0; rr < nr; ++rr) {
      const int r = flags[rb * R + rr];
      for (int q = t; q < kIN; q += 256) xs[rr][q] = x[(size_t)r * kIN + q];
    }
    __syncthreads();
    const int j = jc * JC + t;
    float s[R];
    const float b = eb0[j];
#pragma unroll
    for (int rr = 0; rr < R; ++rr) s[rr] = b;
#pragma unroll 8
    for (int k = 0; k < kIN; ++k) {
      float wv = ew0[(size_t)k * kH1 + j];
#pragma unroll
      for (int rr = 0; rr < R; ++rr) s[rr] = fmaf(xs[rr][k], wv, s[rr]);
    }
    for (int rr = 0; rr < nr; ++rr)
      h1f[(size_t)(rb * R + rr) * kH1 + j] = fmaxf(s[rr], 0.f);
    __syncthreads();
  }
}

// ---------------- fix phase B: h2f = relu(h1f @ ew1 + eb1) ------------------
__global__ __launch_bounds__(256) void fix_h2(
    const float* __restrict__ h1f, const float* __restrict__ ew1,
    const float* __restrict__ eb1, const int* __restrict__ flagcnt,
    float* __restrict__ h2f) {
  constexpr int R = 4, NJC = 4, JC = kH2 / NJC;  // 256 cols/chunk
  __shared__ float hs[R][kH1];  // 32 KB
  const int t = threadIdx.x;
  int cnt = *flagcnt;
  if (cnt > kMaxFix) cnt = kMaxFix;
  const int nrb = (cnt + R - 1) / R;
  const int nwork = nrb * NJC;
  for (int w = blockIdx.x; w < nwork; w += gridDim.x) {
    const int rb = w / NJC, jc = w % NJC;
    const int nr = min(R, cnt - rb * R);
    for (int rr = 0; rr < nr; ++rr)
      for (int q = t; q < kH1; q += 256)
        hs[rr][q] = h1f[(size_t)(rb * R + rr) * kH1 + q];
    __syncthreads();
    const int j = jc * JC + t;
    float s[R];
    const float b = eb1[j];
#pragma unroll
    for (int rr = 0; rr < R; ++rr) s[rr] = b;
#pragma unroll 8
    for (int k = 0; k < kH1; ++k) {
      float wv = ew1[(size_t)k * kH2 + j];
#pragma unroll
      for (int rr = 0; rr < R; ++rr) s[rr] = fmaf(hs[rr][k], wv, s[rr]);
    }
    for (int rr = 0; rr < nr; ++rr)
      h2f[(size_t)(rb * R + rr) * kH2 + j] = fmaxf(s[rr], 0.f);
    __syncthreads();
  }
}

// ---------------- fix phase C: z + argmin + outputs (1 block / row) ---------
__global__ __launch_bounds__(256) void fix_z(
    const float* __restrict__ h2f, const float* __restrict__ ew2,
    const float* __restrict__ eb2, const float* __restrict__ cb,
    const int* __restrict__ flags, const int* __restrict__ flagcnt,
    float* __restrict__ z, float* __restrict__ idx_out,
    float* __restrict__ xq_out, unsigned short* __restrict__ xqb_out,
    float* __restrict__ xn_out, float* __restrict__ acc) {
  __shared__ float hrow[kH2];
  __shared__ float sred[256];
  __shared__ float szs[kE];
  __shared__ float rv[256];
  __shared__ int ri[256];
  const int t = threadIdx.x;
  int cnt = *flagcnt;
  if (cnt > kMaxFix) cnt = kMaxFix;
  for (int fi = blockIdx.x; fi < cnt; fi += gridDim.x) {
    const int r = flags[fi];
    for (int q = t; q < kH2; q += 256) hrow[q] = h2f[(size_t)fi * kH2 + q];
    __syncthreads();
    // z: 64 outputs, 4 partial threads each (same order as old fix_rows)
    {
      const int j = t & 63, p = t >> 6;
      float s = 0.f;
      for (int k = p * 256; k < p * 256 + 256; ++k)
        s = fmaf(hrow[k], ew2[(size_t)k * kE + j], s);
      sred[t] = s;
      __syncthreads();
      if (t < kE) {
        float zv = sred[t] + sred[t + 64] + sred[t + 128] + sred[t + 192] + eb2[t];
        szs[t] = zv;
        z[(size_t)r * kE + t] = zv;
      }
      __syncthreads();
    }
    // argmin over codes
    {
      float dot = 0.f, nrm = 0.f;
      const float* c = cb + (size_t)t * kE;
#pragma unroll 8
      for (int e = 0; e < kE; ++e) {
        float ce = c[e];
        dot = fmaf(szs[e], ce, dot);
        nrm = fmaf(ce, ce, nrm);
      }
      rv[t] = nrm - 2.f * dot;
      ri[t] = t;
      __syncthreads();
      for (int s = 128; s > 0; s >>= 1) {
        if (t < s) {
          float v2 = rv[t + s];
          int i2 = ri[t + s];
          if (v2 < rv[t] || (v2 == rv[t] && i2 < ri[t])) { rv[t] = v2; ri[t] = i2; }
        }
        __syncthreads();
      }
      const int best = ri[0];
      if (t == 0) idx_out[r] = (float)best;
      if (t < kE) {
        float xq = cb[(size_t)best * kE + t];
        xq_out[(size_t)r * kE + t] = xq;
        xqb_out[(size_t)r * kE + t] = f2bf(xq);
        float dd = xq - szs[t];
        float sq = dd * dd;
        float nq = xq * xq;
#pragma unroll
        for (int m = 32; m > 0; m >>= 1) {
          sq += __shfl_xor(sq, m);
          nq += __shfl_xor(nq, m);
        }
        float inv = 1.f / fmaxf(sqrtf(nq), 1e-12f);
        xn_out[(size_t)r * kE + t] = xq * inv;
        if (t == 0) atomicAdd(&acc[r & 255], sq);
      }
      __syncthreads();
    }
  }
}

// ---------------- fallback: exact fp32 MLP for rows >= kMaxFix --------------
__global__ __launch_bounds__(256) void fix_rows(
    const float* __restrict__ x, const float* __restrict__ ew0,
    const float* __restrict__ eb0, const float* __restrict__ ew1,
    const float* __restrict__ eb1, const float* __restrict__ ew2,
    const float* __restrict__ eb2, const float* __restrict__ cb,
    const int* __restrict__ flags, const int* __restrict__ flagcnt,
    float* __restrict__ z, float* __restrict__ idx_out,
    float* __restrict__ xq_out, unsigned short* __restrict__ xqb_out,
    float* __restrict__ xn_out, float* __restrict__ acc) {
  __shared__ float xs[kIN];
  __shared__ float sh1[kH1];
  __shared__ float sh2[kH2];
  __shared__ float sred[256];
  __shared__ float szs[kE];
  __shared__ float rv[256];
  __shared__ int ri[256];
  const int t = threadIdx.x;
  const int cnt = *flagcnt;
  for (int fi = kMaxFix + blockIdx.x; fi < cnt; fi += gridDim.x) {
    const int r = flags[fi];
    for (int q = t; q < kIN; q += 256) xs[q] = x[(size_t)r * kIN + q];
    __syncthreads();
#pragma unroll
    for (int o = 0; o < kH1 / 256; ++o) {
      int j = t + 256 * o;
      float s = eb0[j];
      for (int k = 0; k < kIN; ++k) s = fmaf(xs[k], ew0[(size_t)k * kH1 + j], s);
      sh1[j] = fmaxf(s, 0.f);
    }
    __syncthreads();
#pragma unroll
    for (int o = 0; o < kH2 / 256; ++o) {
      int j = t + 256 * o;
      float s = eb1[j];
      for (int k = 0; k < kH1; ++k) s = fmaf(sh1[k], ew1[(size_t)k * kH2 + j], s);
      sh2[j] = fmaxf(s, 0.f);
    }
    __syncthreads();
    {
      int j = t & 63, p = t >> 6;
      float s = 0.f;
      for (int k = p * 256; k < p * 256 + 256; ++k)
        s = fmaf(sh2[k], ew2[(size_t)k * kE + j], s);
      sred[t] = s;
      __syncthreads();
      if (t < kE) {
        float zv = sred[t] + sred[t + 64] + sred[t + 128] + sred[t + 192] + eb2[t];
        szs[t] = zv;
        z[(size_t)r * kE + t] = zv;
      }
      __syncthreads();
    }
    {
      float dot = 0.f, nrm = 0.f;
      const float* c = cb + (size_t)t * kE;
#pragma unroll 8
      for (int e = 0; e < kE; ++e) {
        float ce = c[e];
        dot = fmaf(szs[e], ce, dot);
        nrm = fmaf(ce, ce, nrm);
      }
      rv[t] = nrm - 2.f * dot;
      ri[t] = t;
      __syncthreads();
      for (int s = 128; s > 0; s >>= 1) {
        if (t < s) {
          float v2 = rv[t + s];
          int i2 = ri[t + s];
          if (v2 < rv[t] || (v2 == rv[t] && i2 < ri[t])) { rv[t] = v2; ri[t] = i2; }
        }
        __syncthreads();
      }
      const int best = ri[0];
      if (t == 0) idx_out[r] = (float)best;
      if (t < kE) {
        float xq = cb[(size_t)best * kE + t];
        xq_out[(size_t)r * kE + t] = xq;
        xqb_out[(size_t)r * kE + t] = f2bf(xq);
        float dd = xq - szs[t];
        float sq = dd * dd;
        float nq = xq * xq;
#pragma unroll
        for (int m = 32; m > 0; m >>= 1) {
          sq += __shfl_xor(sq, m);
          nq += __shfl_xor(nq, m);
        }
        float inv = 1.f / fmaxf(sqrtf(nq), 1e-12f);
        xn_out[(size_t)r * kE + t] = xq * inv;
        if (t == 0) atomicAdd(&acc[r & 255], sq);
      }
      __syncthreads();
    }
  }
}

// ---------------- qd_align ----------------
__global__ __launch_bounds__(256) void qd_kernel(const float* __restrict__ z,
                                                 const float* __restrict__ qz,
                                                 const float* __restrict__ w,
                                                 float* __restrict__ acc) {
  const int i = blockIdx.x * 4 + (threadIdx.x >> 6);
  const int l = threadIdx.x & 63;
  float a = z[(size_t)i * kE + l];
  float b = qz[(size_t)i * kE + l];
  float dot = a * b, na = a * a, nb = b * b;
#pragma unroll
  for (int m = 32; m > 0; m >>= 1) {
    dot += __shfl_xor(dot, m);
    na += __shfl_xor(na, m);
    nb += __shfl_xor(nb, m);
  }
  if (l == 0) {
    float cosv = dot / fmaxf(sqrtf(na) * sqrtf(nb), 1e-8f);
    atomicAdd(&acc[i & 255], w[i] * cosv);
  }
}

// ---------------- triplet ----------------
__global__ __launch_bounds__(256) void trip_kernel(const float* __restrict__ z,
                                                   const int* __restrict__ tr,
                                                   float* __restrict__ acc) {
  const int t = blockIdx.x * 4 + (threadIdx.x >> 6);
  const int l = threadIdx.x & 63;
  int ia = tr[3 * t], ip = tr[3 * t + 1], in2 = tr[3 * t + 2];
  float a = z[(size_t)ia * kE + l];
  float p = z[(size_t)ip * kE + l];
  float n = z[(size_t)in2 * kE + l];
  float d1 = (a - p) * (a - p);
  float d2 = (a - n) * (a - n);
#pragma unroll
  for (int m = 32; m > 0; m >>= 1) {
    d1 += __shfl_xor(d1, m);
    d2 += __shfl_xor(d2, m);
  }
  if (l == 0) {
    float dp = sqrtf(d1 + 1e-12f);
    float dn = sqrtf(d2 + 1e-12f);
    atomicAdd(&acc[t & 255], fmaxf(dp - dn + 0.2f, 0.f));
  }
}

// ---------------- pairs: subtract positive sim ----------------
__global__ __launch_bounds__(256) void pos_kernel(const float* __restrict__ xn,
                                                  const int* __restrict__ pairs,
                                                  float* __restrict__ acc) {
  const int k = blockIdx.x * 4 + (threadIdx.x >> 6);
  const int l = threadIdx.x & 63;
  int i0 = pairs[2 * k], i1 = pairs[2 * k + 1];
  float v = xn[(size_t)i0 * kE + l] * xn[(size_t)i1 * kE + l];
#pragma unroll
  for (int m = 32; m > 0; m >>= 1) v += __shfl_xor(v, m);
  if (l == 0) atomicAdd(&acc[k & 255], -10.f * v);
}

// ---------------- code-space LSE ----------------
// Every xn row is a normalized codebook entry, so
//   sum_j exp(10 * <xn[a_p], xn[j]>) = sum_c count[c] * exp(10 * G[code(a_p)][c])
// with G = cbn @ cbn^T (256x256). Histogram + tiny dot table replace the
// 4096x32768 fp32 GEMM (was 370 us).

// histogram of final idx over all N rows
__global__ __launch_bounds__(256) void hist_kernel(const float* __restrict__ idx_out,
                                                   int* __restrict__ cnt) {
  __shared__ int h[kNE];
  const int t = threadIdx.x;
  h[t] = 0;
  __syncthreads();
  int i = blockIdx.x * 256 + t;
  atomicAdd(&h[(int)idx_out[i]], 1);
  __syncthreads();
  if (h[t]) atomicAdd(&cnt[t], h[t]);
}

// E[a] = sum_c cnt[c] * exp(10 * <cbn[a], cbn[c]>); one block per code a
__global__ __launch_bounds__(256) void code_lse(const float* __restrict__ cb,
                                                const int* __restrict__ cnt,
                                                float* __restrict__ E) {
  __shared__ float cbn[kNE][kE + 1];  // +1 pad: avoid 32-way bank conflict
  __shared__ float red[256];
  const int t = threadIdx.x, a = blockIdx.x;
  // normalize row t of the codebook into LDS
  const float* r = cb + (size_t)t * kE;
  float s = 0.f;
#pragma unroll 8
  for (int e = 0; e < kE; ++e) s = fmaf(r[e], r[e], s);
  float inv = 1.f / fmaxf(sqrtf(s), 1e-12f);
#pragma unroll 8
  for (int e = 0; e < kE; ++e) cbn[t][e] = r[e] * inv;
  __syncthreads();
  float dot = 0.f;
#pragma unroll 8
  for (int e = 0; e < kE; ++e) dot = fmaf(cbn[a][e], cbn[t][e], dot);
  red[t] = (float)cnt[t] * expf(10.f * dot);
  __syncthreads();
  for (int sred = 128; sred > 0; sred >>= 1) {
    if (t < sred) red[t] += red[t + sred];
    __syncthreads();
  }
  if (t == 0) E[a] = red[0];
}

// acc += log(E[code(anchor_p)]) for each pair
__global__ __launch_bounds__(256) void pair_log(const float* __restrict__ idx_out,
                                                const int* __restrict__ pairs,
                                                const float* __restrict__ E,
                                                float* __restrict__ acc) {
  int p = blockIdx.x * 256 + threadIdx.x;
  int a = (int)idx_out[pairs[2 * p]];
  atomicAdd(&acc[p & 255], logf(E[a]));
}

// ---------------- finalize scalars ----------------
__global__ __launch_bounds__(256) void finalize_kernel(const float* __restrict__ acc,
                                                       float* __restrict__ out) {
  const int t = threadIdx.x;
  float vq = acc[t], qd = acc[256 + t], tr = acc[512 + t], ou = acc[768 + t];
#pragma unroll
  for (int m = 32; m > 0; m >>= 1) {
    vq += __shfl_xor(vq, m);
    qd += __shfl_xor(qd, m);
    tr += __shfl_xor(tr, m);
    ou += __shfl_xor(ou, m);
  }
  __shared__ float sm[4][4];
  const int w = t >> 6;
  if ((t & 63) == 0) { sm[0][w] = vq; sm[1][w] = qd; sm[2][w] = tr; sm[3][w] = ou; }
  __syncthreads();
  if (t == 0) {
    float svq = sm[0][0] + sm[0][1] + sm[0][2] + sm[0][3];
    float sqd = sm[1][0] + sm[1][1] + sm[1][2] + sm[1][3];
    float str = sm[2][0] + sm[2][1] + sm[2][2] + sm[2][3];
    float sou = sm[3][0] + sm[3][1] + sm[3][2] + sm[3][3];
    out[OFF_VQ]  = 1.001f * svq / (float)((size_t)kN * kE);
    out[OFF_OCL] = sou / (float)kKP;
    out[OFF_ITL] = str / (float)kTT;
    out[OFF_QDA] = 1.f - sqd / (float)kN;
  }
}

// ---------------- orchestration ----------------
extern "C" void kernel_launch(void* const* d_in, const int* in_sizes, int n_in,
                              void* d_out, int out_size, void* d_ws, size_t ws_size,
                              hipStream_t stream) {
  (void)in_sizes; (void)n_in; (void)out_size; (void)ws_size;
  const float* x    = (const float*)d_in[0];
  const float* qe   = (const float*)d_in[1];
  const float* qdw  = (const float*)d_in[2];
  const int*   prs  = (const int*)d_in[3];
  const int*   trs  = (const int*)d_in[4];
  const float* ew0  = (const float*)d_in[5];
  const float* eb0  = (const float*)d_in[6];
  const float* ew1  = (const float*)d_in[7];
  const float* eb1  = (const float*)d_in[8];
  const float* ew2  = (const float*)d_in[9];
  const float* eb2  = (const float*)d_in[10];
  const float* dw0  = (const float*)d_in[11];
  const float* db0  = (const float*)d_in[12];
  const float* dw1  = (const float*)d_in[13];
  const float* db1  = (const float*)d_in[14];
  const float* dw2  = (const float*)d_in[15];
  const float* db2  = (const float*)d_in[16];
  const float* cb   = (const float*)d_in[17];
  float* out = (float*)d_out;

  // ---- workspace carve-up (~114 MB) ----
  float* z   = (float*)d_ws;                         // N x E fp32
  float* qz  = z  + (size_t)kN * kE;
  float* xn  = qz + (size_t)kN * kE;
  float* acc = xn + (size_t)kN * kE;                 // 1024
  float* pairsum = acc + 1024;                       // 4096 (cnt + E live here)
  int*   flagcnt = (int*)(pairsum + 4096);           // 64 (1 used)
  int*   flags   = flagcnt + 64;                     // kN ints
  unsigned short* xqb  = (unsigned short*)(flags + kN);     // N x E bf16
  unsigned short* wt0h = xqb  + (size_t)kN * kE;     // enc w0^T hi 2048x768
  unsigned short* wt0l = wt0h + (size_t)kH1 * kIN;
  unsigned short* wt1h = wt0l + (size_t)kH1 * kIN;   // 1024x2048
  unsigned short* wt1l = wt1h + (size_t)kH2 * kH1;
  unsigned short* wt2h = wt1l + (size_t)kH2 * kH1;   // 64x1024
  unsigned short* wt2l = wt2h + (size_t)kE * kH2;
  unsigned short* wt3  = wt2l + (size_t)kE * kH2;    // dec w0^T 1024x64
  unsigned short* wt4  = wt3  + (size_t)kH2 * kE;    // dec w1^T 2048x1024
  unsigned short* wt5  = wt4  + (size_t)kH1 * kH2;   // dec w2^T 768x2048
  // chunk scratch (union across phases), 4096-row chunks
  unsigned short* xh  = wt5 + (size_t)kIN * kH1;     // 4096x768
  unsigned short* xl  = xh + (size_t)kCh * kIN;
  unsigned short* h1h = xl + (size_t)kCh * kIN;      // 4096x2048
  unsigned short* h1l = h1h + (size_t)kCh * kH1;
  unsigned short* h2h = h1l + (size_t)kCh * kH1;     // 4096x1024
  unsigned short* h2l = h2h + (size_t)kCh * kH2;
  // fix-chain scratch: aliases chunk scratch (dead between x-enc and decoder).
  float* h1f = (float*)xh;
  float* h2f = h1f + (size_t)kMaxFix * kH1;
  // code-LSE scratch: cnt + E carved from the (zeroed) pairsum region
  int*   cnt = (int*)pairsum;          // 256 ints
  float* E   = pairsum + 256;          // 256 floats

  hipMemsetAsync(acc, 0, (1024 + 4096 + 64) * sizeof(float), stream);

  // weight transposes: encoder split, decoder single
  transpose_bf16_split<<<dim3(kH1 / 32, kIN / 32), 256, 0, stream>>>(ew0, wt0h, wt0l, kIN, kH1);
  transpose_bf16_split<<<dim3(kH2 / 32, kH1 / 32), 256, 0, stream>>>(ew1, wt1h, wt1l, kH1, kH2);
  transpose_bf16_split<<<dim3(kE / 32, kH2 / 32), 256, 0, stream>>>(ew2, wt2h, wt2l, kH2, kE);
  transpose_bf16<<<dim3(kH2 / 32, kE / 32), 256, 0, stream>>>(dw0, wt3, kE, kH2);
  transpose_bf16<<<dim3(kH1 / 32, kH2 / 32), 256, 0, stream>>>(dw1, wt4, kH2, kH1);
  transpose_bf16<<<dim3(kIN / 32, kH1 / 32), 256, 0, stream>>>(dw2, wt5, kH1, kIN);

  // x-encoder (split-bf16 MFMA) -> z fp32
  for (int c = 0; c < kN / kCh; ++c) {
    conv_split<<<(kCh * kIN / 4 + 255) / 256, 256, 0, stream>>>(
        x + (size_t)c * kCh * kIN, xh, xl, kCh * kIN / 4);
    gemm_bt_split<128, 128, 64, true, 2>
        <<<dim3(kH1 / 128, kCh / 128), 256, 0, stream>>>(
            xh, xl, wt0h, wt0l, eb0, nullptr, h1h, h1l, kH1, kIN);
    gemm_bt_split<128, 128, 64, true, 2>
        <<<dim3(kH2 / 128, kCh / 128), 256, 0, stream>>>(
            h1h, h1l, wt1h, wt1l, eb1, nullptr, h2h, h2l, kH2, kH1);
    gemm_bt_split<128, 64, 64, false, 0>
        <<<dim3(kE / 64, kCh / 128), 256, 0, stream>>>(
            h2h, h2l, wt2h, wt2l, eb2, z + (size_t)c * kCh * kE, nullptr, nullptr,
            kE, kH2);
  }

  // VQ with gap-flagging, then exact fp32 fix for flagged rows
  vq_kernel<<<kN, 256, 0, stream>>>(z, cb, out + OFF_IDX, out + OFF_XQ, xqb, xn,
                                    acc, flags, flagcnt);
  fix_h1<<<512, 256, 0, stream>>>(x, ew0, eb0, flags, flagcnt, h1f);
  fix_h2<<<512, 256, 0, stream>>>(h1f, ew1, eb1, flagcnt, h2f);
  fix_z<<<512, 256, 0, stream>>>(h2f, ew2, eb2, cb, flags, flagcnt, z,
                                 out + OFF_IDX, out + OFF_XQ, xqb, xn, acc);
  // fallback for pathological flag counts (> kMaxFix); no-op otherwise
  fix_rows<<<64, 256, 0, stream>>>(x, ew0, eb0, ew1, eb1, ew2, eb2, cb, flags,
                                   flagcnt, z, out + OFF_IDX, out + OFF_XQ, xqb,
                                   xn, acc);

  // decoder (bf16 MFMA) on x_q_st -> out
  for (int c = 0; c < kN / kCh; ++c) {
    gemm_bt<128, 128, 64, true, false, true>
        <<<dim3(kH2 / 128, kCh / 128), 256, 0, stream>>>(
            xqb + (size_t)c * kCh * kE, wt3, db0, nullptr, h2h, kH2, kE);
    gemm_bt<128, 128, 64, true, false, true>
        <<<dim3(kH1 / 128, kCh / 128), 256, 0, stream>>>(
            h2h, wt4, db1, nullptr, h1h, kH1, kH2);
    gemm_bt<128, 128, 64, false, true, false>
        <<<dim3(kIN / 128, kCh / 128), 256, 0, stream>>>(
            h1h, wt5, db2, out + OFF_OUT + (size_t)c * kCh * kIN, nullptr, kIN, kH1);
  }

  // q-encoder (bf16 MFMA) -> qz
  for (int c = 0; c < kN / kCh; ++c) {
    conv_bf16<<<(kCh * kIN / 4 + 255) / 256, 256, 0, stream>>>(
        qe + (size_t)c * kCh * kIN, xh, kCh * kIN / 4);
    gemm_bt<128, 128, 64, true, false, true>
        <<<dim3(kH1 / 128, kCh / 128), 256, 0, stream>>>(
            xh, wt0h, eb0, nullptr, h1h, kH1, kIN);
    gemm_bt<128, 128, 64, true, false, true>
        <<<dim3(kH2 / 128, kCh / 128), 256, 0, stream>>>(
            h1h, wt1h, eb1, nullptr, h2h, kH2, kH1);
    gemm_bt<128, 64, 64, false, true, false>
        <<<dim3(kE / 64, kCh / 128), 256, 0, stream>>>(
            h2h, wt2h, eb2, qz + (size_t)c * kCh * kE, nullptr, kE, kH2);
  }

  // small loss kernels (all after fix chain: z/xn/idx final)
  qd_kernel<<<kN / 4, 256, 0, stream>>>(z, qz, qdw, acc + 256);
  trip_kernel<<<kTT / 4, 256, 0, stream>>>(z, trs, acc + 512);
  pos_kernel<<<kKP / 4, 256, 0, stream>>>(xn, prs, acc + 768);
  // code-space LSE: histogram -> 256x256 exp table -> per-pair log
  hist_kernel<<<kN / 256, 256, 0, stream>>>(out + OFF_IDX, cnt);
  code_lse<<<kNE, 256, 0, stream>>>(cb, cnt, E);
  pair_log<<<kKP / 256, 256, 0, stream>>>(out + OFF_IDX, prs, E, acc + 768);

  finalize_kernel<<<1, 256, 0, stream>>>(acc, out);
}

// Round 3
// 2988.015 us; speedup vs baseline: 1.2143x; 1.0291x over previous
//
#include <hip/hip_runtime.h>
#include <hip/hip_bf16.h>

// ---------------- problem constants ----------------
namespace {
constexpr int kN = 32768, kIN = 768, kH1 = 2048, kH2 = 1024, kE = 64, kNE = 256;
constexpr int kKP = 4096, kTT = 8192;
constexpr int kCh = 4096;  // rows per GEMM slice
constexpr int kMaxFix = 4096;  // rows handled by the fast fix chain

// flat float32 offsets in d_out, reference return order
constexpr size_t OFF_OUT = 0;
constexpr size_t OFF_VQ  = (size_t)kN * kIN;
constexpr size_t OFF_IDX = OFF_VQ + 1;
constexpr size_t OFF_XQ  = OFF_IDX + (size_t)kN;
constexpr size_t OFF_OCL = OFF_XQ + (size_t)kN * kE;
constexpr size_t OFF_ITL = OFF_OCL + 1;
constexpr size_t OFF_QDA = OFF_ITL + 1;
}  // namespace

typedef short bf16x8 __attribute__((ext_vector_type(8)));
typedef float f32x4 __attribute__((ext_vector_type(4)));

__device__ __forceinline__ unsigned short f2bf(float v) {
  __hip_bfloat16 h = __float2bfloat16(v);
  return *reinterpret_cast<unsigned short*>(&h);
}
__device__ __forceinline__ float bf2f(unsigned short u) {
  __hip_bfloat16 h = *reinterpret_cast<__hip_bfloat16*>(&u);
  return __bfloat162float(h);
}

__device__ __forceinline__ void gload_lds16(const void* g, void* lds) {
  __builtin_amdgcn_global_load_lds(
      (const __attribute__((address_space(1))) void*)g,
      (__attribute__((address_space(3))) void*)lds, 16, 0, 0);
}

// ---------------- bf16 MFMA GEMM: C = relu?(A @ Bt^T + bias) ----------------
// A: MxK bf16 row-major. Bt: NxK bf16 row-major. 4 waves in 2x2; 16x16x32 MFMA.
template <int BM, int BN, int BK, bool RELU, bool OUTF, bool OUTB>
__global__ __launch_bounds__(256) void gemm_bt(const unsigned short* __restrict__ A,
                                               const unsigned short* __restrict__ Bt,
                                               const float* __restrict__ bias,
                                               float* __restrict__ Cf,
                                               unsigned short* __restrict__ Cb,
                                               int N, int K) {
  constexpr int WM = BM / 2, WN = BN / 2, TMt = WM / 16, TNt = WN / 16;
  constexpr int CH = BK / 8;
  constexpr int RA = BM * BK / 2048, RB = BN * BK / 2048;
  __shared__ unsigned short As[BM * BK];
  __shared__ unsigned short Bs[BN * BK];
  const int tid = threadIdx.x, lane = tid & 63, wave = tid >> 6;
  const int wm = (wave >> 1) * WM, wn = (wave & 1) * WN;
  const int l15 = lane & 15, quad = lane >> 4;
  const int rowA0 = blockIdx.y * BM, colB0 = blockIdx.x * BN;
  f32x4 acc[TMt][TNt];
#pragma unroll
  for (int i = 0; i < TMt; ++i)
#pragma unroll
    for (int j = 0; j < TNt; ++j) acc[i][j] = (f32x4){0.f, 0.f, 0.f, 0.f};

  const char* Ab = (const char*)A;
  const char* Bb = (const char*)Bt;
  char* AsB = (char*)As;
  char* BsB = (char*)Bs;

  for (int k0 = 0; k0 < K; k0 += BK) {
    if (k0) __syncthreads();
#pragma unroll
    for (int r = 0; r < RA; ++r) {
      int off = (r * 256 + tid) * 16;
      int row = off / (BK * 2);
      int sc = ((off >> 4) ^ row) & (CH - 1);
      gload_lds16(Ab + (size_t)(rowA0 + row) * (K * 2) + (size_t)k0 * 2 + sc * 16,
                  AsB + off);
    }
#pragma unroll
    for (int r = 0; r < RB; ++r) {
      int off = (r * 256 + tid) * 16;
      int row = off / (BK * 2);
      int sc = ((off >> 4) ^ row) & (CH - 1);
      gload_lds16(Bb + (size_t)(colB0 + row) * (K * 2) + (size_t)k0 * 2 + sc * 16,
                  BsB + off);
    }
    __syncthreads();
#pragma unroll
    for (int ks = 0; ks < BK; ks += 32) {
      bf16x8 af[TMt], bfr[TNt];
#pragma unroll
      for (int i = 0; i < TMt; ++i) {
        int row = wm + i * 16 + l15;
        int c = (((ks >> 3) + quad) ^ row) & (CH - 1);
        af[i] = *(const bf16x8*)(AsB + row * (BK * 2) + c * 16);
      }
#pragma unroll
      for (int j = 0; j < TNt; ++j) {
        int col = wn + j * 16 + l15;
        int c = (((ks >> 3) + quad) ^ col) & (CH - 1);
        bfr[j] = *(const bf16x8*)(BsB + col * (BK * 2) + c * 16);
      }
#pragma unroll
      for (int i = 0; i < TMt; ++i)
#pragma unroll
        for (int j = 0; j < TNt; ++j)
          acc[i][j] = __builtin_amdgcn_mfma_f32_16x16x32_bf16(af[i], bfr[j],
                                                              acc[i][j], 0, 0, 0);
    }
  }
#pragma unroll
  for (int j = 0; j < TNt; ++j) {
    int col = colB0 + wn + j * 16 + l15;
    float bv = bias[col];
#pragma unroll
    for (int i = 0; i < TMt; ++i) {
      int rbase = rowA0 + wm + i * 16 + quad * 4;
#pragma unroll
      for (int r = 0; r < 4; ++r) {
        float v = acc[i][j][r] + bv;
        if (RELU) v = fmaxf(v, 0.f);
        size_t o = (size_t)(rbase + r) * N + col;
        if (OUTF) Cf[o] = v;
        if (OUTB) Cb[o] = f2bf(v);
      }
    }
  }
}

// ---------------- split-bf16 MFMA GEMM (fp32-accurate x-path) ----------------
// C = relu?((Ah+Al) @ (Bh+Bl)^T + bias), dropping Al*Bl (err ~2^-18).
// OM: 0 = write fp32 C; 2 = write split bf16 (Ch, Cl).
template <int BM, int BN, int BK, bool RELU, int OM>
__global__ __launch_bounds__(256) void gemm_bt_split(
    const unsigned short* __restrict__ Ah, const unsigned short* __restrict__ Al,
    const unsigned short* __restrict__ Bh, const unsigned short* __restrict__ Bl,
    const float* __restrict__ bias, float* __restrict__ Cf,
    unsigned short* __restrict__ Ch, unsigned short* __restrict__ Cl,
    int N, int K) {
  constexpr int WM = BM / 2, WN = BN / 2, TMt = WM / 16, TNt = WN / 16;
  constexpr int CH = BK / 8;
  constexpr int RA = BM * BK / 2048, RB = BN * BK / 2048;
  __shared__ unsigned short AsH[BM * BK];
  __shared__ unsigned short AsL[BM * BK];
  __shared__ unsigned short BsH[BN * BK];
  __shared__ unsigned short BsL[BN * BK];
  const int tid = threadIdx.x, lane = tid & 63, wave = tid >> 6;
  const int wm = (wave >> 1) * WM, wn = (wave & 1) * WN;
  const int l15 = lane & 15, quad = lane >> 4;
  const int rowA0 = blockIdx.y * BM, colB0 = blockIdx.x * BN;
  f32x4 acc[TMt][TNt];
#pragma unroll
  for (int i = 0; i < TMt; ++i)
#pragma unroll
    for (int j = 0; j < TNt; ++j) acc[i][j] = (f32x4){0.f, 0.f, 0.f, 0.f};

  const char* AhB = (const char*)Ah;
  const char* AlB = (const char*)Al;
  const char* BhB = (const char*)Bh;
  const char* BlB = (const char*)Bl;

  for (int k0 = 0; k0 < K; k0 += BK) {
    if (k0) __syncthreads();
#pragma unroll
    for (int r = 0; r < RA; ++r) {
      int off = (r * 256 + tid) * 16;
      int row = off / (BK * 2);
      int sc = ((off >> 4) ^ row) & (CH - 1);
      size_t go = (size_t)(rowA0 + row) * (K * 2) + (size_t)k0 * 2 + sc * 16;
      gload_lds16(AhB + go, (char*)AsH + off);
      gload_lds16(AlB + go, (char*)AsL + off);
    }
#pragma unroll
    for (int r = 0; r < RB; ++r) {
      int off = (r * 256 + tid) * 16;
      int row = off / (BK * 2);
      int sc = ((off >> 4) ^ row) & (CH - 1);
      size_t go = (size_t)(colB0 + row) * (K * 2) + (size_t)k0 * 2 + sc * 16;
      gload_lds16(BhB + go, (char*)BsH + off);
      gload_lds16(BlB + go, (char*)BsL + off);
    }
    __syncthreads();
#pragma unroll
    for (int ks = 0; ks < BK; ks += 32) {
      bf16x8 ah[TMt], al[TMt], bh[TNt], bl[TNt];
#pragma unroll
      for (int i = 0; i < TMt; ++i) {
        int row = wm + i * 16 + l15;
        int c = (((ks >> 3) + quad) ^ row) & (CH - 1);
        int off = row * (BK * 2) + c * 16;
        ah[i] = *(const bf16x8*)((const char*)AsH + off);
        al[i] = *(const bf16x8*)((const char*)AsL + off);
      }
#pragma unroll
      for (int j = 0; j < TNt; ++j) {
        int col = wn + j * 16 + l15;
        int c = (((ks >> 3) + quad) ^ col) & (CH - 1);
        int off = col * (BK * 2) + c * 16;
        bh[j] = *(const bf16x8*)((const char*)BsH + off);
        bl[j] = *(const bf16x8*)((const char*)BsL + off);
      }
#pragma unroll
      for (int i = 0; i < TMt; ++i)
#pragma unroll
        for (int j = 0; j < TNt; ++j) {
          acc[i][j] = __builtin_amdgcn_mfma_f32_16x16x32_bf16(ah[i], bh[j], acc[i][j], 0, 0, 0);
          acc[i][j] = __builtin_amdgcn_mfma_f32_16x16x32_bf16(ah[i], bl[j], acc[i][j], 0, 0, 0);
          acc[i][j] = __builtin_amdgcn_mfma_f32_16x16x32_bf16(al[i], bh[j], acc[i][j], 0, 0, 0);
        }
    }
  }
#pragma unroll
  for (int j = 0; j < TNt; ++j) {
    int col = colB0 + wn + j * 16 + l15;
    float bv = bias[col];
#pragma unroll
    for (int i = 0; i < TMt; ++i) {
      int rbase = rowA0 + wm + i * 16 + quad * 4;
#pragma unroll
      for (int r = 0; r < 4; ++r) {
        float v = acc[i][j][r] + bv;
        if (RELU) v = fmaxf(v, 0.f);
        size_t o = (size_t)(rbase + r) * N + col;
        if (OM == 0) {
          Cf[o] = v;
        } else {
          unsigned short hi = f2bf(v);
          Ch[o] = hi;
          Cl[o] = f2bf(v - bf2f(hi));
        }
      }
    }
  }
}

// ---------------- weight transpose fp32 KxN -> bf16 NxK (single) ------------
__global__ __launch_bounds__(256) void transpose_bf16(const float* __restrict__ W,
                                                      unsigned short* __restrict__ Wt,
                                                      int K, int N) {
  __shared__ float t[32][33];
  int bx = blockIdx.x * 32, by = blockIdx.y * 32;
  int tx = threadIdx.x & 31, ty = threadIdx.x >> 5;
#pragma unroll
  for (int i = 0; i < 32; i += 8)
    t[ty + i][tx] = W[(size_t)(by + ty + i) * N + bx + tx];
  __syncthreads();
#pragma unroll
  for (int i = 0; i < 32; i += 8)
    Wt[(size_t)(bx + ty + i) * K + by + tx] = f2bf(t[tx][ty + i]);
}

// ---------------- weight transpose fp32 KxN -> split bf16 NxK ---------------
__global__ __launch_bounds__(256) void transpose_bf16_split(
    const float* __restrict__ W, unsigned short* __restrict__ Wh,
    unsigned short* __restrict__ Wl, int K, int N) {
  __shared__ float t[32][33];
  int bx = blockIdx.x * 32, by = blockIdx.y * 32;
  int tx = threadIdx.x & 31, ty = threadIdx.x >> 5;
#pragma unroll
  for (int i = 0; i < 32; i += 8)
    t[ty + i][tx] = W[(size_t)(by + ty + i) * N + bx + tx];
  __syncthreads();
#pragma unroll
  for (int i = 0; i < 32; i += 8) {
    float v = t[tx][ty + i];
    unsigned short hi = f2bf(v);
    size_t o = (size_t)(bx + ty + i) * K + by + tx;
    Wh[o] = hi;
    Wl[o] = f2bf(v - bf2f(hi));
  }
}

// ---------------- fp32 -> bf16 convert (single) ----------------
__global__ __launch_bounds__(256) void conv_bf16(const float* __restrict__ in,
                                                 unsigned short* __restrict__ out,
                                                 int n4) {
  int i = (blockIdx.x * 256 + threadIdx.x);
  if (i < n4) {
    float4 v = *(const float4*)(in + (size_t)i * 4);
    unsigned short o[4] = {f2bf(v.x), f2bf(v.y), f2bf(v.z), f2bf(v.w)};
    *(uint2*)(out + (size_t)i * 4) = *(uint2*)o;
  }
}

// ---------------- fp32 -> split bf16 convert ----------------
__global__ __launch_bounds__(256) void conv_split(const float* __restrict__ in,
                                                  unsigned short* __restrict__ oh,
                                                  unsigned short* __restrict__ ol,
                                                  int n4) {
  int i = (blockIdx.x * 256 + threadIdx.x);
  if (i < n4) {
    float4 v = *(const float4*)(in + (size_t)i * 4);
    unsigned short h[4], l[4];
    float vv[4] = {v.x, v.y, v.z, v.w};
#pragma unroll
    for (int k = 0; k < 4; ++k) {
      h[k] = f2bf(vv[k]);
      l[k] = f2bf(vv[k] - bf2f(h[k]));
    }
    *(uint2*)(oh + (size_t)i * 4) = *(uint2*)h;
    *(uint2*)(ol + (size_t)i * 4) = *(uint2*)l;
  }
}

// ---------------- VQ: argmin over 256 codes + gap-flagging ----------------
// Restructured (R2): 512 resident blocks; codebook staged transposed in LDS
// once per block; lane l owns codes 4l..4l+3 (f32x4 LDS reads, conflict-free);
// per-wave top-2 reduction via shuffles (no __syncthreads in the row loop);
// each codebook LDS read feeds 4 rows. Same d arithmetic / tie-break / tau as
// the old kernel (zn summation order differs: butterfly vs serial — only
// fuzzes the defer threshold's last bit; both paths are valid).
#define FMA4(a, s, v)              \
  a[0] = fmaf(s, v[0], a[0]);      \
  a[1] = fmaf(s, v[1], a[1]);      \
  a[2] = fmaf(s, v[2], a[2]);      \
  a[3] = fmaf(s, v[3], a[3])

__global__ __launch_bounds__(256) void vq_kernel(const float* __restrict__ z,
                                                 const float* __restrict__ cb,
                                                 float* __restrict__ idx_out,
                                                 float* __restrict__ xq_out,
                                                 unsigned short* __restrict__ xqb_out,
                                                 float* __restrict__ xn_out,
                                                 float* __restrict__ acc,
                                                 int* __restrict__ flags,
                                                 int* __restrict__ flagcnt) {
  __shared__ float cbT[kE * kNE];  // cbT[e*256 + c] = cb[c][e]  (64 KB)
  const int t = threadIdx.x;
  // stage codebook transposed: thread t owns code row t
  {
    const f32x4* src = (const f32x4*)(cb + (size_t)t * kE);
#pragma unroll
    for (int q = 0; q < 16; ++q) {
      f32x4 v = src[q];
      cbT[(4 * q + 0) * kNE + t] = v[0];
      cbT[(4 * q + 1) * kNE + t] = v[1];
      cbT[(4 * q + 2) * kNE + t] = v[2];
      cbT[(4 * q + 3) * kNE + t] = v[3];
    }
  }
  __syncthreads();
  const int l = t & 63, wv = t >> 6;
  // per-lane code norms (codes 4l..4l+3), same fmaf order as before
  f32x4 cn = (f32x4){0.f, 0.f, 0.f, 0.f};
  for (int e = 0; e < kE; ++e) {
    f32x4 cv = *(const f32x4*)&cbT[e * kNE + 4 * l];
    cn[0] = fmaf(cv[0], cv[0], cn[0]);
    cn[1] = fmaf(cv[1], cv[1], cn[1]);
    cn[2] = fmaf(cv[2], cv[2], cn[2]);
    cn[3] = fmaf(cv[3], cv[3], cn[3]);
  }
  const int rowBase = (blockIdx.x * 4 + wv) * 16;  // 512 blocks * 4 waves * 16 rows = 32768
  for (int p = 0; p < 4; ++p) {
    const int ra = rowBase + p * 4;
    f32x4 dt[4];
#pragma unroll
    for (int r = 0; r < 4; ++r) dt[r] = (f32x4){0.f, 0.f, 0.f, 0.f};
#pragma unroll
    for (int e4 = 0; e4 < 16; ++e4) {
      f32x4 c0 = *(const f32x4*)&cbT[(4 * e4 + 0) * kNE + 4 * l];
      f32x4 c1 = *(const f32x4*)&cbT[(4 * e4 + 1) * kNE + 4 * l];
      f32x4 c2 = *(const f32x4*)&cbT[(4 * e4 + 2) * kNE + 4 * l];
      f32x4 c3 = *(const f32x4*)&cbT[(4 * e4 + 3) * kNE + 4 * l];
#pragma unroll
      for (int r = 0; r < 4; ++r) {
        f32x4 zv = *(const f32x4*)(z + (size_t)(ra + r) * kE + e4 * 4);
        FMA4(dt[r], zv[0], c0);
        FMA4(dt[r], zv[1], c1);
        FMA4(dt[r], zv[2], c2);
        FMA4(dt[r], zv[3], c3);
      }
    }
#pragma unroll
    for (int r = 0; r < 4; ++r) {
      const int row = ra + r;
      // d = nrm - 2*dot, codes 4l..4l+3
      float d0 = cn[0] - 2.f * dt[r][0];
      float d1 = cn[1] - 2.f * dt[r][1];
      float d2 = cn[2] - 2.f * dt[r][2];
      float d3 = cn[3] - 2.f * dt[r][3];
      // lane-local top-2 (ascending index order; strict < keeps lowest idx)
      float m1 = d0, m2 = 3.4e38f;
      int i1 = 4 * l;
      if (d1 < m1) { m2 = m1; m1 = d1; i1 = 4 * l + 1; } else m2 = fminf(m2, d1);
      if (d2 < m1) { m2 = m1; m1 = d2; i1 = 4 * l + 2; } else m2 = fminf(m2, d2);
      if (d3 < m1) { m2 = m1; m1 = d3; i1 = 4 * l + 3; } else m2 = fminf(m2, d3);
      // cross-lane top-2 butterfly (all lanes converge)
#pragma unroll
      for (int m = 32; m > 0; m >>= 1) {
        float om1 = __shfl_xor(m1, m);
        int oi1 = __shfl_xor(i1, m);
        float om2 = __shfl_xor(m2, m);
        float nm2 = fminf(fminf(m2, om2), fmaxf(m1, om1));
        if (om1 < m1 || (om1 == m1 && oi1 < i1)) { m1 = om1; i1 = oi1; }
        m2 = nm2;
      }
      // zn for tau
      float zl = z[(size_t)row * kE + l];
      float zn = zl * zl;
#pragma unroll
      for (int m = 32; m > 0; m >>= 1) zn += __shfl_xor(zn, m);
      float tau = 5e-5f * sqrtf(zn);
      if (m2 - m1 < tau) {
        if (l == 0) {
          int slot = atomicAdd(flagcnt, 1);
          flags[slot] = row;
        }
        continue;
      }
      const int best = i1;
      if (l == 0) idx_out[row] = (float)best;
      float xq = cb[(size_t)best * kE + l];
      xq_out[(size_t)row * kE + l] = xq;
      xqb_out[(size_t)row * kE + l] = f2bf(xq);
      float dd = xq - zl;
      float sq = dd * dd;
      float nq = xq * xq;
#pragma unroll
      for (int m = 32; m > 0; m >>= 1) {
        sq += __shfl_xor(sq, m);
        nq += __shfl_xor(nq, m);
      }
      float inv = 1.f / fmaxf(sqrtf(nq), 1e-12f);
      xn_out[(size_t)row * kE + l] = xq * inv;
      if (l == 0) atomicAdd(&acc[row & 255], sq);
    }
  }
}
#undef FMA4

// ---------------- fix phase A: h1f = relu(x[flag] @ ew0 + eb0) --------------
// Work item = (row-batch of 8, 256-column chunk). Weight element reused 8x.
__global__ __launch_bounds__(256) void fix_h1(
    const float* __restrict__ x, const float* __restrict__ ew0,
    const float* __restrict__ eb0, const int* __restrict__ flags,
    const int* __restrict__ flagcnt, float* __restrict__ h1f) {
  constexpr int R = 8, NJC = 8, JC = kH1 / NJC;  // 256 cols/chunk
  __shared__ float xs[R][kIN];
  const int t = threadIdx.x;
  int cnt = *flagcnt;
  if (cnt > kMaxFix) cnt = kMaxFix;
  const int nrb = (cnt + R - 1) / R;
  const int nwork = nrb * NJC;
  for (int w = blockIdx.x; w < nwork; w += gridDim.x) {
    const int rb = w / NJC, jc = w % NJC;
    const int nr = min(R, cnt - rb * R);
    for (int rr = 0; rr < nr; ++rr) {
      const int r = flags[rb * R + rr];
      for (int q = t; q < kIN; q += 256) xs[rr][q] = x[(size_t)r * kIN + q];
    }
    __syncthreads();
    const int j = jc * JC + t;
    float s[R];
    const float b = eb0[j];
#pragma unroll
    for (int rr = 0; rr < R; ++rr) s[rr] = b;
#pragma unroll 8
    for (int k = 0; k < kIN; ++k) {
      float wv = ew0[(size_t)k * kH1 + j];
#pragma unroll
      for (int rr = 0; rr < R; ++rr) s[rr] = fmaf(xs[rr][k], wv, s[rr]);
    }
    for (int rr = 0; rr < nr; ++rr)
      h1f[(size_t)(rb * R + rr) * kH1 + j] = fmaxf(s[rr], 0.f);
    __syncthreads();
  }
}

// ---------------- fix phase B: h2f = relu(h1f @ ew1 + eb1) ------------------
__global__ __launch_bounds__(256) void fix_h2(
    const float* __restrict__ h1f, const float* __restrict__ ew1,
    const float* __restrict__ eb1, const int* __restrict__ flagcnt,
    float* __restrict__ h2f) {
  constexpr int R = 4, NJC = 4, JC = kH2 / NJC;  // 256 cols/chunk
  __shared__ float hs[R][kH1];  // 32 KB
  const int t = threadIdx.x;
  int cnt = *flagcnt;
  if (cnt > kMaxFix) cnt = kMaxFix;
  const int nrb = (cnt + R - 1) / R;
  const int nwork = nrb * NJC;
  for (int w = blockIdx.x; w < nwork; w += gridDim.x) {
    const int rb = w / NJC, jc = w % NJC;
    const int nr = min(R, cnt - rb * R);
    for (int rr = 0; rr < nr; ++rr)
      for (int q = t; q < kH1; q += 256)
        hs[rr][q] = h1f[(size_t)(rb * R + rr) * kH1 + q];
    __syncthreads();
    const int j = jc * JC + t;
    float s[R];
    const float b = eb1[j];
#pragma unroll
    for (int rr = 0; rr < R; ++rr) s[rr] = b;
#pragma unroll 8
    for (int k = 0; k < kH1; ++k) {
      float wv = ew1[(size_t)k * kH2 + j];
#pragma unroll
      for (int rr = 0; rr < R; ++rr) s[rr] = fmaf(hs[rr][k], wv, s[rr]);
    }
    for (int rr = 0; rr < nr; ++rr)
      h2f[(size_t)(rb * R + rr) * kH2 + j] = fmaxf(s[rr], 0.f);
    __syncthreads();
  }
}

// ---------------- fix phase C: z + argmin + outputs (1 block / row) ---------
__global__ __launch_bounds__(256) void fix_z(
    const float* __restrict__ h2f, const float* __restrict__ ew2,
    const float* __restrict__ eb2, const float* __restrict__ cb,
    const int* __restrict__ flags, const int* __restrict__ flagcnt,
    float* __restrict__ z, float* __restrict__ idx_out,
    float* __restrict__ xq_out, unsigned short* __restrict__ xqb_out,
    float* __restrict__ xn_out, float* __restrict__ acc) {
  __shared__ float hrow[kH2];
  __shared__ float sred[256];
  __shared__ float szs[kE];
  __shared__ float rv[256];
  __shared__ int ri[256];
  const int t = threadIdx.x;
  int cnt = *flagcnt;
  if (cnt > kMaxFix) cnt = kMaxFix;
  for (int fi = blockIdx.x; fi < cnt; fi += gridDim.x) {
    const int r = flags[fi];
    for (int q = t; q < kH2; q += 256) hrow[q] = h2f[(size_t)fi * kH2 + q];
    __syncthreads();
    // z: 64 outputs, 4 partial threads each (same order as old fix_rows)
    {
      const int j = t & 63, p = t >> 6;
      float s = 0.f;
      for (int k = p * 256; k < p * 256 + 256; ++k)
        s = fmaf(hrow[k], ew2[(size_t)k * kE + j], s);
      sred[t] = s;
      __syncthreads();
      if (t < kE) {
        float zv = sred[t] + sred[t + 64] + sred[t + 128] + sred[t + 192] + eb2[t];
        szs[t] = zv;
        z[(size_t)r * kE + t] = zv;
      }
      __syncthreads();
    }
    // argmin over codes
    {
      float dot = 0.f, nrm = 0.f;
      const float* c = cb + (size_t)t * kE;
#pragma unroll 8
      for (int e = 0; e < kE; ++e) {
        float ce = c[e];
        dot = fmaf(szs[e], ce, dot);
        nrm = fmaf(ce, ce, nrm);
      }
      rv[t] = nrm - 2.f * dot;
      ri[t] = t;
      __syncthreads();
      for (int s = 128; s > 0; s >>= 1) {
        if (t < s) {
          float v2 = rv[t + s];
          int i2 = ri[t + s];
          if (v2 < rv[t] || (v2 == rv[t] && i2 < ri[t])) { rv[t] = v2; ri[t] = i2; }
        }
        __syncthreads();
      }
      const int best = ri[0];
      if (t == 0) idx_out[r] = (float)best;
      if (t < kE) {
        float xq = cb[(size_t)best * kE + t];
        xq_out[(size_t)r * kE + t] = xq;
        xqb_out[(size_t)r * kE + t] = f2bf(xq);
        float dd = xq - szs[t];
        float sq = dd * dd;
        float nq = xq * xq;
#pragma unroll
        for (int m = 32; m > 0; m >>= 1) {
          sq += __shfl_xor(sq, m);
          nq += __shfl_xor(nq, m);
        }
        float inv = 1.f / fmaxf(sqrtf(nq), 1e-12f);
        xn_out[(size_t)r * kE + t] = xq * inv;
        if (t == 0) atomicAdd(&acc[r & 255], sq);
      }
      __syncthreads();
    }
  }
}

// ---------------- fallback: exact fp32 MLP for rows >= kMaxFix --------------
__global__ __launch_bounds__(256) void fix_rows(
    const float* __restrict__ x, const float* __restrict__ ew0,
    const float* __restrict__ eb0, const float* __restrict__ ew1,
    const float* __restrict__ eb1, const float* __restrict__ ew2,
    const float* __restrict__ eb2, const float* __restrict__ cb,
    const int* __restrict__ flags, const int* __restrict__ flagcnt,
    float* __restrict__ z, float* __restrict__ idx_out,
    float* __restrict__ xq_out, unsigned short* __restrict__ xqb_out,
    float* __restrict__ xn_out, float* __restrict__ acc) {
  __shared__ float xs[kIN];
  __shared__ float sh1[kH1];
  __shared__ float sh2[kH2];
  __shared__ float sred[256];
  __shared__ float szs[kE];
  __shared__ float rv[256];
  __shared__ int ri[256];
  const int t = threadIdx.x;
  const int cnt = *flagcnt;
  for (int fi = kMaxFix + blockIdx.x; fi < cnt; fi += gridDim.x) {
    const int r = flags[fi];
    for (int q = t; q < kIN; q += 256) xs[q] = x[(size_t)r * kIN + q];
    __syncthreads();
#pragma unroll
    for (int o = 0; o < kH1 / 256; ++o) {
      int j = t + 256 * o;
      float s = eb0[j];
      for (int k = 0; k < kIN; ++k) s = fmaf(xs[k], ew0[(size_t)k * kH1 + j], s);
      sh1[j] = fmaxf(s, 0.f);
    }
    __syncthreads();
#pragma unroll
    for (int o = 0; o < kH2 / 256; ++o) {
      int j = t + 256 * o;
      float s = eb1[j];
      for (int k = 0; k < kH1; ++k) s = fmaf(sh1[k], ew1[(size_t)k * kH2 + j], s);
      sh2[j] = fmaxf(s, 0.f);
    }
    __syncthreads();
    {
      int j = t & 63, p = t >> 6;
      float s = 0.f;
      for (int k = p * 256; k < p * 256 + 256; ++k)
        s = fmaf(sh2[k], ew2[(size_t)k * kE + j], s);
      sred[t] = s;
      __syncthreads();
      if (t < kE) {
        float zv = sred[t] + sred[t + 64] + sred[t + 128] + sred[t + 192] + eb2[t];
        szs[t] = zv;
        z[(size_t)r * kE + t] = zv;
      }
      __syncthreads();
    }
    {
      float dot = 0.f, nrm = 0.f;
      const float* c = cb + (size_t)t * kE;
#pragma unroll 8
      for (int e = 0; e < kE; ++e) {
        float ce = c[e];
        dot = fmaf(szs[e], ce, dot);
        nrm = fmaf(ce, ce, nrm);
      }
      rv[t] = nrm - 2.f * dot;
      ri[t] = t;
      __syncthreads();
      for (int s = 128; s > 0; s >>= 1) {
        if (t < s) {
          float v2 = rv[t + s];
          int i2 = ri[t + s];
          if (v2 < rv[t] || (v2 == rv[t] && i2 < ri[t])) { rv[t] = v2; ri[t] = i2; }
        }
        __syncthreads();
      }
      const int best = ri[0];
      if (t == 0) idx_out[r] = (float)best;
      if (t < kE) {
        float xq = cb[(size_t)best * kE + t];
        xq_out[(size_t)r * kE + t] = xq;
        xqb_out[(size_t)r * kE + t] = f2bf(xq);
        float dd = xq - szs[t];
        float sq = dd * dd;
        float nq = xq * xq;
#pragma unroll
        for (int m = 32; m > 0; m >>= 1) {
          sq += __shfl_xor(sq, m);
          nq += __shfl_xor(nq, m);
        }
        float inv = 1.f / fmaxf(sqrtf(nq), 1e-12f);
        xn_out[(size_t)r * kE + t] = xq * inv;
        if (t == 0) atomicAdd(&acc[r & 255], sq);
      }
      __syncthreads();
    }
  }
}

// ---------------- qd_align ----------------
__global__ __launch_bounds__(256) void qd_kernel(const float* __restrict__ z,
                                                 const float* __restrict__ qz,
                                                 const float* __restrict__ w,
                                                 float* __restrict__ acc) {
  const int i = blockIdx.x * 4 + (threadIdx.x >> 6);
  const int l = threadIdx.x & 63;
  float a = z[(size_t)i * kE + l];
  float b = qz[(size_t)i * kE + l];
  float dot = a * b, na = a * a, nb = b * b;
#pragma unroll
  for (int m = 32; m > 0; m >>= 1) {
    dot += __shfl_xor(dot, m);
    na += __shfl_xor(na, m);
    nb += __shfl_xor(nb, m);
  }
  if (l == 0) {
    float cosv = dot / fmaxf(sqrtf(na) * sqrtf(nb), 1e-8f);
    atomicAdd(&acc[i & 255], w[i] * cosv);
  }
}

// ---------------- triplet ----------------
__global__ __launch_bounds__(256) void trip_kernel(const float* __restrict__ z,
                                                   const int* __restrict__ tr,
                                                   float* __restrict__ acc) {
  const int t = blockIdx.x * 4 + (threadIdx.x >> 6);
  const int l = threadIdx.x & 63;
  int ia = tr[3 * t], ip = tr[3 * t + 1], in2 = tr[3 * t + 2];
  float a = z[(size_t)ia * kE + l];
  float p = z[(size_t)ip * kE + l];
  float n = z[(size_t)in2 * kE + l];
  float d1 = (a - p) * (a - p);
  float d2 = (a - n) * (a - n);
#pragma unroll
  for (int m = 32; m > 0; m >>= 1) {
    d1 += __shfl_xor(d1, m);
    d2 += __shfl_xor(d2, m);
  }
  if (l == 0) {
    float dp = sqrtf(d1 + 1e-12f);
    float dn = sqrtf(d2 + 1e-12f);
    atomicAdd(&acc[t & 255], fmaxf(dp - dn + 0.2f, 0.f));
  }
}

// ---------------- pairs: subtract positive sim ----------------
__global__ __launch_bounds__(256) void pos_kernel(const float* __restrict__ xn,
                                                  const int* __restrict__ pairs,
                                                  float* __restrict__ acc) {
  const int k = blockIdx.x * 4 + (threadIdx.x >> 6);
  const int l = threadIdx.x & 63;
  int i0 = pairs[2 * k], i1 = pairs[2 * k + 1];
  float v = xn[(size_t)i0 * kE + l] * xn[(size_t)i1 * kE + l];
#pragma unroll
  for (int m = 32; m > 0; m >>= 1) v += __shfl_xor(v, m);
  if (l == 0) atomicAdd(&acc[k & 255], -10.f * v);
}

// ---------------- code-space LSE ----------------
// Every xn row is a normalized codebook entry, so
//   sum_j exp(10 * <xn[a_p], xn[j]>) = sum_c count[c] * exp(10 * G[code(a_p)][c])
// with G = cbn @ cbn^T (256x256). Histogram + tiny dot table replace the
// 4096x32768 fp32 GEMM (was 370 us).

// histogram of final idx over all N rows
__global__ __launch_bounds__(256) void hist_kernel(const float* __restrict__ idx_out,
                                                   int* __restrict__ cnt) {
  __shared__ int h[kNE];
  const int t = threadIdx.x;
  h[t] = 0;
  __syncthreads();
  int i = blockIdx.x * 256 + t;
  atomicAdd(&h[(int)idx_out[i]], 1);
  __syncthreads();
  if (h[t]) atomicAdd(&cnt[t], h[t]);
}

// E[a] = sum_c cnt[c] * exp(10 * <cbn[a], cbn[c]>); one block per code a
__global__ __launch_bounds__(256) void code_lse(const float* __restrict__ cb,
                                                const int* __restrict__ cnt,
                                                float* __restrict__ E) {
  __shared__ float cbn[kNE][kE + 1];  // +1 pad: avoid 32-way bank conflict
  __shared__ float red[256];
  const int t = threadIdx.x, a = blockIdx.x;
  // normalize row t of the codebook into LDS
  const float* r = cb + (size_t)t * kE;
  float s = 0.f;
#pragma unroll 8
  for (int e = 0; e < kE; ++e) s = fmaf(r[e], r[e], s);
  float inv = 1.f / fmaxf(sqrtf(s), 1e-12f);
#pragma unroll 8
  for (int e = 0; e < kE; ++e) cbn[t][e] = r[e] * inv;
  __syncthreads();
  float dot = 0.f;
#pragma unroll 8
  for (int e = 0; e < kE; ++e) dot = fmaf(cbn[a][e], cbn[t][e], dot);
  red[t] = (float)cnt[t] * expf(10.f * dot);
  __syncthreads();
  for (int sred = 128; sred > 0; sred >>= 1) {
    if (t < sred) red[t] += red[t + sred];
    __syncthreads();
  }
  if (t == 0) E[a] = red[0];
}

// acc += log(E[code(anchor_p)]) for each pair
__global__ __launch_bounds__(256) void pair_log(const float* __restrict__ idx_out,
                                                const int* __restrict__ pairs,
                                                const float* __restrict__ E,
                                                float* __restrict__ acc) {
  int p = blockIdx.x * 256 + threadIdx.x;
  int a = (int)idx_out[pairs[2 * p]];
  atomicAdd(&acc[p & 255], logf(E[a]));
}

// ---------------- finalize scalars ----------------
__global__ __launch_bounds__(256) void finalize_kernel(const float* __restrict__ acc,
                                                       float* __restrict__ out) {
  const int t = threadIdx.x;
  float vq = acc[t], qd = acc[256 + t], tr = acc[512 + t], ou = acc[768 + t];
#pragma unroll
  for (int m = 32; m > 0; m >>= 1) {
    vq += __shfl_xor(vq, m);
    qd += __shfl_xor(qd, m);
    tr += __shfl_xor(tr, m);
    ou += __shfl_xor(ou, m);
  }
  __shared__ float sm[4][4];
  const int w = t >> 6;
  if ((t & 63) == 0) { sm[0][w] = vq; sm[1][w] = qd; sm[2][w] = tr; sm[3][w] = ou; }
  __syncthreads();
  if (t == 0) {
    float svq = sm[0][0] + sm[0][1] + sm[0][2] + sm[0][3];
    float sqd = sm[1][0] + sm[1][1] + sm[1][2] + sm[1][3];
    float str = sm[2][0] + sm[2][1] + sm[2][2] + sm[2][3];
    float sou = sm[3][0] + sm[3][1] + sm[3][2] + sm[3][3];
    out[OFF_VQ]  = 1.001f * svq / (float)((size_t)kN * kE);
    out[OFF_OCL] = sou / (float)kKP;
    out[OFF_ITL] = str / (float)kTT;
    out[OFF_QDA] = 1.f - sqd / (float)kN;
  }
}

// ---------------- orchestration ----------------
extern "C" void kernel_launch(void* const* d_in, const int* in_sizes, int n_in,
                              void* d_out, int out_size, void* d_ws, size_t ws_size,
                              hipStream_t stream) {
  (void)in_sizes; (void)n_in; (void)out_size; (void)ws_size;
  const float* x    = (const float*)d_in[0];
  const float* qe   = (const float*)d_in[1];
  const float* qdw  = (const float*)d_in[2];
  const int*   prs  = (const int*)d_in[3];
  const int*   trs  = (const int*)d_in[4];
  const float* ew0  = (const float*)d_in[5];
  const float* eb0  = (const float*)d_in[6];
  const float* ew1  = (const float*)d_in[7];
  const float* eb1  = (const float*)d_in[8];
  const float* ew2  = (const float*)d_in[9];
  const float* eb2  = (const float*)d_in[10];
  const float* dw0  = (const float*)d_in[11];
  const float* db0  = (const float*)d_in[12];
  const float* dw1  = (const float*)d_in[13];
  const float* db1  = (const float*)d_in[14];
  const float* dw2  = (const float*)d_in[15];
  const float* db2  = (const float*)d_in[16];
  const float* cb   = (const float*)d_in[17];
  float* out = (float*)d_out;

  // ---- workspace carve-up (~114 MB) ----
  float* z   = (float*)d_ws;                         // N x E fp32
  float* qz  = z  + (size_t)kN * kE;
  float* xn  = qz + (size_t)kN * kE;
  float* acc = xn + (size_t)kN * kE;                 // 1024
  float* pairsum = acc + 1024;                       // 4096 (cnt + E live here)
  int*   flagcnt = (int*)(pairsum + 4096);           // 64 (1 used)
  int*   flags   = flagcnt + 64;                     // kN ints
  unsigned short* xqb  = (unsigned short*)(flags + kN);     // N x E bf16
  unsigned short* wt0h = xqb  + (size_t)kN * kE;     // enc w0^T hi 2048x768
  unsigned short* wt0l = wt0h + (size_t)kH1 * kIN;
  unsigned short* wt1h = wt0l + (size_t)kH1 * kIN;   // 1024x2048
  unsigned short* wt1l = wt1h + (size_t)kH2 * kH1;
  unsigned short* wt2h = wt1l + (size_t)kH2 * kH1;   // 64x1024
  unsigned short* wt2l = wt2h + (size_t)kE * kH2;
  unsigned short* wt3  = wt2l + (size_t)kE * kH2;    // dec w0^T 1024x64
  unsigned short* wt4  = wt3  + (size_t)kH2 * kE;    // dec w1^T 2048x1024
  unsigned short* wt5  = wt4  + (size_t)kH1 * kH2;   // dec w2^T 768x2048
  // chunk scratch (union across phases), 4096-row chunks
  unsigned short* xh  = wt5 + (size_t)kIN * kH1;     // 4096x768
  unsigned short* xl  = xh + (size_t)kCh * kIN;
  unsigned short* h1h = xl + (size_t)kCh * kIN;      // 4096x2048
  unsigned short* h1l = h1h + (size_t)kCh * kH1;
  unsigned short* h2h = h1l + (size_t)kCh * kH1;     // 4096x1024
  unsigned short* h2l = h2h + (size_t)kCh * kH2;
  // fix-chain scratch: aliases chunk scratch (dead between x-enc and decoder).
  float* h1f = (float*)xh;
  float* h2f = h1f + (size_t)kMaxFix * kH1;
  // code-LSE scratch: cnt + E carved from the (zeroed) pairsum region
  int*   cnt = (int*)pairsum;          // 256 ints
  float* E   = pairsum + 256;          // 256 floats

  hipMemsetAsync(acc, 0, (1024 + 4096 + 64) * sizeof(float), stream);

  // weight transposes: encoder split, decoder single
  transpose_bf16_split<<<dim3(kH1 / 32, kIN / 32), 256, 0, stream>>>(ew0, wt0h, wt0l, kIN, kH1);
  transpose_bf16_split<<<dim3(kH2 / 32, kH1 / 32), 256, 0, stream>>>(ew1, wt1h, wt1l, kH1, kH2);
  transpose_bf16_split<<<dim3(kE / 32, kH2 / 32), 256, 0, stream>>>(ew2, wt2h, wt2l, kH2, kE);
  transpose_bf16<<<dim3(kH2 / 32, kE / 32), 256, 0, stream>>>(dw0, wt3, kE, kH2);
  transpose_bf16<<<dim3(kH1 / 32, kH2 / 32), 256, 0, stream>>>(dw1, wt4, kH2, kH1);
  transpose_bf16<<<dim3(kIN / 32, kH1 / 32), 256, 0, stream>>>(dw2, wt5, kH1, kIN);

  // x-encoder (split-bf16 MFMA) -> z fp32
  for (int c = 0; c < kN / kCh; ++c) {
    conv_split<<<(kCh * kIN / 4 + 255) / 256, 256, 0, stream>>>(
        x + (size_t)c * kCh * kIN, xh, xl, kCh * kIN / 4);
    gemm_bt_split<128, 128, 64, true, 2>
        <<<dim3(kH1 / 128, kCh / 128), 256, 0, stream>>>(
            xh, xl, wt0h, wt0l, eb0, nullptr, h1h, h1l, kH1, kIN);
    gemm_bt_split<128, 128, 64, true, 2>
        <<<dim3(kH2 / 128, kCh / 128), 256, 0, stream>>>(
            h1h, h1l, wt1h, wt1l, eb1, nullptr, h2h, h2l, kH2, kH1);
    gemm_bt_split<128, 64, 64, false, 0>
        <<<dim3(kE / 64, kCh / 128), 256, 0, stream>>>(
            h2h, h2l, wt2h, wt2l, eb2, z + (size_t)c * kCh * kE, nullptr, nullptr,
            kE, kH2);
  }

  // VQ with gap-flagging, then exact fp32 fix for flagged rows
  vq_kernel<<<512, 256, 0, stream>>>(z, cb, out + OFF_IDX, out + OFF_XQ, xqb, xn,
                                     acc, flags, flagcnt);
  fix_h1<<<512, 256, 0, stream>>>(x, ew0, eb0, flags, flagcnt, h1f);
  fix_h2<<<512, 256, 0, stream>>>(h1f, ew1, eb1, flagcnt, h2f);
  fix_z<<<512, 256, 0, stream>>>(h2f, ew2, eb2, cb, flags, flagcnt, z,
                                 out + OFF_IDX, out + OFF_XQ, xqb, xn, acc);
  // fallback for pathological flag counts (> kMaxFix); no-op otherwise
  fix_rows<<<64, 256, 0, stream>>>(x, ew0, eb0, ew1, eb1, ew2, eb2, cb, flags,
                                   flagcnt, z, out + OFF_IDX, out + OFF_XQ, xqb,
                                   xn, acc);

  // decoder (bf16 MFMA) on x_q_st -> out
  for (int c = 0; c < kN / kCh; ++c) {
    gemm_bt<128, 128, 64, true, false, true>
        <<<dim3(kH2 / 128, kCh / 128), 256, 0, stream>>>(
            xqb + (size_t)c * kCh * kE, wt3, db0, nullptr, h2h, kH2, kE);
    gemm_bt<128, 128, 64, true, false, true>
        <<<dim3(kH1 / 128, kCh / 128), 256, 0, stream>>>(
            h2h, wt4, db1, nullptr, h1h, kH1, kH2);
    gemm_bt<128, 128, 64, false, true, false>
        <<<dim3(kIN / 128, kCh / 128), 256, 0, stream>>>(
            h1h, wt5, db2, out + OFF_OUT + (size_t)c * kCh * kIN, nullptr, kIN, kH1);
  }

  // q-encoder (bf16 MFMA) -> qz
  for (int c = 0; c < kN / kCh; ++c) {
    conv_bf16<<<(kCh * kIN / 4 + 255) / 256, 256, 0, stream>>>(
        qe + (size_t)c * kCh * kIN, xh, kCh * kIN / 4);
    gemm_bt<128, 128, 64, true, false, true>
        <<<dim3(kH1 / 128, kCh / 128), 256, 0, stream>>>(
            xh, wt0h, eb0, nullptr, h1h, kH1, kIN);
    gemm_bt<128, 128, 64, true, false, true>
        <<<dim3(kH2 / 128, kCh / 128), 256, 0, stream>>>(
            h1h, wt1h, eb1, nullptr, h2h, kH2, kH1);
    gemm_bt<128, 64, 64, false, true, false>
        <<<dim3(kE / 64, kCh / 128), 256, 0, stream>>>(
            h2h, wt2h, eb2, qz + (size_t)c * kCh * kE, nullptr, kE, kH2);
  }

  // small loss kernels (all after fix chain: z/xn/idx final)
  qd_kernel<<<kN / 4, 256, 0, stream>>>(z, qz, qdw, acc + 256);
  trip_kernel<<<kTT / 4, 256, 0, stream>>>(z, trs, acc + 512);
  pos_kernel<<<kKP / 4, 256, 0, stream>>>(xn, prs, acc + 768);
  // code-space LSE: histogram -> 256x256 exp table -> per-pair log
  hist_kernel<<<kN / 256, 256, 0, stream>>>(out + OFF_IDX, cnt);
  code_lse<<<kNE, 256, 0, stream>>>(cb, cnt, E);
  pair_log<<<kKP / 256, 256, 0, stream>>>(out + OFF_IDX, prs, E, acc + 768);

  finalize_kernel<<<1, 256, 0, stream>>>(acc, out);
}

// Round 4
// 2893.944 us; speedup vs baseline: 1.2537x; 1.0325x over previous
//
#include <hip/hip_runtime.h>
#include <hip/hip_bf16.h>

// ---------------- problem constants ----------------
namespace {
constexpr int kN = 32768, kIN = 768, kH1 = 2048, kH2 = 1024, kE = 64, kNE = 256;
constexpr int kKP = 4096, kTT = 8192;
constexpr int kCh = 4096;  // rows per GEMM slice
constexpr int kMaxFix = 4096;  // rows handled by the fast fix chain

// flat float32 offsets in d_out, reference return order
constexpr size_t OFF_OUT = 0;
constexpr size_t OFF_VQ  = (size_t)kN * kIN;
constexpr size_t OFF_IDX = OFF_VQ + 1;
constexpr size_t OFF_XQ  = OFF_IDX + (size_t)kN;
constexpr size_t OFF_OCL = OFF_XQ + (size_t)kN * kE;
constexpr size_t OFF_ITL = OFF_OCL + 1;
constexpr size_t OFF_QDA = OFF_ITL + 1;
}  // namespace

typedef short bf16x8 __attribute__((ext_vector_type(8)));
typedef float f32x4 __attribute__((ext_vector_type(4)));

__device__ __forceinline__ unsigned short f2bf(float v) {
  __hip_bfloat16 h = __float2bfloat16(v);
  return *reinterpret_cast<unsigned short*>(&h);
}
__device__ __forceinline__ float bf2f(unsigned short u) {
  __hip_bfloat16 h = *reinterpret_cast<__hip_bfloat16*>(&u);
  return __bfloat162float(h);
}

__device__ __forceinline__ void gload_lds16(const void* g, void* lds) {
  __builtin_amdgcn_global_load_lds(
      (const __attribute__((address_space(1))) void*)g,
      (__attribute__((address_space(3))) void*)lds, 16, 0, 0);
}

// XCD-aware block swizzle (T1): valid when total workgroups % 8 == 0.
__device__ __forceinline__ void xcd_swizzle(int& bx, int& by) {
  int gx = gridDim.x, gy = gridDim.y;
  int nwg = gx * gy;
  if (nwg & 7) return;  // not divisible; keep default
  int bid = by * gx + bx;
  int cpx = nwg >> 3;
  int swz = (bid & 7) * cpx + (bid >> 3);
  bx = swz % gx;
  by = swz / gx;
}

// ---------------- bf16 MFMA GEMM: C = relu?(A @ Bt^T + bias) ----------------
// A: MxK bf16 row-major. Bt: NxK bf16 row-major. 4 waves in 2x2; 16x16x32 MFMA.
template <int BM, int BN, int BK, bool RELU, bool OUTF, bool OUTB>
__global__ __launch_bounds__(256) void gemm_bt(const unsigned short* __restrict__ A,
                                               const unsigned short* __restrict__ Bt,
                                               const float* __restrict__ bias,
                                               float* __restrict__ Cf,
                                               unsigned short* __restrict__ Cb,
                                               int N, int K) {
  constexpr int WM = BM / 2, WN = BN / 2, TMt = WM / 16, TNt = WN / 16;
  constexpr int CH = BK / 8;
  constexpr int RA = BM * BK / 2048, RB = BN * BK / 2048;
  __shared__ unsigned short As[BM * BK];
  __shared__ unsigned short Bs[BN * BK];
  const int tid = threadIdx.x, lane = tid & 63, wave = tid >> 6;
  const int wm = (wave >> 1) * WM, wn = (wave & 1) * WN;
  const int l15 = lane & 15, quad = lane >> 4;
  int bxs = blockIdx.x, bys = blockIdx.y;
  xcd_swizzle(bxs, bys);
  const int rowA0 = bys * BM, colB0 = bxs * BN;
  f32x4 acc[TMt][TNt];
#pragma unroll
  for (int i = 0; i < TMt; ++i)
#pragma unroll
    for (int j = 0; j < TNt; ++j) acc[i][j] = (f32x4){0.f, 0.f, 0.f, 0.f};

  const char* Ab = (const char*)A;
  const char* Bb = (const char*)Bt;
  char* AsB = (char*)As;
  char* BsB = (char*)Bs;

  for (int k0 = 0; k0 < K; k0 += BK) {
    if (k0) __syncthreads();
#pragma unroll
    for (int r = 0; r < RA; ++r) {
      int off = (r * 256 + tid) * 16;
      int row = off / (BK * 2);
      int sc = ((off >> 4) ^ row) & (CH - 1);
      gload_lds16(Ab + (size_t)(rowA0 + row) * (K * 2) + (size_t)k0 * 2 + sc * 16,
                  AsB + off);
    }
#pragma unroll
    for (int r = 0; r < RB; ++r) {
      int off = (r * 256 + tid) * 16;
      int row = off / (BK * 2);
      int sc = ((off >> 4) ^ row) & (CH - 1);
      gload_lds16(Bb + (size_t)(colB0 + row) * (K * 2) + (size_t)k0 * 2 + sc * 16,
                  BsB + off);
    }
    __syncthreads();
#pragma unroll
    for (int ks = 0; ks < BK; ks += 32) {
      bf16x8 af[TMt], bfr[TNt];
#pragma unroll
      for (int i = 0; i < TMt; ++i) {
        int row = wm + i * 16 + l15;
        int c = (((ks >> 3) + quad) ^ row) & (CH - 1);
        af[i] = *(const bf16x8*)(AsB + row * (BK * 2) + c * 16);
      }
#pragma unroll
      for (int j = 0; j < TNt; ++j) {
        int col = wn + j * 16 + l15;
        int c = (((ks >> 3) + quad) ^ col) & (CH - 1);
        bfr[j] = *(const bf16x8*)(BsB + col * (BK * 2) + c * 16);
      }
#pragma unroll
      for (int i = 0; i < TMt; ++i)
#pragma unroll
        for (int j = 0; j < TNt; ++j)
          acc[i][j] = __builtin_amdgcn_mfma_f32_16x16x32_bf16(af[i], bfr[j],
                                                              acc[i][j], 0, 0, 0);
    }
  }
#pragma unroll
  for (int j = 0; j < TNt; ++j) {
    int col = colB0 + wn + j * 16 + l15;
    float bv = bias[col];
#pragma unroll
    for (int i = 0; i < TMt; ++i) {
      int rbase = rowA0 + wm + i * 16 + quad * 4;
#pragma unroll
      for (int r = 0; r < 4; ++r) {
        float v = acc[i][j][r] + bv;
        if (RELU) v = fmaxf(v, 0.f);
        size_t o = (size_t)(rbase + r) * N + col;
        if (OUTF) Cf[o] = v;
        if (OUTB) Cb[o] = f2bf(v);
      }
    }
  }
}

// ---------------- split-bf16 MFMA GEMM (fp32-accurate x-path) ----------------
// C = relu?((Ah+Al) @ (Bh+Bl)^T + bias), dropping Al*Bl (err ~2^-18).
// OM: 0 = write fp32 C; 2 = write split bf16 (Ch, Cl).
template <int BM, int BN, int BK, bool RELU, int OM>
__global__ __launch_bounds__(256) void gemm_bt_split(
    const unsigned short* __restrict__ Ah, const unsigned short* __restrict__ Al,
    const unsigned short* __restrict__ Bh, const unsigned short* __restrict__ Bl,
    const float* __restrict__ bias, float* __restrict__ Cf,
    unsigned short* __restrict__ Ch, unsigned short* __restrict__ Cl,
    int N, int K) {
  constexpr int WM = BM / 2, WN = BN / 2, TMt = WM / 16, TNt = WN / 16;
  constexpr int CH = BK / 8;
  constexpr int RA = BM * BK / 2048, RB = BN * BK / 2048;
  __shared__ unsigned short AsH[BM * BK];
  __shared__ unsigned short AsL[BM * BK];
  __shared__ unsigned short BsH[BN * BK];
  __shared__ unsigned short BsL[BN * BK];
  const int tid = threadIdx.x, lane = tid & 63, wave = tid >> 6;
  const int wm = (wave >> 1) * WM, wn = (wave & 1) * WN;
  const int l15 = lane & 15, quad = lane >> 4;
  int bxs = blockIdx.x, bys = blockIdx.y;
  xcd_swizzle(bxs, bys);
  const int rowA0 = bys * BM, colB0 = bxs * BN;
  f32x4 acc[TMt][TNt];
#pragma unroll
  for (int i = 0; i < TMt; ++i)
#pragma unroll
    for (int j = 0; j < TNt; ++j) acc[i][j] = (f32x4){0.f, 0.f, 0.f, 0.f};

  const char* AhB = (const char*)Ah;
  const char* AlB = (const char*)Al;
  const char* BhB = (const char*)Bh;
  const char* BlB = (const char*)Bl;

  for (int k0 = 0; k0 < K; k0 += BK) {
    if (k0) __syncthreads();
#pragma unroll
    for (int r = 0; r < RA; ++r) {
      int off = (r * 256 + tid) * 16;
      int row = off / (BK * 2);
      int sc = ((off >> 4) ^ row) & (CH - 1);
      size_t go = (size_t)(rowA0 + row) * (K * 2) + (size_t)k0 * 2 + sc * 16;
      gload_lds16(AhB + go, (char*)AsH + off);
      gload_lds16(AlB + go, (char*)AsL + off);
    }
#pragma unroll
    for (int r = 0; r < RB; ++r) {
      int off = (r * 256 + tid) * 16;
      int row = off / (BK * 2);
      int sc = ((off >> 4) ^ row) & (CH - 1);
      size_t go = (size_t)(colB0 + row) * (K * 2) + (size_t)k0 * 2 + sc * 16;
      gload_lds16(BhB + go, (char*)BsH + off);
      gload_lds16(BlB + go, (char*)BsL + off);
    }
    __syncthreads();
#pragma unroll
    for (int ks = 0; ks < BK; ks += 32) {
      bf16x8 ah[TMt], al[TMt], bh[TNt], bl[TNt];
#pragma unroll
      for (int i = 0; i < TMt; ++i) {
        int row = wm + i * 16 + l15;
        int c = (((ks >> 3) + quad) ^ row) & (CH - 1);
        int off = row * (BK * 2) + c * 16;
        ah[i] = *(const bf16x8*)((const char*)AsH + off);
        al[i] = *(const bf16x8*)((const char*)AsL + off);
      }
#pragma unroll
      for (int j = 0; j < TNt; ++j) {
        int col = wn + j * 16 + l15;
        int c = (((ks >> 3) + quad) ^ col) & (CH - 1);
        int off = col * (BK * 2) + c * 16;
        bh[j] = *(const bf16x8*)((const char*)BsH + off);
        bl[j] = *(const bf16x8*)((const char*)BsL + off);
      }
#pragma unroll
      for (int i = 0; i < TMt; ++i)
#pragma unroll
        for (int j = 0; j < TNt; ++j) {
          acc[i][j] = __builtin_amdgcn_mfma_f32_16x16x32_bf16(ah[i], bh[j], acc[i][j], 0, 0, 0);
          acc[i][j] = __builtin_amdgcn_mfma_f32_16x16x32_bf16(ah[i], bl[j], acc[i][j], 0, 0, 0);
          acc[i][j] = __builtin_amdgcn_mfma_f32_16x16x32_bf16(al[i], bh[j], acc[i][j], 0, 0, 0);
        }
    }
  }
#pragma unroll
  for (int j = 0; j < TNt; ++j) {
    int col = colB0 + wn + j * 16 + l15;
    float bv = bias[col];
#pragma unroll
    for (int i = 0; i < TMt; ++i) {
      int rbase = rowA0 + wm + i * 16 + quad * 4;
#pragma unroll
      for (int r = 0; r < 4; ++r) {
        float v = acc[i][j][r] + bv;
        if (RELU) v = fmaxf(v, 0.f);
        size_t o = (size_t)(rbase + r) * N + col;
        if (OM == 0) {
          Cf[o] = v;
        } else {
          unsigned short hi = f2bf(v);
          Ch[o] = hi;
          Cl[o] = f2bf(v - bf2f(hi));
        }
      }
    }
  }
}

// ---------------- weight transpose fp32 KxN -> bf16 NxK (single) ------------
__global__ __launch_bounds__(256) void transpose_bf16(const float* __restrict__ W,
                                                      unsigned short* __restrict__ Wt,
                                                      int K, int N) {
  __shared__ float t[32][33];
  int bx = blockIdx.x * 32, by = blockIdx.y * 32;
  int tx = threadIdx.x & 31, ty = threadIdx.x >> 5;
#pragma unroll
  for (int i = 0; i < 32; i += 8)
    t[ty + i][tx] = W[(size_t)(by + ty + i) * N + bx + tx];
  __syncthreads();
#pragma unroll
  for (int i = 0; i < 32; i += 8)
    Wt[(size_t)(bx + ty + i) * K + by + tx] = f2bf(t[tx][ty + i]);
}

// ---------------- weight transpose fp32 KxN -> split bf16 NxK ---------------
__global__ __launch_bounds__(256) void transpose_bf16_split(
    const float* __restrict__ W, unsigned short* __restrict__ Wh,
    unsigned short* __restrict__ Wl, int K, int N) {
  __shared__ float t[32][33];
  int bx = blockIdx.x * 32, by = blockIdx.y * 32;
  int tx = threadIdx.x & 31, ty = threadIdx.x >> 5;
#pragma unroll
  for (int i = 0; i < 32; i += 8)
    t[ty + i][tx] = W[(size_t)(by + ty + i) * N + bx + tx];
  __syncthreads();
#pragma unroll
  for (int i = 0; i < 32; i += 8) {
    float v = t[tx][ty + i];
    unsigned short hi = f2bf(v);
    size_t o = (size_t)(bx + ty + i) * K + by + tx;
    Wh[o] = hi;
    Wl[o] = f2bf(v - bf2f(hi));
  }
}

// ---------------- fp32 -> bf16 convert (single) ----------------
__global__ __launch_bounds__(256) void conv_bf16(const float* __restrict__ in,
                                                 unsigned short* __restrict__ out,
                                                 int n4) {
  int i = (blockIdx.x * 256 + threadIdx.x);
  if (i < n4) {
    float4 v = *(const float4*)(in + (size_t)i * 4);
    unsigned short o[4] = {f2bf(v.x), f2bf(v.y), f2bf(v.z), f2bf(v.w)};
    *(uint2*)(out + (size_t)i * 4) = *(uint2*)o;
  }
}

// ---------------- fp32 -> split bf16 convert ----------------
__global__ __launch_bounds__(256) void conv_split(const float* __restrict__ in,
                                                  unsigned short* __restrict__ oh,
                                                  unsigned short* __restrict__ ol,
                                                  int n4) {
  int i = (blockIdx.x * 256 + threadIdx.x);
  if (i < n4) {
    float4 v = *(const float4*)(in + (size_t)i * 4);
    unsigned short h[4], l[4];
    float vv[4] = {v.x, v.y, v.z, v.w};
#pragma unroll
    for (int k = 0; k < 4; ++k) {
      h[k] = f2bf(vv[k]);
      l[k] = f2bf(vv[k] - bf2f(h[k]));
    }
    *(uint2*)(oh + (size_t)i * 4) = *(uint2*)h;
    *(uint2*)(ol + (size_t)i * 4) = *(uint2*)l;
  }
}

// ---------------- VQ: argmin over 256 codes + gap-flagging ----------------
// R3: 8-row dt batches (halves ds_read_b128 count vs 4-row); codebook staged
// transposed in LDS; per-wave shuffle top-2; same arithmetic per row.
#define FMA4(a, s, v)              \
  a[0] = fmaf(s, v[0], a[0]);      \
  a[1] = fmaf(s, v[1], a[1]);      \
  a[2] = fmaf(s, v[2], a[2]);      \
  a[3] = fmaf(s, v[3], a[3])

__global__ __launch_bounds__(256) void vq_kernel(const float* __restrict__ z,
                                                 const float* __restrict__ cb,
                                                 float* __restrict__ idx_out,
                                                 float* __restrict__ xq_out,
                                                 unsigned short* __restrict__ xqb_out,
                                                 float* __restrict__ xn_out,
                                                 float* __restrict__ acc,
                                                 int* __restrict__ flags,
                                                 int* __restrict__ flagcnt) {
  __shared__ float cbT[kE * kNE];  // cbT[e*256 + c] = cb[c][e]  (64 KB)
  const int t = threadIdx.x;
  {
    const f32x4* src = (const f32x4*)(cb + (size_t)t * kE);
#pragma unroll
    for (int q = 0; q < 16; ++q) {
      f32x4 v = src[q];
      cbT[(4 * q + 0) * kNE + t] = v[0];
      cbT[(4 * q + 1) * kNE + t] = v[1];
      cbT[(4 * q + 2) * kNE + t] = v[2];
      cbT[(4 * q + 3) * kNE + t] = v[3];
    }
  }
  __syncthreads();
  const int l = t & 63, wv = t >> 6;
  // per-lane code norms (codes 4l..4l+3), same fmaf order as before
  f32x4 cn = (f32x4){0.f, 0.f, 0.f, 0.f};
  for (int e = 0; e < kE; ++e) {
    f32x4 cv = *(const f32x4*)&cbT[e * kNE + 4 * l];
    cn[0] = fmaf(cv[0], cv[0], cn[0]);
    cn[1] = fmaf(cv[1], cv[1], cn[1]);
    cn[2] = fmaf(cv[2], cv[2], cn[2]);
    cn[3] = fmaf(cv[3], cv[3], cn[3]);
  }
  const int rowBase = (blockIdx.x * 4 + wv) * 16;  // 512 blocks * 4 waves * 16 rows
  for (int p = 0; p < 2; ++p) {
    const int ra = rowBase + p * 8;
    f32x4 dt[8];
#pragma unroll
    for (int r = 0; r < 8; ++r) dt[r] = (f32x4){0.f, 0.f, 0.f, 0.f};
#pragma unroll
    for (int e4 = 0; e4 < 16; ++e4) {
      f32x4 c0 = *(const f32x4*)&cbT[(4 * e4 + 0) * kNE + 4 * l];
      f32x4 c1 = *(const f32x4*)&cbT[(4 * e4 + 1) * kNE + 4 * l];
      f32x4 c2 = *(const f32x4*)&cbT[(4 * e4 + 2) * kNE + 4 * l];
      f32x4 c3 = *(const f32x4*)&cbT[(4 * e4 + 3) * kNE + 4 * l];
#pragma unroll
      for (int r = 0; r < 8; ++r) {
        f32x4 zv = *(const f32x4*)(z + (size_t)(ra + r) * kE + e4 * 4);
        FMA4(dt[r], zv[0], c0);
        FMA4(dt[r], zv[1], c1);
        FMA4(dt[r], zv[2], c2);
        FMA4(dt[r], zv[3], c3);
      }
    }
#pragma unroll
    for (int r = 0; r < 8; ++r) {
      const int row = ra + r;
      float d0 = cn[0] - 2.f * dt[r][0];
      float d1 = cn[1] - 2.f * dt[r][1];
      float d2 = cn[2] - 2.f * dt[r][2];
      float d3 = cn[3] - 2.f * dt[r][3];
      float m1 = d0, m2 = 3.4e38f;
      int i1 = 4 * l;
      if (d1 < m1) { m2 = m1; m1 = d1; i1 = 4 * l + 1; } else m2 = fminf(m2, d1);
      if (d2 < m1) { m2 = m1; m1 = d2; i1 = 4 * l + 2; } else m2 = fminf(m2, d2);
      if (d3 < m1) { m2 = m1; m1 = d3; i1 = 4 * l + 3; } else m2 = fminf(m2, d3);
#pragma unroll
      for (int m = 32; m > 0; m >>= 1) {
        float om1 = __shfl_xor(m1, m);
        int oi1 = __shfl_xor(i1, m);
        float om2 = __shfl_xor(m2, m);
        float nm2 = fminf(fminf(m2, om2), fmaxf(m1, om1));
        if (om1 < m1 || (om1 == m1 && oi1 < i1)) { m1 = om1; i1 = oi1; }
        m2 = nm2;
      }
      float zl = z[(size_t)row * kE + l];
      float zn = zl * zl;
#pragma unroll
      for (int m = 32; m > 0; m >>= 1) zn += __shfl_xor(zn, m);
      float tau = 5e-5f * sqrtf(zn);
      if (m2 - m1 < tau) {
        if (l == 0) {
          int slot = atomicAdd(flagcnt, 1);
          flags[slot] = row;
        }
        continue;
      }
      const int best = i1;
      if (l == 0) idx_out[row] = (float)best;
      float xq = cb[(size_t)best * kE + l];
      xq_out[(size_t)row * kE + l] = xq;
      xqb_out[(size_t)row * kE + l] = f2bf(xq);
      float dd = xq - zl;
      float sq = dd * dd;
      float nq = xq * xq;
#pragma unroll
      for (int m = 32; m > 0; m >>= 1) {
        sq += __shfl_xor(sq, m);
        nq += __shfl_xor(nq, m);
      }
      float inv = 1.f / fmaxf(sqrtf(nq), 1e-12f);
      xn_out[(size_t)row * kE + l] = xq * inv;
      if (l == 0) atomicAdd(&acc[row & 255], sq);
    }
  }
}
#undef FMA4

// ---------------- fix MLP layer: H = relu(X[rows] @ W + b) ------------------
// R3 restructure: R=16 rows/row-block (2x weight reuse vs old), JC=64 cols,
// 4 waves split each 256-k chunk, ordered cross-wave LDS reduce (deterministic).
// 36 KB LDS -> 4 blocks/CU; ~500-1100 work items -> latency hidden by TLP.
template <int K, int OUTN, bool GATHER>
__global__ __launch_bounds__(256) void fix_mlp(
    const float* __restrict__ X, const float* __restrict__ W,
    const float* __restrict__ bias, const int* __restrict__ flags,
    const int* __restrict__ flagcnt, float* __restrict__ H) {
  constexpr int R = 16, JC = 64, KC = 256;
  constexpr int NJC = OUTN / JC;
  constexpr int NKC = K / KC;
  constexpr int PAD = 20;  // xs row stride: 16B-aligned f32x4 reads, 8-bank write spread
  __shared__ float xs[KC * PAD];     // 20 KB
  __shared__ float red[4 * R * JC];  // 16 KB
  const int t = threadIdx.x;
  const int lane = t & 63, w = t >> 6;
  int cnt = *flagcnt;
  if (cnt > kMaxFix) cnt = kMaxFix;
  const int nrb = (cnt + R - 1) / R;
  const int nwork = nrb * NJC;
  for (int item = blockIdx.x; item < nwork; item += gridDim.x) {
    const int rb = item / NJC, jc = item % NJC;
    const int j = jc * JC + lane;
    float acc[R];
#pragma unroll
    for (int r = 0; r < R; ++r) acc[r] = 0.f;
    for (int kc = 0; kc < NKC; ++kc) {
      __syncthreads();  // xs/red reuse barrier
      for (int i = t; i < R * KC; i += 256) {
        int r = i >> 8;   // i / KC
        int k = i & 255;  // i % KC
        int row = rb * R + r;
        if (row >= cnt) row = cnt - 1;
        const float* src = GATHER ? (X + (size_t)flags[row] * K)
                                  : (X + (size_t)row * K);
        xs[k * PAD + r] = src[kc * KC + k];
      }
      __syncthreads();
      // wave w handles k in [w*64, w*64+64) of this chunk
      const float* wp = W + (size_t)(kc * KC + w * 64) * OUTN + j;
#pragma unroll 4
      for (int k = 0; k < 64; ++k) {
        float wv = wp[(size_t)k * OUTN];
        const float* xp = &xs[(w * 64 + k) * PAD];
        f32x4 x0 = *(const f32x4*)(xp + 0);
        f32x4 x1 = *(const f32x4*)(xp + 4);
        f32x4 x2 = *(const f32x4*)(xp + 8);
        f32x4 x3 = *(const f32x4*)(xp + 12);
        acc[0] = fmaf(x0[0], wv, acc[0]);
        acc[1] = fmaf(x0[1], wv, acc[1]);
        acc[2] = fmaf(x0[2], wv, acc[2]);
        acc[3] = fmaf(x0[3], wv, acc[3]);
        acc[4] = fmaf(x1[0], wv, acc[4]);
        acc[5] = fmaf(x1[1], wv, acc[5]);
        acc[6] = fmaf(x1[2], wv, acc[6]);
        acc[7] = fmaf(x1[3], wv, acc[7]);
        acc[8] = fmaf(x2[0], wv, acc[8]);
        acc[9] = fmaf(x2[1], wv, acc[9]);
        acc[10] = fmaf(x2[2], wv, acc[10]);
        acc[11] = fmaf(x2[3], wv, acc[11]);
        acc[12] = fmaf(x3[0], wv, acc[12]);
        acc[13] = fmaf(x3[1], wv, acc[13]);
        acc[14] = fmaf(x3[2], wv, acc[14]);
        acc[15] = fmaf(x3[3], wv, acc[15]);
      }
    }
    __syncthreads();
#pragma unroll
    for (int r = 0; r < R; ++r) red[(w * R + r) * JC + lane] = acc[r];
    __syncthreads();
    // ordered sum: bias + p(wave0) + p(wave1) + p(wave2) + p(wave3)
#pragma unroll
    for (int r4 = 0; r4 < 4; ++r4) {
      int r = w * 4 + r4;
      int row = rb * R + r;
      if (row < cnt) {
        float s = bias[j] + red[(0 * R + r) * JC + lane] +
                  red[(1 * R + r) * JC + lane] + red[(2 * R + r) * JC + lane] +
                  red[(3 * R + r) * JC + lane];
        H[(size_t)row * OUTN + j] = fmaxf(s, 0.f);
      }
    }
  }
}

// ---------------- fix phase C: z + argmin + outputs (1 block / row) ---------
__global__ __launch_bounds__(256) void fix_z(
    const float* __restrict__ h2f, const float* __restrict__ ew2,
    const float* __restrict__ eb2, const float* __restrict__ cb,
    const int* __restrict__ flags, const int* __restrict__ flagcnt,
    float* __restrict__ z, float* __restrict__ idx_out,
    float* __restrict__ xq_out, unsigned short* __restrict__ xqb_out,
    float* __restrict__ xn_out, float* __restrict__ acc) {
  __shared__ float hrow[kH2];
  __shared__ float sred[256];
  __shared__ float szs[kE];
  __shared__ float rv[256];
  __shared__ int ri[256];
  const int t = threadIdx.x;
  int cnt = *flagcnt;
  if (cnt > kMaxFix) cnt = kMaxFix;
  for (int fi = blockIdx.x; fi < cnt; fi += gridDim.x) {
    const int r = flags[fi];
    for (int q = t; q < kH2; q += 256) hrow[q] = h2f[(size_t)fi * kH2 + q];
    __syncthreads();
    {
      const int j = t & 63, p = t >> 6;
      float s = 0.f;
      for (int k = p * 256; k < p * 256 + 256; ++k)
        s = fmaf(hrow[k], ew2[(size_t)k * kE + j], s);
      sred[t] = s;
      __syncthreads();
      if (t < kE) {
        float zv = sred[t] + sred[t + 64] + sred[t + 128] + sred[t + 192] + eb2[t];
        szs[t] = zv;
        z[(size_t)r * kE + t] = zv;
      }
      __syncthreads();
    }
    {
      float dot = 0.f, nrm = 0.f;
      const float* c = cb + (size_t)t * kE;
#pragma unroll 8
      for (int e = 0; e < kE; ++e) {
        float ce = c[e];
        dot = fmaf(szs[e], ce, dot);
        nrm = fmaf(ce, ce, nrm);
      }
      rv[t] = nrm - 2.f * dot;
      ri[t] = t;
      __syncthreads();
      for (int s = 128; s > 0; s >>= 1) {
        if (t < s) {
          float v2 = rv[t + s];
          int i2 = ri[t + s];
          if (v2 < rv[t] || (v2 == rv[t] && i2 < ri[t])) { rv[t] = v2; ri[t] = i2; }
        }
        __syncthreads();
      }
      const int best = ri[0];
      if (t == 0) idx_out[r] = (float)best;
      if (t < kE) {
        float xq = cb[(size_t)best * kE + t];
        xq_out[(size_t)r * kE + t] = xq;
        xqb_out[(size_t)r * kE + t] = f2bf(xq);
        float dd = xq - szs[t];
        float sq = dd * dd;
        float nq = xq * xq;
#pragma unroll
        for (int m = 32; m > 0; m >>= 1) {
          sq += __shfl_xor(sq, m);
          nq += __shfl_xor(nq, m);
        }
        float inv = 1.f / fmaxf(sqrtf(nq), 1e-12f);
        xn_out[(size_t)r * kE + t] = xq * inv;
        if (t == 0) atomicAdd(&acc[r & 255], sq);
      }
      __syncthreads();
    }
  }
}

// ---------------- fallback: exact fp32 MLP for rows >= kMaxFix --------------
__global__ __launch_bounds__(256) void fix_rows(
    const float* __restrict__ x, const float* __restrict__ ew0,
    const float* __restrict__ eb0, const float* __restrict__ ew1,
    const float* __restrict__ eb1, const float* __restrict__ ew2,
    const float* __restrict__ eb2, const float* __restrict__ cb,
    const int* __restrict__ flags, const int* __restrict__ flagcnt,
    float* __restrict__ z, float* __restrict__ idx_out,
    float* __restrict__ xq_out, unsigned short* __restrict__ xqb_out,
    float* __restrict__ xn_out, float* __restrict__ acc) {
  __shared__ float xs[kIN];
  __shared__ float sh1[kH1];
  __shared__ float sh2[kH2];
  __shared__ float sred[256];
  __shared__ float szs[kE];
  __shared__ float rv[256];
  __shared__ int ri[256];
  const int t = threadIdx.x;
  const int cnt = *flagcnt;
  for (int fi = kMaxFix + blockIdx.x; fi < cnt; fi += gridDim.x) {
    const int r = flags[fi];
    for (int q = t; q < kIN; q += 256) xs[q] = x[(size_t)r * kIN + q];
    __syncthreads();
#pragma unroll
    for (int o = 0; o < kH1 / 256; ++o) {
      int j = t + 256 * o;
      float s = eb0[j];
      for (int k = 0; k < kIN; ++k) s = fmaf(xs[k], ew0[(size_t)k * kH1 + j], s);
      sh1[j] = fmaxf(s, 0.f);
    }
    __syncthreads();
#pragma unroll
    for (int o = 0; o < kH2 / 256; ++o) {
      int j = t + 256 * o;
      float s = eb1[j];
      for (int k = 0; k < kH1; ++k) s = fmaf(sh1[k], ew1[(size_t)k * kH2 + j], s);
      sh2[j] = fmaxf(s, 0.f);
    }
    __syncthreads();
    {
      int j = t & 63, p = t >> 6;
      float s = 0.f;
      for (int k = p * 256; k < p * 256 + 256; ++k)
        s = fmaf(sh2[k], ew2[(size_t)k * kE + j], s);
      sred[t] = s;
      __syncthreads();
      if (t < kE) {
        float zv = sred[t] + sred[t + 64] + sred[t + 128] + sred[t + 192] + eb2[t];
        szs[t] = zv;
        z[(size_t)r * kE + t] = zv;
      }
      __syncthreads();
    }
    {
      float dot = 0.f, nrm = 0.f;
      const float* c = cb + (size_t)t * kE;
#pragma unroll 8
      for (int e = 0; e < kE; ++e) {
        float ce = c[e];
        dot = fmaf(szs[e], ce, dot);
        nrm = fmaf(ce, ce, nrm);
      }
      rv[t] = nrm - 2.f * dot;
      ri[t] = t;
      __syncthreads();
      for (int s = 128; s > 0; s >>= 1) {
        if (t < s) {
          float v2 = rv[t + s];
          int i2 = ri[t + s];
          if (v2 < rv[t] || (v2 == rv[t] && i2 < ri[t])) { rv[t] = v2; ri[t] = i2; }
        }
        __syncthreads();
      }
      const int best = ri[0];
      if (t == 0) idx_out[r] = (float)best;
      if (t < kE) {
        float xq = cb[(size_t)best * kE + t];
        xq_out[(size_t)r * kE + t] = xq;
        xqb_out[(size_t)r * kE + t] = f2bf(xq);
        float dd = xq - szs[t];
        float sq = dd * dd;
        float nq = xq * xq;
#pragma unroll
        for (int m = 32; m > 0; m >>= 1) {
          sq += __shfl_xor(sq, m);
          nq += __shfl_xor(nq, m);
        }
        float inv = 1.f / fmaxf(sqrtf(nq), 1e-12f);
        xn_out[(size_t)r * kE + t] = xq * inv;
        if (t == 0) atomicAdd(&acc[r & 255], sq);
      }
      __syncthreads();
    }
  }
}

// ---------------- qd_align ----------------
__global__ __launch_bounds__(256) void qd_kernel(const float* __restrict__ z,
                                                 const float* __restrict__ qz,
                                                 const float* __restrict__ w,
                                                 float* __restrict__ acc) {
  const int i = blockIdx.x * 4 + (threadIdx.x >> 6);
  const int l = threadIdx.x & 63;
  float a = z[(size_t)i * kE + l];
  float b = qz[(size_t)i * kE + l];
  float dot = a * b, na = a * a, nb = b * b;
#pragma unroll
  for (int m = 32; m > 0; m >>= 1) {
    dot += __shfl_xor(dot, m);
    na += __shfl_xor(na, m);
    nb += __shfl_xor(nb, m);
  }
  if (l == 0) {
    float cosv = dot / fmaxf(sqrtf(na) * sqrtf(nb), 1e-8f);
    atomicAdd(&acc[i & 255], w[i] * cosv);
  }
}

// ---------------- triplet ----------------
__global__ __launch_bounds__(256) void trip_kernel(const float* __restrict__ z,
                                                   const int* __restrict__ tr,
                                                   float* __restrict__ acc) {
  const int t = blockIdx.x * 4 + (threadIdx.x >> 6);
  const int l = threadIdx.x & 63;
  int ia = tr[3 * t], ip = tr[3 * t + 1], in2 = tr[3 * t + 2];
  float a = z[(size_t)ia * kE + l];
  float p = z[(size_t)ip * kE + l];
  float n = z[(size_t)in2 * kE + l];
  float d1 = (a - p) * (a - p);
  float d2 = (a - n) * (a - n);
#pragma unroll
  for (int m = 32; m > 0; m >>= 1) {
    d1 += __shfl_xor(d1, m);
    d2 += __shfl_xor(d2, m);
  }
  if (l == 0) {
    float dp = sqrtf(d1 + 1e-12f);
    float dn = sqrtf(d2 + 1e-12f);
    atomicAdd(&acc[t & 255], fmaxf(dp - dn + 0.2f, 0.f));
  }
}

// ---------------- pairs: subtract positive sim ----------------
__global__ __launch_bounds__(256) void pos_kernel(const float* __restrict__ xn,
                                                  const int* __restrict__ pairs,
                                                  float* __restrict__ acc) {
  const int k = blockIdx.x * 4 + (threadIdx.x >> 6);
  const int l = threadIdx.x & 63;
  int i0 = pairs[2 * k], i1 = pairs[2 * k + 1];
  float v = xn[(size_t)i0 * kE + l] * xn[(size_t)i1 * kE + l];
#pragma unroll
  for (int m = 32; m > 0; m >>= 1) v += __shfl_xor(v, m);
  if (l == 0) atomicAdd(&acc[k & 255], -10.f * v);
}

// ---------------- code-space LSE ----------------
// histogram of final idx over all N rows
__global__ __launch_bounds__(256) void hist_kernel(const float* __restrict__ idx_out,
                                                   int* __restrict__ cnt) {
  __shared__ int h[kNE];
  const int t = threadIdx.x;
  h[t] = 0;
  __syncthreads();
  int i = blockIdx.x * 256 + t;
  atomicAdd(&h[(int)idx_out[i]], 1);
  __syncthreads();
  if (h[t]) atomicAdd(&cnt[t], h[t]);
}

// E[a] = sum_c cnt[c] * exp(10 * <cbn[a], cbn[c]>); one block per code a
__global__ __launch_bounds__(256) void code_lse(const float* __restrict__ cb,
                                                const int* __restrict__ cnt,
                                                float* __restrict__ E) {
  __shared__ float cbn[kNE][kE + 1];
  __shared__ float red[256];
  const int t = threadIdx.x, a = blockIdx.x;
  const float* r = cb + (size_t)t * kE;
  float s = 0.f;
#pragma unroll 8
  for (int e = 0; e < kE; ++e) s = fmaf(r[e], r[e], s);
  float inv = 1.f / fmaxf(sqrtf(s), 1e-12f);
#pragma unroll 8
  for (int e = 0; e < kE; ++e) cbn[t][e] = r[e] * inv;
  __syncthreads();
  float dot = 0.f;
#pragma unroll 8
  for (int e = 0; e < kE; ++e) dot = fmaf(cbn[a][e], cbn[t][e], dot);
  red[t] = (float)cnt[t] * expf(10.f * dot);
  __syncthreads();
  for (int sred = 128; sred > 0; sred >>= 1) {
    if (t < sred) red[t] += red[t + sred];
    __syncthreads();
  }
  if (t == 0) E[a] = red[0];
}

// acc += log(E[code(anchor_p)]) for each pair
__global__ __launch_bounds__(256) void pair_log(const float* __restrict__ idx_out,
                                                const int* __restrict__ pairs,
                                                const float* __restrict__ E,
                                                float* __restrict__ acc) {
  int p = blockIdx.x * 256 + threadIdx.x;
  int a = (int)idx_out[pairs[2 * p]];
  atomicAdd(&acc[p & 255], logf(E[a]));
}

// ---------------- finalize scalars ----------------
__global__ __launch_bounds__(256) void finalize_kernel(const float* __restrict__ acc,
                                                       float* __restrict__ out) {
  const int t = threadIdx.x;
  float vq = acc[t], qd = acc[256 + t], tr = acc[512 + t], ou = acc[768 + t];
#pragma unroll
  for (int m = 32; m > 0; m >>= 1) {
    vq += __shfl_xor(vq, m);
    qd += __shfl_xor(qd, m);
    tr += __shfl_xor(tr, m);
    ou += __shfl_xor(ou, m);
  }
  __shared__ float sm[4][4];
  const int w = t >> 6;
  if ((t & 63) == 0) { sm[0][w] = vq; sm[1][w] = qd; sm[2][w] = tr; sm[3][w] = ou; }
  __syncthreads();
  if (t == 0) {
    float svq = sm[0][0] + sm[0][1] + sm[0][2] + sm[0][3];
    float sqd = sm[1][0] + sm[1][1] + sm[1][2] + sm[1][3];
    float str = sm[2][0] + sm[2][1] + sm[2][2] + sm[2][3];
    float sou = sm[3][0] + sm[3][1] + sm[3][2] + sm[3][3];
    out[OFF_VQ]  = 1.001f * svq / (float)((size_t)kN * kE);
    out[OFF_OCL] = sou / (float)kKP;
    out[OFF_ITL] = str / (float)kTT;
    out[OFF_QDA] = 1.f - sqd / (float)kN;
  }
}

// ---------------- orchestration ----------------
extern "C" void kernel_launch(void* const* d_in, const int* in_sizes, int n_in,
                              void* d_out, int out_size, void* d_ws, size_t ws_size,
                              hipStream_t stream) {
  (void)in_sizes; (void)n_in; (void)out_size; (void)ws_size;
  const float* x    = (const float*)d_in[0];
  const float* qe   = (const float*)d_in[1];
  const float* qdw  = (const float*)d_in[2];
  const int*   prs  = (const int*)d_in[3];
  const int*   trs  = (const int*)d_in[4];
  const float* ew0  = (const float*)d_in[5];
  const float* eb0  = (const float*)d_in[6];
  const float* ew1  = (const float*)d_in[7];
  const float* eb1  = (const float*)d_in[8];
  const float* ew2  = (const float*)d_in[9];
  const float* eb2  = (const float*)d_in[10];
  const float* dw0  = (const float*)d_in[11];
  const float* db0  = (const float*)d_in[12];
  const float* dw1  = (const float*)d_in[13];
  const float* db1  = (const float*)d_in[14];
  const float* dw2  = (const float*)d_in[15];
  const float* db2  = (const float*)d_in[16];
  const float* cb   = (const float*)d_in[17];
  float* out = (float*)d_out;

  // ---- workspace carve-up (~114 MB) ----
  float* z   = (float*)d_ws;                         // N x E fp32
  float* qz  = z  + (size_t)kN * kE;
  float* xn  = qz + (size_t)kN * kE;
  float* acc = xn + (size_t)kN * kE;                 // 1024
  float* pairsum = acc + 1024;                       // 4096 (cnt + E live here)
  int*   flagcnt = (int*)(pairsum + 4096);           // 64 (1 used)
  int*   flags   = flagcnt + 64;                     // kN ints
  unsigned short* xqb  = (unsigned short*)(flags + kN);     // N x E bf16
  unsigned short* wt0h = xqb  + (size_t)kN * kE;     // enc w0^T hi 2048x768
  unsigned short* wt0l = wt0h + (size_t)kH1 * kIN;
  unsigned short* wt1h = wt0l + (size_t)kH1 * kIN;   // 1024x2048
  unsigned short* wt1l = wt1h + (size_t)kH2 * kH1;
  unsigned short* wt2h = wt1l + (size_t)kH2 * kH1;   // 64x1024
  unsigned short* wt2l = wt2h + (size_t)kE * kH2;
  unsigned short* wt3  = wt2l + (size_t)kE * kH2;    // dec w0^T 1024x64
  unsigned short* wt4  = wt3  + (size_t)kH2 * kE;    // dec w1^T 2048x1024
  unsigned short* wt5  = wt4  + (size_t)kH1 * kH2;   // dec w2^T 768x2048
  // chunk scratch (union across phases), 4096-row chunks
  unsigned short* xh  = wt5 + (size_t)kIN * kH1;     // 4096x768
  unsigned short* xl  = xh + (size_t)kCh * kIN;
  unsigned short* h1h = xl + (size_t)kCh * kIN;      // 4096x2048
  unsigned short* h1l = h1h + (size_t)kCh * kH1;
  unsigned short* h2h = h1l + (size_t)kCh * kH1;     // 4096x1024
  unsigned short* h2l = h2h + (size_t)kCh * kH2;
  // fix-chain scratch: aliases chunk scratch (dead between x-enc and decoder).
  float* h1f = (float*)xh;
  float* h2f = h1f + (size_t)kMaxFix * kH1;
  // code-LSE scratch: cnt + E carved from the (zeroed) pairsum region
  int*   cnt = (int*)pairsum;          // 256 ints
  float* E   = pairsum + 256;          // 256 floats

  hipMemsetAsync(acc, 0, (1024 + 4096 + 64) * sizeof(float), stream);

  // weight transposes: encoder split, decoder single
  transpose_bf16_split<<<dim3(kH1 / 32, kIN / 32), 256, 0, stream>>>(ew0, wt0h, wt0l, kIN, kH1);
  transpose_bf16_split<<<dim3(kH2 / 32, kH1 / 32), 256, 0, stream>>>(ew1, wt1h, wt1l, kH1, kH2);
  transpose_bf16_split<<<dim3(kE / 32, kH2 / 32), 256, 0, stream>>>(ew2, wt2h, wt2l, kH2, kE);
  transpose_bf16<<<dim3(kH2 / 32, kE / 32), 256, 0, stream>>>(dw0, wt3, kE, kH2);
  transpose_bf16<<<dim3(kH1 / 32, kH2 / 32), 256, 0, stream>>>(dw1, wt4, kH2, kH1);
  transpose_bf16<<<dim3(kIN / 32, kH1 / 32), 256, 0, stream>>>(dw2, wt5, kH1, kIN);

  // x-encoder (split-bf16 MFMA) -> z fp32
  for (int c = 0; c < kN / kCh; ++c) {
    conv_split<<<(kCh * kIN / 4 + 255) / 256, 256, 0, stream>>>(
        x + (size_t)c * kCh * kIN, xh, xl, kCh * kIN / 4);
    gemm_bt_split<128, 128, 64, true, 2>
        <<<dim3(kH1 / 128, kCh / 128), 256, 0, stream>>>(
            xh, xl, wt0h, wt0l, eb0, nullptr, h1h, h1l, kH1, kIN);
    gemm_bt_split<128, 128, 64, true, 2>
        <<<dim3(kH2 / 128, kCh / 128), 256, 0, stream>>>(
            h1h, h1l, wt1h, wt1l, eb1, nullptr, h2h, h2l, kH2, kH1);
    gemm_bt_split<128, 64, 64, false, 0>
        <<<dim3(kE / 64, kCh / 128), 256, 0, stream>>>(
            h2h, h2l, wt2h, wt2l, eb2, z + (size_t)c * kCh * kE, nullptr, nullptr,
            kE, kH2);
  }

  // VQ with gap-flagging, then exact fp32 fix for flagged rows
  vq_kernel<<<512, 256, 0, stream>>>(z, cb, out + OFF_IDX, out + OFF_XQ, xqb, xn,
                                     acc, flags, flagcnt);
  fix_mlp<kIN, kH1, true><<<1024, 256, 0, stream>>>(x, ew0, eb0, flags, flagcnt, h1f);
  fix_mlp<kH1, kH2, false><<<1024, 256, 0, stream>>>(h1f, ew1, eb1, flags, flagcnt, h2f);
  fix_z<<<512, 256, 0, stream>>>(h2f, ew2, eb2, cb, flags, flagcnt, z,
                                 out + OFF_IDX, out + OFF_XQ, xqb, xn, acc);
  // fallback for pathological flag counts (> kMaxFix); no-op otherwise
  fix_rows<<<64, 256, 0, stream>>>(x, ew0, eb0, ew1, eb1, ew2, eb2, cb, flags,
                                   flagcnt, z, out + OFF_IDX, out + OFF_XQ, xqb,
                                   xn, acc);

  // decoder (bf16 MFMA) on x_q_st -> out
  for (int c = 0; c < kN / kCh; ++c) {
    gemm_bt<128, 128, 64, true, false, true>
        <<<dim3(kH2 / 128, kCh / 128), 256, 0, stream>>>(
            xqb + (size_t)c * kCh * kE, wt3, db0, nullptr, h2h, kH2, kE);
    gemm_bt<128, 128, 64, true, false, true>
        <<<dim3(kH1 / 128, kCh / 128), 256, 0, stream>>>(
            h2h, wt4, db1, nullptr, h1h, kH1, kH2);
    gemm_bt<128, 128, 64, false, true, false>
        <<<dim3(kIN / 128, kCh / 128), 256, 0, stream>>>(
            h1h, wt5, db2, out + OFF_OUT + (size_t)c * kCh * kIN, nullptr, kIN, kH1);
  }

  // q-encoder (bf16 MFMA) -> qz
  for (int c = 0; c < kN / kCh; ++c) {
    conv_bf16<<<(kCh * kIN / 4 + 255) / 256, 256, 0, stream>>>(
        qe + (size_t)c * kCh * kIN, xh, kCh * kIN / 4);
    gemm_bt<128, 128, 64, true, false, true>
        <<<dim3(kH1 / 128, kCh / 128), 256, 0, stream>>>(
            xh, wt0h, eb0, nullptr, h1h, kH1, kIN);
    gemm_bt<128, 128, 64, true, false, true>
        <<<dim3(kH2 / 128, kCh / 128), 256, 0, stream>>>(
            h1h, wt1h, eb1, nullptr, h2h, kH2, kH1);
    gemm_bt<128, 64, 64, false, true, false>
        <<<dim3(kE / 64, kCh / 128), 256, 0, stream>>>(
            h2h, wt2h, eb2, qz + (size_t)c * kCh * kE, nullptr, kE, kH2);
  }

  // small loss kernels (all after fix chain: z/xn/idx final)
  qd_kernel<<<kN / 4, 256, 0, stream>>>(z, qz, qdw, acc + 256);
  trip_kernel<<<kTT / 4, 256, 0, stream>>>(z, trs, acc + 512);
  pos_kernel<<<kKP / 4, 256, 0, stream>>>(xn, prs, acc + 768);
  // code-space LSE: histogram -> 256x256 exp table -> per-pair log
  hist_kernel<<<kN / 256, 256, 0, stream>>>(out + OFF_IDX, cnt);
  code_lse<<<kNE, 256, 0, stream>>>(cb, cnt, E);
  pair_log<<<kKP / 256, 256, 0, stream>>>(out + OFF_IDX, prs, E, acc + 768);

  finalize_kernel<<<1, 256, 0, stream>>>(acc, out);
}

// Round 5
// 2711.145 us; speedup vs baseline: 1.3383x; 1.0674x over previous
//
#include <hip/hip_runtime.h>
#include <hip/hip_bf16.h>

// ---------------- problem constants ----------------
namespace {
constexpr int kN = 32768, kIN = 768, kH1 = 2048, kH2 = 1024, kE = 64, kNE = 256;
constexpr int kKP = 4096, kTT = 8192;
constexpr int kCh = 4096;  // rows per GEMM slice
constexpr int kMaxFix = 4096;  // rows handled by the fast fix chain

// flat float32 offsets in d_out, reference return order
constexpr size_t OFF_OUT = 0;
constexpr size_t OFF_VQ  = (size_t)kN * kIN;
constexpr size_t OFF_IDX = OFF_VQ + 1;
constexpr size_t OFF_XQ  = OFF_IDX + (size_t)kN;
constexpr size_t OFF_OCL = OFF_XQ + (size_t)kN * kE;
constexpr size_t OFF_ITL = OFF_OCL + 1;
constexpr size_t OFF_QDA = OFF_ITL + 1;
}  // namespace

typedef short bf16x8 __attribute__((ext_vector_type(8)));
typedef float f32x4 __attribute__((ext_vector_type(4)));

__device__ __forceinline__ unsigned short f2bf(float v) {
  __hip_bfloat16 h = __float2bfloat16(v);
  return *reinterpret_cast<unsigned short*>(&h);
}
__device__ __forceinline__ float bf2f(unsigned short u) {
  __hip_bfloat16 h = *reinterpret_cast<__hip_bfloat16*>(&u);
  return __bfloat162float(h);
}

__device__ __forceinline__ void gload_lds16(const void* g, void* lds) {
  __builtin_amdgcn_global_load_lds(
      (const __attribute__((address_space(1))) void*)g,
      (__attribute__((address_space(3))) void*)lds, 16, 0, 0);
}

// XCD-aware block swizzle (T1): valid when total workgroups % 8 == 0.
__device__ __forceinline__ void xcd_swizzle(int& bx, int& by) {
  int gx = gridDim.x, gy = gridDim.y;
  int nwg = gx * gy;
  if (nwg & 7) return;  // not divisible; keep default
  int bid = by * gx + bx;
  int cpx = nwg >> 3;
  int swz = (bid & 7) * cpx + (bid >> 3);
  bx = swz % gx;
  by = swz / gx;
}

// ---------------- bf16 MFMA GEMM: C = relu?(A @ Bt^T + bias) ----------------
// A: MxK bf16 row-major. Bt: NxK bf16 row-major. 4 waves in 2x2; 16x16x32 MFMA.
template <int BM, int BN, int BK, bool RELU, bool OUTF, bool OUTB>
__global__ __launch_bounds__(256) void gemm_bt(const unsigned short* __restrict__ A,
                                               const unsigned short* __restrict__ Bt,
                                               const float* __restrict__ bias,
                                               float* __restrict__ Cf,
                                               unsigned short* __restrict__ Cb,
                                               int N, int K) {
  constexpr int WM = BM / 2, WN = BN / 2, TMt = WM / 16, TNt = WN / 16;
  constexpr int CH = BK / 8;
  constexpr int RA = BM * BK / 2048, RB = BN * BK / 2048;
  __shared__ unsigned short As[BM * BK];
  __shared__ unsigned short Bs[BN * BK];
  const int tid = threadIdx.x, lane = tid & 63, wave = tid >> 6;
  const int wm = (wave >> 1) * WM, wn = (wave & 1) * WN;
  const int l15 = lane & 15, quad = lane >> 4;
  int bxs = blockIdx.x, bys = blockIdx.y;
  xcd_swizzle(bxs, bys);
  const int rowA0 = bys * BM, colB0 = bxs * BN;
  f32x4 acc[TMt][TNt];
#pragma unroll
  for (int i = 0; i < TMt; ++i)
#pragma unroll
    for (int j = 0; j < TNt; ++j) acc[i][j] = (f32x4){0.f, 0.f, 0.f, 0.f};

  const char* Ab = (const char*)A;
  const char* Bb = (const char*)Bt;
  char* AsB = (char*)As;
  char* BsB = (char*)Bs;

  for (int k0 = 0; k0 < K; k0 += BK) {
    if (k0) __syncthreads();
#pragma unroll
    for (int r = 0; r < RA; ++r) {
      int off = (r * 256 + tid) * 16;
      int row = off / (BK * 2);
      int sc = ((off >> 4) ^ row) & (CH - 1);
      gload_lds16(Ab + (size_t)(rowA0 + row) * (K * 2) + (size_t)k0 * 2 + sc * 16,
                  AsB + off);
    }
#pragma unroll
    for (int r = 0; r < RB; ++r) {
      int off = (r * 256 + tid) * 16;
      int row = off / (BK * 2);
      int sc = ((off >> 4) ^ row) & (CH - 1);
      gload_lds16(Bb + (size_t)(colB0 + row) * (K * 2) + (size_t)k0 * 2 + sc * 16,
                  BsB + off);
    }
    __syncthreads();
#pragma unroll
    for (int ks = 0; ks < BK; ks += 32) {
      bf16x8 af[TMt], bfr[TNt];
#pragma unroll
      for (int i = 0; i < TMt; ++i) {
        int row = wm + i * 16 + l15;
        int c = (((ks >> 3) + quad) ^ row) & (CH - 1);
        af[i] = *(const bf16x8*)(AsB + row * (BK * 2) + c * 16);
      }
#pragma unroll
      for (int j = 0; j < TNt; ++j) {
        int col = wn + j * 16 + l15;
        int c = (((ks >> 3) + quad) ^ col) & (CH - 1);
        bfr[j] = *(const bf16x8*)(BsB + col * (BK * 2) + c * 16);
      }
#pragma unroll
      for (int i = 0; i < TMt; ++i)
#pragma unroll
        for (int j = 0; j < TNt; ++j)
          acc[i][j] = __builtin_amdgcn_mfma_f32_16x16x32_bf16(af[i], bfr[j],
                                                              acc[i][j], 0, 0, 0);
    }
  }
#pragma unroll
  for (int j = 0; j < TNt; ++j) {
    int col = colB0 + wn + j * 16 + l15;
    float bv = bias[col];
#pragma unroll
    for (int i = 0; i < TMt; ++i) {
      int rbase = rowA0 + wm + i * 16 + quad * 4;
#pragma unroll
      for (int r = 0; r < 4; ++r) {
        float v = acc[i][j][r] + bv;
        if (RELU) v = fmaxf(v, 0.f);
        size_t o = (size_t)(rbase + r) * N + col;
        if (OUTF) Cf[o] = v;
        if (OUTB) Cb[o] = f2bf(v);
      }
    }
  }
}

// ---------------- split-bf16 MFMA GEMM (fp32-accurate x-path) ----------------
// C = relu?((Ah+Al) @ (Bh+Bl)^T + bias), dropping Al*Bl (err ~2^-18).
// OM: 0 = write fp32 C; 2 = write split bf16 (Ch, Cl).
template <int BM, int BN, int BK, bool RELU, int OM>
__global__ __launch_bounds__(256) void gemm_bt_split(
    const unsigned short* __restrict__ Ah, const unsigned short* __restrict__ Al,
    const unsigned short* __restrict__ Bh, const unsigned short* __restrict__ Bl,
    const float* __restrict__ bias, float* __restrict__ Cf,
    unsigned short* __restrict__ Ch, unsigned short* __restrict__ Cl,
    int N, int K) {
  constexpr int WM = BM / 2, WN = BN / 2, TMt = WM / 16, TNt = WN / 16;
  constexpr int CH = BK / 8;
  constexpr int RA = BM * BK / 2048, RB = BN * BK / 2048;
  __shared__ unsigned short AsH[BM * BK];
  __shared__ unsigned short AsL[BM * BK];
  __shared__ unsigned short BsH[BN * BK];
  __shared__ unsigned short BsL[BN * BK];
  const int tid = threadIdx.x, lane = tid & 63, wave = tid >> 6;
  const int wm = (wave >> 1) * WM, wn = (wave & 1) * WN;
  const int l15 = lane & 15, quad = lane >> 4;
  int bxs = blockIdx.x, bys = blockIdx.y;
  xcd_swizzle(bxs, bys);
  const int rowA0 = bys * BM, colB0 = bxs * BN;
  f32x4 acc[TMt][TNt];
#pragma unroll
  for (int i = 0; i < TMt; ++i)
#pragma unroll
    for (int j = 0; j < TNt; ++j) acc[i][j] = (f32x4){0.f, 0.f, 0.f, 0.f};

  const char* AhB = (const char*)Ah;
  const char* AlB = (const char*)Al;
  const char* BhB = (const char*)Bh;
  const char* BlB = (const char*)Bl;

  for (int k0 = 0; k0 < K; k0 += BK) {
    if (k0) __syncthreads();
#pragma unroll
    for (int r = 0; r < RA; ++r) {
      int off = (r * 256 + tid) * 16;
      int row = off / (BK * 2);
      int sc = ((off >> 4) ^ row) & (CH - 1);
      size_t go = (size_t)(rowA0 + row) * (K * 2) + (size_t)k0 * 2 + sc * 16;
      gload_lds16(AhB + go, (char*)AsH + off);
      gload_lds16(AlB + go, (char*)AsL + off);
    }
#pragma unroll
    for (int r = 0; r < RB; ++r) {
      int off = (r * 256 + tid) * 16;
      int row = off / (BK * 2);
      int sc = ((off >> 4) ^ row) & (CH - 1);
      size_t go = (size_t)(colB0 + row) * (K * 2) + (size_t)k0 * 2 + sc * 16;
      gload_lds16(BhB + go, (char*)BsH + off);
      gload_lds16(BlB + go, (char*)BsL + off);
    }
    __syncthreads();
#pragma unroll
    for (int ks = 0; ks < BK; ks += 32) {
      bf16x8 ah[TMt], al[TMt], bh[TNt], bl[TNt];
#pragma unroll
      for (int i = 0; i < TMt; ++i) {
        int row = wm + i * 16 + l15;
        int c = (((ks >> 3) + quad) ^ row) & (CH - 1);
        int off = row * (BK * 2) + c * 16;
        ah[i] = *(const bf16x8*)((const char*)AsH + off);
        al[i] = *(const bf16x8*)((const char*)AsL + off);
      }
#pragma unroll
      for (int j = 0; j < TNt; ++j) {
        int col = wn + j * 16 + l15;
        int c = (((ks >> 3) + quad) ^ col) & (CH - 1);
        int off = col * (BK * 2) + c * 16;
        bh[j] = *(const bf16x8*)((const char*)BsH + off);
        bl[j] = *(const bf16x8*)((const char*)BsL + off);
      }
#pragma unroll
      for (int i = 0; i < TMt; ++i)
#pragma unroll
        for (int j = 0; j < TNt; ++j) {
          acc[i][j] = __builtin_amdgcn_mfma_f32_16x16x32_bf16(ah[i], bh[j], acc[i][j], 0, 0, 0);
          acc[i][j] = __builtin_amdgcn_mfma_f32_16x16x32_bf16(ah[i], bl[j], acc[i][j], 0, 0, 0);
          acc[i][j] = __builtin_amdgcn_mfma_f32_16x16x32_bf16(al[i], bh[j], acc[i][j], 0, 0, 0);
        }
    }
  }
#pragma unroll
  for (int j = 0; j < TNt; ++j) {
    int col = colB0 + wn + j * 16 + l15;
    float bv = bias[col];
#pragma unroll
    for (int i = 0; i < TMt; ++i) {
      int rbase = rowA0 + wm + i * 16 + quad * 4;
#pragma unroll
      for (int r = 0; r < 4; ++r) {
        float v = acc[i][j][r] + bv;
        if (RELU) v = fmaxf(v, 0.f);
        size_t o = (size_t)(rbase + r) * N + col;
        if (OM == 0) {
          Cf[o] = v;
        } else {
          unsigned short hi = f2bf(v);
          Ch[o] = hi;
          Cl[o] = f2bf(v - bf2f(hi));
        }
      }
    }
  }
}

// ---------------- weight transpose fp32 KxN -> bf16 NxK (single) ------------
__global__ __launch_bounds__(256) void transpose_bf16(const float* __restrict__ W,
                                                      unsigned short* __restrict__ Wt,
                                                      int K, int N) {
  __shared__ float t[32][33];
  int bx = blockIdx.x * 32, by = blockIdx.y * 32;
  int tx = threadIdx.x & 31, ty = threadIdx.x >> 5;
#pragma unroll
  for (int i = 0; i < 32; i += 8)
    t[ty + i][tx] = W[(size_t)(by + ty + i) * N + bx + tx];
  __syncthreads();
#pragma unroll
  for (int i = 0; i < 32; i += 8)
    Wt[(size_t)(bx + ty + i) * K + by + tx] = f2bf(t[tx][ty + i]);
}

// ---------------- weight transpose fp32 KxN -> split bf16 NxK ---------------
__global__ __launch_bounds__(256) void transpose_bf16_split(
    const float* __restrict__ W, unsigned short* __restrict__ Wh,
    unsigned short* __restrict__ Wl, int K, int N) {
  __shared__ float t[32][33];
  int bx = blockIdx.x * 32, by = blockIdx.y * 32;
  int tx = threadIdx.x & 31, ty = threadIdx.x >> 5;
#pragma unroll
  for (int i = 0; i < 32; i += 8)
    t[ty + i][tx] = W[(size_t)(by + ty + i) * N + bx + tx];
  __syncthreads();
#pragma unroll
  for (int i = 0; i < 32; i += 8) {
    float v = t[tx][ty + i];
    unsigned short hi = f2bf(v);
    size_t o = (size_t)(bx + ty + i) * K + by + tx;
    Wh[o] = hi;
    Wl[o] = f2bf(v - bf2f(hi));
  }
}

// ---------------- fp32 -> bf16 convert (single) ----------------
__global__ __launch_bounds__(256) void conv_bf16(const float* __restrict__ in,
                                                 unsigned short* __restrict__ out,
                                                 int n4) {
  int i = (blockIdx.x * 256 + threadIdx.x);
  if (i < n4) {
    float4 v = *(const float4*)(in + (size_t)i * 4);
    unsigned short o[4] = {f2bf(v.x), f2bf(v.y), f2bf(v.z), f2bf(v.w)};
    *(uint2*)(out + (size_t)i * 4) = *(uint2*)o;
  }
}

// ---------------- fp32 -> split bf16 convert ----------------
__global__ __launch_bounds__(256) void conv_split(const float* __restrict__ in,
                                                  unsigned short* __restrict__ oh,
                                                  unsigned short* __restrict__ ol,
                                                  int n4) {
  int i = (blockIdx.x * 256 + threadIdx.x);
  if (i < n4) {
    float4 v = *(const float4*)(in + (size_t)i * 4);
    unsigned short h[4], l[4];
    float vv[4] = {v.x, v.y, v.z, v.w};
#pragma unroll
    for (int k = 0; k < 4; ++k) {
      h[k] = f2bf(vv[k]);
      l[k] = f2bf(vv[k] - bf2f(h[k]));
    }
    *(uint2*)(oh + (size_t)i * 4) = *(uint2*)h;
    *(uint2*)(ol + (size_t)i * 4) = *(uint2*)l;
  }
}

// ---------------- VQ: argmin over 256 codes + gap-flagging ----------------
// R2 structure (known-good 117 us, no spill): 512 blocks; codebook staged
// transposed in LDS; lane l owns codes 4l..4l+3 (f32x4 reads, conflict-free);
// dt[4] row batches (dt[8] spilled to scratch at VGPR=256 — R3 regression);
// per-wave shuffle top-2; same d arithmetic / tie-break / tau as original.
#define FMA4(a, s, v)              \
  a[0] = fmaf(s, v[0], a[0]);      \
  a[1] = fmaf(s, v[1], a[1]);      \
  a[2] = fmaf(s, v[2], a[2]);      \
  a[3] = fmaf(s, v[3], a[3])

__global__ __launch_bounds__(256) void vq_kernel(const float* __restrict__ z,
                                                 const float* __restrict__ cb,
                                                 float* __restrict__ idx_out,
                                                 float* __restrict__ xq_out,
                                                 unsigned short* __restrict__ xqb_out,
                                                 float* __restrict__ xn_out,
                                                 float* __restrict__ acc,
                                                 int* __restrict__ flags,
                                                 int* __restrict__ flagcnt) {
  __shared__ float cbT[kE * kNE];  // cbT[e*256 + c] = cb[c][e]  (64 KB)
  const int t = threadIdx.x;
  // stage codebook transposed: thread t owns code row t
  {
    const f32x4* src = (const f32x4*)(cb + (size_t)t * kE);
#pragma unroll
    for (int q = 0; q < 16; ++q) {
      f32x4 v = src[q];
      cbT[(4 * q + 0) * kNE + t] = v[0];
      cbT[(4 * q + 1) * kNE + t] = v[1];
      cbT[(4 * q + 2) * kNE + t] = v[2];
      cbT[(4 * q + 3) * kNE + t] = v[3];
    }
  }
  __syncthreads();
  const int l = t & 63, wv = t >> 6;
  // per-lane code norms (codes 4l..4l+3), same fmaf order as before
  f32x4 cn = (f32x4){0.f, 0.f, 0.f, 0.f};
  for (int e = 0; e < kE; ++e) {
    f32x4 cv = *(const f32x4*)&cbT[e * kNE + 4 * l];
    cn[0] = fmaf(cv[0], cv[0], cn[0]);
    cn[1] = fmaf(cv[1], cv[1], cn[1]);
    cn[2] = fmaf(cv[2], cv[2], cn[2]);
    cn[3] = fmaf(cv[3], cv[3], cn[3]);
  }
  const int rowBase = (blockIdx.x * 4 + wv) * 16;  // 512 blocks * 4 waves * 16 rows = 32768
  for (int p = 0; p < 4; ++p) {
    const int ra = rowBase + p * 4;
    f32x4 dt[4];
#pragma unroll
    for (int r = 0; r < 4; ++r) dt[r] = (f32x4){0.f, 0.f, 0.f, 0.f};
#pragma unroll
    for (int e4 = 0; e4 < 16; ++e4) {
      f32x4 c0 = *(const f32x4*)&cbT[(4 * e4 + 0) * kNE + 4 * l];
      f32x4 c1 = *(const f32x4*)&cbT[(4 * e4 + 1) * kNE + 4 * l];
      f32x4 c2 = *(const f32x4*)&cbT[(4 * e4 + 2) * kNE + 4 * l];
      f32x4 c3 = *(const f32x4*)&cbT[(4 * e4 + 3) * kNE + 4 * l];
#pragma unroll
      for (int r = 0; r < 4; ++r) {
        f32x4 zv = *(const f32x4*)(z + (size_t)(ra + r) * kE + e4 * 4);
        FMA4(dt[r], zv[0], c0);
        FMA4(dt[r], zv[1], c1);
        FMA4(dt[r], zv[2], c2);
        FMA4(dt[r], zv[3], c3);
      }
    }
#pragma unroll
    for (int r = 0; r < 4; ++r) {
      const int row = ra + r;
      // d = nrm - 2*dot, codes 4l..4l+3
      float d0 = cn[0] - 2.f * dt[r][0];
      float d1 = cn[1] - 2.f * dt[r][1];
      float d2 = cn[2] - 2.f * dt[r][2];
      float d3 = cn[3] - 2.f * dt[r][3];
      // lane-local top-2 (ascending index order; strict < keeps lowest idx)
      float m1 = d0, m2 = 3.4e38f;
      int i1 = 4 * l;
      if (d1 < m1) { m2 = m1; m1 = d1; i1 = 4 * l + 1; } else m2 = fminf(m2, d1);
      if (d2 < m1) { m2 = m1; m1 = d2; i1 = 4 * l + 2; } else m2 = fminf(m2, d2);
      if (d3 < m1) { m2 = m1; m1 = d3; i1 = 4 * l + 3; } else m2 = fminf(m2, d3);
      // cross-lane top-2 butterfly (all lanes converge)
#pragma unroll
      for (int m = 32; m > 0; m >>= 1) {
        float om1 = __shfl_xor(m1, m);
        int oi1 = __shfl_xor(i1, m);
        float om2 = __shfl_xor(m2, m);
        float nm2 = fminf(fminf(m2, om2), fmaxf(m1, om1));
        if (om1 < m1 || (om1 == m1 && oi1 < i1)) { m1 = om1; i1 = oi1; }
        m2 = nm2;
      }
      // zn for tau
      float zl = z[(size_t)row * kE + l];
      float zn = zl * zl;
#pragma unroll
      for (int m = 32; m > 0; m >>= 1) zn += __shfl_xor(zn, m);
      float tau = 5e-5f * sqrtf(zn);
      if (m2 - m1 < tau) {
        if (l == 0) {
          int slot = atomicAdd(flagcnt, 1);
          flags[slot] = row;
        }
        continue;
      }
      const int best = i1;
      if (l == 0) idx_out[row] = (float)best;
      float xq = cb[(size_t)best * kE + l];
      xq_out[(size_t)row * kE + l] = xq;
      xqb_out[(size_t)row * kE + l] = f2bf(xq);
      float dd = xq - zl;
      float sq = dd * dd;
      float nq = xq * xq;
#pragma unroll
      for (int m = 32; m > 0; m >>= 1) {
        sq += __shfl_xor(sq, m);
        nq += __shfl_xor(nq, m);
      }
      float inv = 1.f / fmaxf(sqrtf(nq), 1e-12f);
      xn_out[(size_t)row * kE + l] = xq * inv;
      if (l == 0) atomicAdd(&acc[row & 255], sq);
    }
  }
}
#undef FMA4

// ---------------- fix MLP layer: H = relu(X[rows] @ W + b) ------------------
// R=16 rows/row-block, JC=64 cols, 4 waves split each 256-k chunk, ordered
// cross-wave LDS reduce (deterministic). 36 KB LDS -> 4 blocks/CU.
template <int K, int OUTN, bool GATHER>
__global__ __launch_bounds__(256) void fix_mlp(
    const float* __restrict__ X, const float* __restrict__ W,
    const float* __restrict__ bias, const int* __restrict__ flags,
    const int* __restrict__ flagcnt, float* __restrict__ H) {
  constexpr int R = 16, JC = 64, KC = 256;
  constexpr int NJC = OUTN / JC;
  constexpr int NKC = K / KC;
  constexpr int PAD = 20;  // xs row stride: 16B-aligned f32x4 reads, 8-bank write spread
  __shared__ float xs[KC * PAD];     // 20 KB
  __shared__ float red[4 * R * JC];  // 16 KB
  const int t = threadIdx.x;
  const int lane = t & 63, w = t >> 6;
  int cnt = *flagcnt;
  if (cnt > kMaxFix) cnt = kMaxFix;
  const int nrb = (cnt + R - 1) / R;
  const int nwork = nrb * NJC;
  for (int item = blockIdx.x; item < nwork; item += gridDim.x) {
    const int rb = item / NJC, jc = item % NJC;
    const int j = jc * JC + lane;
    float acc[R];
#pragma unroll
    for (int r = 0; r < R; ++r) acc[r] = 0.f;
    for (int kc = 0; kc < NKC; ++kc) {
      __syncthreads();  // xs/red reuse barrier
      for (int i = t; i < R * KC; i += 256) {
        int r = i >> 8;   // i / KC
        int k = i & 255;  // i % KC
        int row = rb * R + r;
        if (row >= cnt) row = cnt - 1;
        const float* src = GATHER ? (X + (size_t)flags[row] * K)
                                  : (X + (size_t)row * K);
        xs[k * PAD + r] = src[kc * KC + k];
      }
      __syncthreads();
      // wave w handles k in [w*64, w*64+64) of this chunk
      const float* wp = W + (size_t)(kc * KC + w * 64) * OUTN + j;
#pragma unroll 4
      for (int k = 0; k < 64; ++k) {
        float wv = wp[(size_t)k * OUTN];
        const float* xp = &xs[(w * 64 + k) * PAD];
        f32x4 x0 = *(const f32x4*)(xp + 0);
        f32x4 x1 = *(const f32x4*)(xp + 4);
        f32x4 x2 = *(const f32x4*)(xp + 8);
        f32x4 x3 = *(const f32x4*)(xp + 12);
        acc[0] = fmaf(x0[0], wv, acc[0]);
        acc[1] = fmaf(x0[1], wv, acc[1]);
        acc[2] = fmaf(x0[2], wv, acc[2]);
        acc[3] = fmaf(x0[3], wv, acc[3]);
        acc[4] = fmaf(x1[0], wv, acc[4]);
        acc[5] = fmaf(x1[1], wv, acc[5]);
        acc[6] = fmaf(x1[2], wv, acc[6]);
        acc[7] = fmaf(x1[3], wv, acc[7]);
        acc[8] = fmaf(x2[0], wv, acc[8]);
        acc[9] = fmaf(x2[1], wv, acc[9]);
        acc[10] = fmaf(x2[2], wv, acc[10]);
        acc[11] = fmaf(x2[3], wv, acc[11]);
        acc[12] = fmaf(x3[0], wv, acc[12]);
        acc[13] = fmaf(x3[1], wv, acc[13]);
        acc[14] = fmaf(x3[2], wv, acc[14]);
        acc[15] = fmaf(x3[3], wv, acc[15]);
      }
    }
    __syncthreads();
#pragma unroll
    for (int r = 0; r < R; ++r) red[(w * R + r) * JC + lane] = acc[r];
    __syncthreads();
    // ordered sum: bias + p(wave0) + p(wave1) + p(wave2) + p(wave3)
#pragma unroll
    for (int r4 = 0; r4 < 4; ++r4) {
      int r = w * 4 + r4;
      int row = rb * R + r;
      if (row < cnt) {
        float s = bias[j] + red[(0 * R + r) * JC + lane] +
                  red[(1 * R + r) * JC + lane] + red[(2 * R + r) * JC + lane] +
                  red[(3 * R + r) * JC + lane];
        H[(size_t)row * OUTN + j] = fmaxf(s, 0.f);
      }
    }
  }
}

// ---------------- fix phase C: z + argmin + outputs (1 block / row) ---------
__global__ __launch_bounds__(256) void fix_z(
    const float* __restrict__ h2f, const float* __restrict__ ew2,
    const float* __restrict__ eb2, const float* __restrict__ cb,
    const int* __restrict__ flags, const int* __restrict__ flagcnt,
    float* __restrict__ z, float* __restrict__ idx_out,
    float* __restrict__ xq_out, unsigned short* __restrict__ xqb_out,
    float* __restrict__ xn_out, float* __restrict__ acc) {
  __shared__ float hrow[kH2];
  __shared__ float sred[256];
  __shared__ float szs[kE];
  __shared__ float rv[256];
  __shared__ int ri[256];
  const int t = threadIdx.x;
  int cnt = *flagcnt;
  if (cnt > kMaxFix) cnt = kMaxFix;
  for (int fi = blockIdx.x; fi < cnt; fi += gridDim.x) {
    const int r = flags[fi];
    for (int q = t; q < kH2; q += 256) hrow[q] = h2f[(size_t)fi * kH2 + q];
    __syncthreads();
    {
      const int j = t & 63, p = t >> 6;
      float s = 0.f;
      for (int k = p * 256; k < p * 256 + 256; ++k)
        s = fmaf(hrow[k], ew2[(size_t)k * kE + j], s);
      sred[t] = s;
      __syncthreads();
      if (t < kE) {
        float zv = sred[t] + sred[t + 64] + sred[t + 128] + sred[t + 192] + eb2[t];
        szs[t] = zv;
        z[(size_t)r * kE + t] = zv;
      }
      __syncthreads();
    }
    {
      float dot = 0.f, nrm = 0.f;
      const float* c = cb + (size_t)t * kE;
#pragma unroll 8
      for (int e = 0; e < kE; ++e) {
        float ce = c[e];
        dot = fmaf(szs[e], ce, dot);
        nrm = fmaf(ce, ce, nrm);
      }
      rv[t] = nrm - 2.f * dot;
      ri[t] = t;
      __syncthreads();
      for (int s = 128; s > 0; s >>= 1) {
        if (t < s) {
          float v2 = rv[t + s];
          int i2 = ri[t + s];
          if (v2 < rv[t] || (v2 == rv[t] && i2 < ri[t])) { rv[t] = v2; ri[t] = i2; }
        }
        __syncthreads();
      }
      const int best = ri[0];
      if (t == 0) idx_out[r] = (float)best;
      if (t < kE) {
        float xq = cb[(size_t)best * kE + t];
        xq_out[(size_t)r * kE + t] = xq;
        xqb_out[(size_t)r * kE + t] = f2bf(xq);
        float dd = xq - szs[t];
        float sq = dd * dd;
        float nq = xq * xq;
#pragma unroll
        for (int m = 32; m > 0; m >>= 1) {
          sq += __shfl_xor(sq, m);
          nq += __shfl_xor(nq, m);
        }
        float inv = 1.f / fmaxf(sqrtf(nq), 1e-12f);
        xn_out[(size_t)r * kE + t] = xq * inv;
        if (t == 0) atomicAdd(&acc[r & 255], sq);
      }
      __syncthreads();
    }
  }
}

// ---------------- fallback: exact fp32 MLP for rows >= kMaxFix --------------
__global__ __launch_bounds__(256) void fix_rows(
    const float* __restrict__ x, const float* __restrict__ ew0,
    const float* __restrict__ eb0, const float* __restrict__ ew1,
    const float* __restrict__ eb1, const float* __restrict__ ew2,
    const float* __restrict__ eb2, const float* __restrict__ cb,
    const int* __restrict__ flags, const int* __restrict__ flagcnt,
    float* __restrict__ z, float* __restrict__ idx_out,
    float* __restrict__ xq_out, unsigned short* __restrict__ xqb_out,
    float* __restrict__ xn_out, float* __restrict__ acc) {
  __shared__ float xs[kIN];
  __shared__ float sh1[kH1];
  __shared__ float sh2[kH2];
  __shared__ float sred[256];
  __shared__ float szs[kE];
  __shared__ float rv[256];
  __shared__ int ri[256];
  const int t = threadIdx.x;
  const int cnt = *flagcnt;
  for (int fi = kMaxFix + blockIdx.x; fi < cnt; fi += gridDim.x) {
    const int r = flags[fi];
    for (int q = t; q < kIN; q += 256) xs[q] = x[(size_t)r * kIN + q];
    __syncthreads();
#pragma unroll
    for (int o = 0; o < kH1 / 256; ++o) {
      int j = t + 256 * o;
      float s = eb0[j];
      for (int k = 0; k < kIN; ++k) s = fmaf(xs[k], ew0[(size_t)k * kH1 + j], s);
      sh1[j] = fmaxf(s, 0.f);
    }
    __syncthreads();
#pragma unroll
    for (int o = 0; o < kH2 / 256; ++o) {
      int j = t + 256 * o;
      float s = eb1[j];
      for (int k = 0; k < kH1; ++k) s = fmaf(sh1[k], ew1[(size_t)k * kH2 + j], s);
      sh2[j] = fmaxf(s, 0.f);
    }
    __syncthreads();
    {
      int j = t & 63, p = t >> 6;
      float s = 0.f;
      for (int k = p * 256; k < p * 256 + 256; ++k)
        s = fmaf(sh2[k], ew2[(size_t)k * kE + j], s);
      sred[t] = s;
      __syncthreads();
      if (t < kE) {
        float zv = sred[t] + sred[t + 64] + sred[t + 128] + sred[t + 192] + eb2[t];
        szs[t] = zv;
        z[(size_t)r * kE + t] = zv;
      }
      __syncthreads();
    }
    {
      float dot = 0.f, nrm = 0.f;
      const float* c = cb + (size_t)t * kE;
#pragma unroll 8
      for (int e = 0; e < kE; ++e) {
        float ce = c[e];
        dot = fmaf(szs[e], ce, dot);
        nrm = fmaf(ce, ce, nrm);
      }
      rv[t] = nrm - 2.f * dot;
      ri[t] = t;
      __syncthreads();
      for (int s = 128; s > 0; s >>= 1) {
        if (t < s) {
          float v2 = rv[t + s];
          int i2 = ri[t + s];
          if (v2 < rv[t] || (v2 == rv[t] && i2 < ri[t])) { rv[t] = v2; ri[t] = i2; }
        }
        __syncthreads();
      }
      const int best = ri[0];
      if (t == 0) idx_out[r] = (float)best;
      if (t < kE) {
        float xq = cb[(size_t)best * kE + t];
        xq_out[(size_t)r * kE + t] = xq;
        xqb_out[(size_t)r * kE + t] = f2bf(xq);
        float dd = xq - szs[t];
        float sq = dd * dd;
        float nq = xq * xq;
#pragma unroll
        for (int m = 32; m > 0; m >>= 1) {
          sq += __shfl_xor(sq, m);
          nq += __shfl_xor(nq, m);
        }
        float inv = 1.f / fmaxf(sqrtf(nq), 1e-12f);
        xn_out[(size_t)r * kE + t] = xq * inv;
        if (t == 0) atomicAdd(&acc[r & 255], sq);
      }
      __syncthreads();
    }
  }
}

// ---------------- qd_align ----------------
__global__ __launch_bounds__(256) void qd_kernel(const float* __restrict__ z,
                                                 const float* __restrict__ qz,
                                                 const float* __restrict__ w,
                                                 float* __restrict__ acc) {
  const int i = blockIdx.x * 4 + (threadIdx.x >> 6);
  const int l = threadIdx.x & 63;
  float a = z[(size_t)i * kE + l];
  float b = qz[(size_t)i * kE + l];
  float dot = a * b, na = a * a, nb = b * b;
#pragma unroll
  for (int m = 32; m > 0; m >>= 1) {
    dot += __shfl_xor(dot, m);
    na += __shfl_xor(na, m);
    nb += __shfl_xor(nb, m);
  }
  if (l == 0) {
    float cosv = dot / fmaxf(sqrtf(na) * sqrtf(nb), 1e-8f);
    atomicAdd(&acc[i & 255], w[i] * cosv);
  }
}

// ---------------- triplet ----------------
__global__ __launch_bounds__(256) void trip_kernel(const float* __restrict__ z,
                                                   const int* __restrict__ tr,
                                                   float* __restrict__ acc) {
  const int t = blockIdx.x * 4 + (threadIdx.x >> 6);
  const int l = threadIdx.x & 63;
  int ia = tr[3 * t], ip = tr[3 * t + 1], in2 = tr[3 * t + 2];
  float a = z[(size_t)ia * kE + l];
  float p = z[(size_t)ip * kE + l];
  float n = z[(size_t)in2 * kE + l];
  float d1 = (a - p) * (a - p);
  float d2 = (a - n) * (a - n);
#pragma unroll
  for (int m = 32; m > 0; m >>= 1) {
    d1 += __shfl_xor(d1, m);
    d2 += __shfl_xor(d2, m);
  }
  if (l == 0) {
    float dp = sqrtf(d1 + 1e-12f);
    float dn = sqrtf(d2 + 1e-12f);
    atomicAdd(&acc[t & 255], fmaxf(dp - dn + 0.2f, 0.f));
  }
}

// ---------------- pairs: subtract positive sim ----------------
__global__ __launch_bounds__(256) void pos_kernel(const float* __restrict__ xn,
                                                  const int* __restrict__ pairs,
                                                  float* __restrict__ acc) {
  const int k = blockIdx.x * 4 + (threadIdx.x >> 6);
  const int l = threadIdx.x & 63;
  int i0 = pairs[2 * k], i1 = pairs[2 * k + 1];
  float v = xn[(size_t)i0 * kE + l] * xn[(size_t)i1 * kE + l];
#pragma unroll
  for (int m = 32; m > 0; m >>= 1) v += __shfl_xor(v, m);
  if (l == 0) atomicAdd(&acc[k & 255], -10.f * v);
}

// ---------------- code-space LSE ----------------
// histogram of final idx over all N rows
__global__ __launch_bounds__(256) void hist_kernel(const float* __restrict__ idx_out,
                                                   int* __restrict__ cnt) {
  __shared__ int h[kNE];
  const int t = threadIdx.x;
  h[t] = 0;
  __syncthreads();
  int i = blockIdx.x * 256 + t;
  atomicAdd(&h[(int)idx_out[i]], 1);
  __syncthreads();
  if (h[t]) atomicAdd(&cnt[t], h[t]);
}

// E[a] = sum_c cnt[c] * exp(10 * <cbn[a], cbn[c]>); one block per code a
__global__ __launch_bounds__(256) void code_lse(const float* __restrict__ cb,
                                                const int* __restrict__ cnt,
                                                float* __restrict__ E) {
  __shared__ float cbn[kNE][kE + 1];
  __shared__ float red[256];
  const int t = threadIdx.x, a = blockIdx.x;
  const float* r = cb + (size_t)t * kE;
  float s = 0.f;
#pragma unroll 8
  for (int e = 0; e < kE; ++e) s = fmaf(r[e], r[e], s);
  float inv = 1.f / fmaxf(sqrtf(s), 1e-12f);
#pragma unroll 8
  for (int e = 0; e < kE; ++e) cbn[t][e] = r[e] * inv;
  __syncthreads();
  float dot = 0.f;
#pragma unroll 8
  for (int e = 0; e < kE; ++e) dot = fmaf(cbn[a][e], cbn[t][e], dot);
  red[t] = (float)cnt[t] * expf(10.f * dot);
  __syncthreads();
  for (int sred = 128; sred > 0; sred >>= 1) {
    if (t < sred) red[t] += red[t + sred];
    __syncthreads();
  }
  if (t == 0) E[a] = red[0];
}

// acc += log(E[code(anchor_p)]) for each pair
__global__ __launch_bounds__(256) void pair_log(const float* __restrict__ idx_out,
                                                const int* __restrict__ pairs,
                                                const float* __restrict__ E,
                                                float* __restrict__ acc) {
  int p = blockIdx.x * 256 + threadIdx.x;
  int a = (int)idx_out[pairs[2 * p]];
  atomicAdd(&acc[p & 255], logf(E[a]));
}

// ---------------- finalize scalars ----------------
__global__ __launch_bounds__(256) void finalize_kernel(const float* __restrict__ acc,
                                                       float* __restrict__ out) {
  const int t = threadIdx.x;
  float vq = acc[t], qd = acc[256 + t], tr = acc[512 + t], ou = acc[768 + t];
#pragma unroll
  for (int m = 32; m > 0; m >>= 1) {
    vq += __shfl_xor(vq, m);
    qd += __shfl_xor(qd, m);
    tr += __shfl_xor(tr, m);
    ou += __shfl_xor(ou, m);
  }
  __shared__ float sm[4][4];
  const int w = t >> 6;
  if ((t & 63) == 0) { sm[0][w] = vq; sm[1][w] = qd; sm[2][w] = tr; sm[3][w] = ou; }
  __syncthreads();
  if (t == 0) {
    float svq = sm[0][0] + sm[0][1] + sm[0][2] + sm[0][3];
    float sqd = sm[1][0] + sm[1][1] + sm[1][2] + sm[1][3];
    float str = sm[2][0] + sm[2][1] + sm[2][2] + sm[2][3];
    float sou = sm[3][0] + sm[3][1] + sm[3][2] + sm[3][3];
    out[OFF_VQ]  = 1.001f * svq / (float)((size_t)kN * kE);
    out[OFF_OCL] = sou / (float)kKP;
    out[OFF_ITL] = str / (float)kTT;
    out[OFF_QDA] = 1.f - sqd / (float)kN;
  }
}

// ---------------- orchestration ----------------
extern "C" void kernel_launch(void* const* d_in, const int* in_sizes, int n_in,
                              void* d_out, int out_size, void* d_ws, size_t ws_size,
                              hipStream_t stream) {
  (void)in_sizes; (void)n_in; (void)out_size; (void)ws_size;
  const float* x    = (const float*)d_in[0];
  const float* qe   = (const float*)d_in[1];
  const float* qdw  = (const float*)d_in[2];
  const int*   prs  = (const int*)d_in[3];
  const int*   trs  = (const int*)d_in[4];
  const float* ew0  = (const float*)d_in[5];
  const float* eb0  = (const float*)d_in[6];
  const float* ew1  = (const float*)d_in[7];
  const float* eb1  = (const float*)d_in[8];
  const float* ew2  = (const float*)d_in[9];
  const float* eb2  = (const float*)d_in[10];
  const float* dw0  = (const float*)d_in[11];
  const float* db0  = (const float*)d_in[12];
  const float* dw1  = (const float*)d_in[13];
  const float* db1  = (const float*)d_in[14];
  const float* dw2  = (const float*)d_in[15];
  const float* db2  = (const float*)d_in[16];
  const float* cb   = (const float*)d_in[17];
  float* out = (float*)d_out;

  // ---- workspace carve-up (~114 MB) ----
  float* z   = (float*)d_ws;                         // N x E fp32
  float* qz  = z  + (size_t)kN * kE;
  float* xn  = qz + (size_t)kN * kE;
  float* acc = xn + (size_t)kN * kE;                 // 1024
  float* pairsum = acc + 1024;                       // 4096 (cnt + E live here)
  int*   flagcnt = (int*)(pairsum + 4096);           // 64 (1 used)
  int*   flags   = flagcnt + 64;                     // kN ints
  unsigned short* xqb  = (unsigned short*)(flags + kN);     // N x E bf16
  unsigned short* wt0h = xqb  + (size_t)kN * kE;     // enc w0^T hi 2048x768
  unsigned short* wt0l = wt0h + (size_t)kH1 * kIN;
  unsigned short* wt1h = wt0l + (size_t)kH1 * kIN;   // 1024x2048
  unsigned short* wt1l = wt1h + (size_t)kH2 * kH1;
  unsigned short* wt2h = wt1l + (size_t)kH2 * kH1;   // 64x1024
  unsigned short* wt2l = wt2h + (size_t)kE * kH2;
  unsigned short* wt3  = wt2l + (size_t)kE * kH2;    // dec w0^T 1024x64
  unsigned short* wt4  = wt3  + (size_t)kH2 * kE;    // dec w1^T 2048x1024
  unsigned short* wt5  = wt4  + (size_t)kH1 * kH2;   // dec w2^T 768x2048
  // chunk scratch (union across phases), 4096-row chunks
  unsigned short* xh  = wt5 + (size_t)kIN * kH1;     // 4096x768
  unsigned short* xl  = xh + (size_t)kCh * kIN;
  unsigned short* h1h = xl + (size_t)kCh * kIN;      // 4096x2048
  unsigned short* h1l = h1h + (size_t)kCh * kH1;
  unsigned short* h2h = h1l + (size_t)kCh * kH1;     // 4096x1024
  unsigned short* h2l = h2h + (size_t)kCh * kH2;
  // fix-chain scratch: aliases chunk scratch (dead between x-enc and decoder).
  float* h1f = (float*)xh;
  float* h2f = h1f + (size_t)kMaxFix * kH1;
  // code-LSE scratch: cnt + E carved from the (zeroed) pairsum region
  int*   cnt = (int*)pairsum;          // 256 ints
  float* E   = pairsum + 256;          // 256 floats

  hipMemsetAsync(acc, 0, (1024 + 4096 + 64) * sizeof(float), stream);

  // weight transposes: encoder split, decoder single
  transpose_bf16_split<<<dim3(kH1 / 32, kIN / 32), 256, 0, stream>>>(ew0, wt0h, wt0l, kIN, kH1);
  transpose_bf16_split<<<dim3(kH2 / 32, kH1 / 32), 256, 0, stream>>>(ew1, wt1h, wt1l, kH1, kH2);
  transpose_bf16_split<<<dim3(kE / 32, kH2 / 32), 256, 0, stream>>>(ew2, wt2h, wt2l, kH2, kE);
  transpose_bf16<<<dim3(kH2 / 32, kE / 32), 256, 0, stream>>>(dw0, wt3, kE, kH2);
  transpose_bf16<<<dim3(kH1 / 32, kH2 / 32), 256, 0, stream>>>(dw1, wt4, kH2, kH1);
  transpose_bf16<<<dim3(kIN / 32, kH1 / 32), 256, 0, stream>>>(dw2, wt5, kH1, kIN);

  // x-encoder (split-bf16 MFMA) -> z fp32
  for (int c = 0; c < kN / kCh; ++c) {
    conv_split<<<(kCh * kIN / 4 + 255) / 256, 256, 0, stream>>>(
        x + (size_t)c * kCh * kIN, xh, xl, kCh * kIN / 4);
    gemm_bt_split<128, 128, 64, true, 2>
        <<<dim3(kH1 / 128, kCh / 128), 256, 0, stream>>>(
            xh, xl, wt0h, wt0l, eb0, nullptr, h1h, h1l, kH1, kIN);
    gemm_bt_split<128, 128, 64, true, 2>
        <<<dim3(kH2 / 128, kCh / 128), 256, 0, stream>>>(
            h1h, h1l, wt1h, wt1l, eb1, nullptr, h2h, h2l, kH2, kH1);
    gemm_bt_split<128, 64, 64, false, 0>
        <<<dim3(kE / 64, kCh / 128), 256, 0, stream>>>(
            h2h, h2l, wt2h, wt2l, eb2, z + (size_t)c * kCh * kE, nullptr, nullptr,
            kE, kH2);
  }

  // VQ with gap-flagging, then exact fp32 fix for flagged rows
  vq_kernel<<<512, 256, 0, stream>>>(z, cb, out + OFF_IDX, out + OFF_XQ, xqb, xn,
                                     acc, flags, flagcnt);
  fix_mlp<kIN, kH1, true><<<1024, 256, 0, stream>>>(x, ew0, eb0, flags, flagcnt, h1f);
  fix_mlp<kH1, kH2, false><<<1024, 256, 0, stream>>>(h1f, ew1, eb1, flags, flagcnt, h2f);
  fix_z<<<512, 256, 0, stream>>>(h2f, ew2, eb2, cb, flags, flagcnt, z,
                                 out + OFF_IDX, out + OFF_XQ, xqb, xn, acc);
  // fallback for pathological flag counts (> kMaxFix); no-op otherwise
  fix_rows<<<64, 256, 0, stream>>>(x, ew0, eb0, ew1, eb1, ew2, eb2, cb, flags,
                                   flagcnt, z, out + OFF_IDX, out + OFF_XQ, xqb,
                                   xn, acc);

  // decoder (bf16 MFMA) on x_q_st -> out
  for (int c = 0; c < kN / kCh; ++c) {
    gemm_bt<128, 128, 64, true, false, true>
        <<<dim3(kH2 / 128, kCh / 128), 256, 0, stream>>>(
            xqb + (size_t)c * kCh * kE, wt3, db0, nullptr, h2h, kH2, kE);
    gemm_bt<128, 128, 64, true, false, true>
        <<<dim3(kH1 / 128, kCh / 128), 256, 0, stream>>>(
            h2h, wt4, db1, nullptr, h1h, kH1, kH2);
    gemm_bt<128, 128, 64, false, true, false>
        <<<dim3(kIN / 128, kCh / 128), 256, 0, stream>>>(
            h1h, wt5, db2, out + OFF_OUT + (size_t)c * kCh * kIN, nullptr, kIN, kH1);
  }

  // q-encoder (bf16 MFMA) -> qz
  for (int c = 0; c < kN / kCh; ++c) {
    conv_bf16<<<(kCh * kIN / 4 + 255) / 256, 256, 0, stream>>>(
        qe + (size_t)c * kCh * kIN, xh, kCh * kIN / 4);
    gemm_bt<128, 128, 64, true, false, true>
        <<<dim3(kH1 / 128, kCh / 128), 256, 0, stream>>>(
            xh, wt0h, eb0, nullptr, h1h, kH1, kIN);
    gemm_bt<128, 128, 64, true, false, true>
        <<<dim3(kH2 / 128, kCh / 128), 256, 0, stream>>>(
            h1h, wt1h, eb1, nullptr, h2h, kH2, kH1);
    gemm_bt<128, 64, 64, false, true, false>
        <<<dim3(kE / 64, kCh / 128), 256, 0, stream>>>(
            h2h, wt2h, eb2, qz + (size_t)c * kCh * kE, nullptr, kE, kH2);
  }

  // small loss kernels (all after fix chain: z/xn/idx final)
  qd_kernel<<<kN / 4, 256, 0, stream>>>(z, qz, qdw, acc + 256);
  trip_kernel<<<kTT / 4, 256, 0, stream>>>(z, trs, acc + 512);
  pos_kernel<<<kKP / 4, 256, 0, stream>>>(xn, prs, acc + 768);
  // code-space LSE: histogram -> 256x256 exp table -> per-pair log
  hist_kernel<<<kN / 256, 256, 0, stream>>>(out + OFF_IDX, cnt);
  code_lse<<<kNE, 256, 0, stream>>>(cb, cnt, E);
  pair_log<<<kKP / 256, 256, 0, stream>>>(out + OFF_IDX, prs, E, acc + 768);

  finalize_kernel<<<1, 256, 0, stream>>>(acc, out);
}